// Round 1
// baseline (2721.884 us; speedup 1.0000x reference)
//
#include <hip/hip_runtime.h>
#include <math.h>

#define NN 10000
#define FF 64
#define TSTEPS 8
#define EE 160000
#define TSS 200
#define HH 128
#define KK 5000
#define G4 512
#define KIN 192
#define EPSF 1e-8f

__device__ inline float wred(float v){
  #pragma unroll
  for (int off = 32; off > 0; off >>= 1) v += __shfl_xor(v, off);
  return v;
}

// ---------- setup kernels ----------

__global__ void k_setup_w(const float* Wx, const float* Wh, const float* bx, const float* bh,
                          const float* mapW, float* Wcomb, float* biasC, float* mapWr) {
  int idx = blockIdx.x * 256 + threadIdx.x;
  if (idx < KIN * G4) {
    int k = idx / G4, gh = idx % G4;
    int g = gh >> 7, hh = gh & 127;
    float v = (k < FF) ? Wx[(g * HH + hh) * FF + k] : Wh[(g * HH + hh) * HH + (k - FF)];
    Wcomb[idx] = v;
  }
  if (idx < G4) biasC[idx] = bx[idx] + bh[idx];
  if (idx < 3 * HH * HH) {
    int s = idx / (HH * HH), r = idx % (HH * HH);
    int d = r / HH, j = r % HH;
    mapWr[idx] = mapW[(s * HH + j) * HH + d];   // mapWr[(s*H+d)][j] = mapW[s][j][d]
  }
}

__global__ void k_zero(int* deg, int* cursor, int* rank, float* acc, float* high) {
  int i = blockIdx.x * 256 + threadIdx.x;
  if (i < NN) { deg[i] = 0; cursor[i] = 0; rank[i] = 0; }
  if (i < 16) acc[i] = 0.f;
  if (i < 128) high[i] = 0.f;
}

__global__ void k_deg(const int* ei, int* deg) {
  int e = blockIdx.x * 256 + threadIdx.x;
  if (e < EE) atomicAdd(&deg[ei[EE + e]], 1);
}

__global__ void k_norm(const int* deg, float* dis, float* self_norm) {
  int n = blockIdx.x * 256 + threadIdx.x;
  if (n < NN) {
    float d = 1.0f + (float)deg[n];
    float r = rsqrtf(d);
    dis[n] = r;
    self_norm[n] = 1.0f / d;
  }
}

__global__ void k_scan(const int* deg, int* row_ptr, int n) {
  __shared__ int buf[1024];
  __shared__ int carry;
  if (threadIdx.x == 0) carry = 0;
  __syncthreads();
  for (int base = 0; base < n; base += 1024) {
    int i = base + threadIdx.x;
    int v = (i < n) ? deg[i] : 0;
    buf[threadIdx.x] = v;
    __syncthreads();
    for (int off = 1; off < 1024; off <<= 1) {
      int t = (threadIdx.x >= off) ? buf[threadIdx.x - off] : 0;
      __syncthreads();
      buf[threadIdx.x] += t;
      __syncthreads();
    }
    if (i < n) row_ptr[i] = carry + buf[threadIdx.x] - v;  // exclusive
    __syncthreads();
    if (threadIdx.x == 1023) carry += buf[1023];
    __syncthreads();
  }
  if (threadIdx.x == 0) row_ptr[n] = carry;
}

__global__ void k_fill(const int* ei, const int* row_ptr, int* cursor, const float* dis,
                       int* col_src, float* col_w) {
  int e = blockIdx.x * 256 + threadIdx.x;
  if (e < EE) {
    int s = ei[e], d = ei[EE + e];
    int pos = row_ptr[d] + atomicAdd(&cursor[d], 1);
    col_src[pos] = s;
    col_w[pos] = dis[s] * dis[d];
  }
}

__global__ void k_init_state(const float* h0, const float* c0, float* hA, float* cA,
                             float* hBC, float* cBC) {
  int i = blockIdx.x * 256 + threadIdx.x;
  if (i < NN * HH) {
    float h = h0[i], c = c0[i];
    hA[i] = h; cA[i] = c;
    hBC[i] = h; hBC[NN * HH + i] = h;
    cBC[i] = c; cBC[NN * HH + i] = c;
  }
}

// ---------- GNN cell kernels ----------

// Aggregate [x|h] (192-dim) over graph with GCN norm.  grid = M blocks, 192 threads.
__global__ void __launch_bounds__(192) k_aggx(const float* xA, const float* xB, const float* h,
    const int* row_ptr, const int* col_src, const float* col_w, const float* self_norm,
    float* uagg, int M) {
  int b = blockIdx.x;
  int ch = threadIdx.x;
  int n = (b < NN) ? b : b - NN;
  const float* xr = (b < NN) ? xA : xB;
  int hbase = (b < NN) ? 0 : NN;
  int e0 = row_ptr[n], e1 = row_ptr[n + 1];
  bool isx = ch < FF;
  int chh = ch - FF;
  float acc = 0.f;
  for (int e = e0; e < e1; e++) {
    int s = col_src[e];
    float w = col_w[e];
    float v = isx ? xr[(size_t)s * FF + ch] : h[(size_t)(hbase + s) * HH + chh];
    acc += v * w;
  }
  float sn = self_norm[n];
  float vs = isx ? xr[(size_t)n * FF + ch] : h[(size_t)b * HH + chh];
  acc += vs * sn;
  uagg[(size_t)b * KIN + ch] = acc;
}

// pre = uagg(Mx192) @ Wcomb(192x512) + bias.  BM=128, BN=64, 256 threads, 8x4 micro.
__global__ void __launch_bounds__(256) k_pre(const float* uagg, const float* Wc, const float* biasC,
                                             float* pre, int M) {
  __shared__ __align__(16) float As[8][128];
  __shared__ __align__(16) float Bs[8][64];
  int m0 = blockIdx.x * 128, n0 = blockIdx.y * 64;
  int tid = threadIdx.x;
  int tx = tid & 15, ty = tid >> 4;
  float acc[8][4] = {};
  for (int kc = 0; kc < 24; kc++) {
    int k0 = kc * 8;
    {
      int ml = tid >> 1, kq = (tid & 1) * 4;
      int m = m0 + ml;
      float4 v = make_float4(0.f, 0.f, 0.f, 0.f);
      if (m < M) v = *(const float4*)(uagg + (size_t)m * KIN + k0 + kq);
      As[kq + 0][ml] = v.x; As[kq + 1][ml] = v.y; As[kq + 2][ml] = v.z; As[kq + 3][ml] = v.w;
    }
    #pragma unroll
    for (int q = 0; q < 2; q++) {
      int e = tid + q * 256;
      int kl = e >> 6, nl = e & 63;
      Bs[kl][nl] = Wc[(size_t)(k0 + kl) * G4 + n0 + nl];
    }
    __syncthreads();
    #pragma unroll
    for (int k = 0; k < 8; k++) {
      float4 a0 = *(const float4*)&As[k][ty * 4];
      float4 a1 = *(const float4*)&As[k][64 + ty * 4];
      float4 b0 = *(const float4*)&Bs[k][tx * 4];
      const float av0[4] = {a0.x, a0.y, a0.z, a0.w};
      const float av1[4] = {a1.x, a1.y, a1.z, a1.w};
      const float bv[4] = {b0.x, b0.y, b0.z, b0.w};
      #pragma unroll
      for (int i = 0; i < 4; i++)
        #pragma unroll
        for (int j = 0; j < 4; j++) {
          acc[i][j] += av0[i] * bv[j];
          acc[4 + i][j] += av1[i] * bv[j];
        }
    }
    __syncthreads();
  }
  #pragma unroll
  for (int g = 0; g < 2; g++)
    #pragma unroll
    for (int i = 0; i < 4; i++) {
      int m = m0 + g * 64 + ty * 4 + i;
      if (m < M) {
        const float* bb = biasC + n0 + tx * 4;
        float4 r;
        r.x = acc[g * 4 + i][0] + bb[0];
        r.y = acc[g * 4 + i][1] + bb[1];
        r.z = acc[g * 4 + i][2] + bb[2];
        r.w = acc[g * 4 + i][3] + bb[3];
        *(float4*)(pre + (size_t)m * G4 + n0 + tx * 4) = r;
      }
    }
}

// gates + LN + state update.  grid = M blocks, 128 threads.
__global__ void __launch_bounds__(128) k_gates(const float* pre, const float* lng, const float* lnb,
                                               float* h, float* c, int M) {
  int b = blockIdx.x;
  int j = threadIdx.x;
  const float* p = pre + (size_t)b * G4;
  float iv = p[j], fv = p[128 + j], ov = p[256 + j], gv = p[384 + j];
  float s = wred(gv), s2 = wred(gv * gv);
  __shared__ float sh[4];
  int wid = j >> 6;
  if ((j & 63) == 0) { sh[wid] = s; sh[2 + wid] = s2; }
  __syncthreads();
  float mean = (sh[0] + sh[1]) * (1.f / 128.f);
  float var = (sh[2] + sh[3]) * (1.f / 128.f) - mean * mean;
  float gn = (gv - mean) * rsqrtf(var + 1e-5f) * lng[j] + lnb[j];
  float gt = tanhf(gn);
  float ii = fmaxf(iv, 0.f), ff = fmaxf(fv, 0.f), oo = fmaxf(ov, 0.f);
  size_t ci = (size_t)b * HH + j;
  float cn = ff * c[ci] + ii * gt;
  c[ci] = cn;
  h[ci] = oo * tanhf(cn);
}

// hidden = hA@W0^T + hB@W1^T + hC@W2^T  via K=384 GEMM.  BM=128, BN=64.
__global__ void __launch_bounds__(256) k_hidden(const float* hA, const float* hB, const float* hC,
                                                const float* Wr, float* out) {
  __shared__ __align__(16) float As[8][128];
  __shared__ __align__(16) float Bs[8][64];
  int m0 = blockIdx.x * 128, n0 = blockIdx.y * 64;
  int tid = threadIdx.x;
  int tx = tid & 15, ty = tid >> 4;
  float acc[8][4] = {};
  for (int kc = 0; kc < 48; kc++) {
    int k0 = kc * 8;
    const float* S = (k0 < 128) ? hA : (k0 < 256 ? hB : hC);
    int koff = k0 & 127;
    {
      int ml = tid >> 1, kq = (tid & 1) * 4;
      int m = m0 + ml;
      float4 v = make_float4(0.f, 0.f, 0.f, 0.f);
      if (m < NN) v = *(const float4*)(S + (size_t)m * HH + koff + kq);
      As[kq + 0][ml] = v.x; As[kq + 1][ml] = v.y; As[kq + 2][ml] = v.z; As[kq + 3][ml] = v.w;
    }
    #pragma unroll
    for (int q = 0; q < 2; q++) {
      int e = tid + q * 256;
      int kl = e >> 6, nl = e & 63;
      Bs[kl][nl] = Wr[(size_t)(k0 + kl) * HH + n0 + nl];
    }
    __syncthreads();
    #pragma unroll
    for (int k = 0; k < 8; k++) {
      float4 a0 = *(const float4*)&As[k][ty * 4];
      float4 a1 = *(const float4*)&As[k][64 + ty * 4];
      float4 b0 = *(const float4*)&Bs[k][tx * 4];
      const float av0[4] = {a0.x, a0.y, a0.z, a0.w};
      const float av1[4] = {a1.x, a1.y, a1.z, a1.w};
      const float bv[4] = {b0.x, b0.y, b0.z, b0.w};
      #pragma unroll
      for (int i = 0; i < 4; i++)
        #pragma unroll
        for (int j = 0; j < 4; j++) {
          acc[i][j] += av0[i] * bv[j];
          acc[4 + i][j] += av1[i] * bv[j];
        }
    }
    __syncthreads();
  }
  #pragma unroll
  for (int g = 0; g < 2; g++)
    #pragma unroll
    for (int i = 0; i < 4; i++) {
      int m = m0 + g * 64 + ty * 4 + i;
      if (m < NN) {
        float4 r;
        r.x = acc[g * 4 + i][0]; r.y = acc[g * 4 + i][1];
        r.z = acc[g * 4 + i][2]; r.w = acc[g * 4 + i][3];
        *(float4*)(out + (size_t)m * HH + n0 + tx * 4) = r;
      }
    }
}

// ---------- pool kernels ----------

__global__ void k_vnorm(const float* pv, float* acc) {
  int t = threadIdx.x;  // 128
  float v = pv[t];
  float s = wred(v * v);
  __shared__ float sh[2];
  if ((t & 63) == 0) sh[t >> 6] = s;
  __syncthreads();
  if (t == 0) acc[0] = 1.0f / (sqrtf(sh[0] + sh[1]) + EPSF);
}

__global__ void __launch_bounds__(256) k_sc(const float* hidden, const float* pv, float* acc,
                                            float* sc) {
  int wid = threadIdx.x >> 6, lane = threadIdx.x & 63;
  int n = blockIdx.x * 4 + wid;
  float dot = 0.f;
  if (n < NN) {
    float2 hv = *(const float2*)(hidden + (size_t)n * HH + lane * 2);
    float2 vv = *(const float2*)(pv + lane * 2);
    dot = hv.x * vv.x + hv.y * vv.y;
  }
  dot = wred(dot);
  if (lane == 0 && n < NN) {
    float s = dot * acc[0];
    sc[n] = s;
    atomicAdd(&acc[1], s);
    atomicAdd(&acc[2], s * s);
  }
}

__global__ void k_sig(const float* sc, const float* acc, float* sig) {
  int n = blockIdx.x * 256 + threadIdx.x;
  if (n < NN) {
    float mean = acc[1] * (1.f / NN);
    float var = acc[2] * (1.f / NN) - mean * mean;
    float sd = sqrtf(fmaxf(var, 0.f)) + EPSF;
    float z = (sc[n] - mean) / sd;
    sig[n] = 1.f / (1.f + expf(-z));
  }
}

__global__ void __launch_bounds__(256) k_rank(const float* sc, int* rank) {
  __shared__ float sj[1024];
  int i = blockIdx.x * 256 + threadIdx.x;
  int j0 = blockIdx.y * 1024;
  for (int k = threadIdx.x; k < 1024; k += 256) {
    int j = j0 + k;
    sj[k] = (j < NN) ? sc[j] : -3.0e38f;
  }
  __syncthreads();
  float si = (i < NN) ? sc[i] : 0.f;
  int jmax = NN - j0; if (jmax > 1024) jmax = 1024;
  int cnt = 0;
  for (int k = 0; k < jmax; k++) {
    float v = sj[k];
    int j = j0 + k;
    cnt += (v > si) || (v == si && j < i);
  }
  if (i < NN && cnt) atomicAdd(&rank[i], cnt);
}

__global__ void __launch_bounds__(256) k_plogs(const float* sig, const int* rank, float* acc) {
  int i = blockIdx.x * 256 + threadIdx.x;
  float v = 0.f;
  if (i < NN) {
    float s = sig[i];
    v = (rank[i] < KK) ? logf(s + EPSF) : logf(1.f - s + EPSF);
  }
  v = wred(v);
  __shared__ float sh[4];
  if ((threadIdx.x & 63) == 0) sh[threadIdx.x >> 6] = v;
  __syncthreads();
  if (threadIdx.x == 0) atomicAdd(&acc[3], sh[0] + sh[1] + sh[2] + sh[3]);
}

__global__ void __launch_bounds__(128) k_high(const float* hidden, const float* sig,
                                              const int* rank, float* high) {
  int ch = threadIdx.x;
  int n0 = blockIdx.x * 128;
  float a = 0.f;
  for (int q = 0; q < 128; q++) {
    int n = n0 + q;
    if (n >= NN) break;
    if (rank[n] < KK) a += hidden[(size_t)n * HH + ch] * sig[n];
  }
  atomicAdd(&high[ch], a);
}

// ---------- LSTM kernels ----------

// zpre[t][r] = sum_n Wih[r][n]*ts[t][n].  grid (25 t-tiles, 8 r-tiles), 256 thr.
__global__ void __launch_bounds__(256) k_zpre(const float* Wih, const float* ts, float* zpre) {
  __shared__ float Ws[64][65];
  __shared__ float Ts[8][64];
  int t0 = blockIdx.x * 8, r0 = blockIdx.y * 64;
  int tid = threadIdx.x;
  int tt = tid >> 5, r2 = tid & 31;
  float a0 = 0.f, a1 = 0.f;
  for (int k0 = 0; k0 < NN; k0 += 64) {
    int kmax = NN - k0; if (kmax > 64) kmax = 64;
    #pragma unroll
    for (int q = 0; q < 16; q++) {
      int e = tid + q * 256;
      int r = e >> 6, k = e & 63;
      Ws[r][k] = (k < kmax) ? Wih[(size_t)(r0 + r) * NN + k0 + k] : 0.f;
    }
    #pragma unroll
    for (int q = 0; q < 2; q++) {
      int e = tid + q * 256;
      int tl = e >> 6, k = e & 63;
      Ts[tl][k] = (k < kmax) ? ts[(size_t)(t0 + tl) * NN + k0 + k] : 0.f;
    }
    __syncthreads();
    #pragma unroll 8
    for (int k = 0; k < 64; k++) {
      float av = Ts[tt][k];
      a0 += av * Ws[r2 * 2][k];
      a1 += av * Ws[r2 * 2 + 1][k];
    }
    __syncthreads();
  }
  zpre[(size_t)(t0 + tt) * G4 + r0 + r2 * 2] = a0;
  zpre[(size_t)(t0 + tt) * G4 + r0 + r2 * 2 + 1] = a1;
}

// serial recurrence: 1 block, 512 threads, Whh rows in registers.
__global__ void __launch_bounds__(512) k_lstm(const float* Whh, const float* bih, const float* bhh,
                                              const float* zpre, float* h_last) {
  __shared__ __align__(16) float hs[128];
  __shared__ float gact[4][128];
  int r = threadIdx.x;
  float w[128];
  #pragma unroll
  for (int k = 0; k < 32; k++) {
    float4 wv = *(const float4*)(Whh + (size_t)r * 128 + 4 * k);
    w[4 * k] = wv.x; w[4 * k + 1] = wv.y; w[4 * k + 2] = wv.z; w[4 * k + 3] = wv.w;
  }
  float bias = bih[r] + bhh[r];
  if (r < 128) hs[r] = 0.f;
  float cc = 0.f;
  int gate = r >> 7, j = r & 127;
  __syncthreads();
  for (int t = 0; t < TSS; t++) {
    float d = bias + zpre[(size_t)t * G4 + r];
    float d0 = 0.f, d1 = 0.f, d2 = 0.f, d3 = 0.f;
    #pragma unroll
    for (int k = 0; k < 32; k++) {
      float4 hv = *(const float4*)&hs[4 * k];
      d0 += w[4 * k] * hv.x;
      d1 += w[4 * k + 1] * hv.y;
      d2 += w[4 * k + 2] * hv.z;
      d3 += w[4 * k + 3] * hv.w;
    }
    d += (d0 + d1) + (d2 + d3);
    float a = (gate == 2) ? tanhf(d) : (1.f / (1.f + expf(-d)));
    gact[gate][j] = a;
    __syncthreads();
    if (r < 128) {
      cc = gact[1][r] * cc + gact[0][r] * gact[2][r];
      hs[r] = gact[3][r] * tanhf(cc);
    }
    __syncthreads();
  }
  if (r < 128) h_last[r] = hs[r];
}

// ---------- final MLP ----------

__global__ void __launch_bounds__(256) k_mlp(const float* high, const float* hlast, const float* acc,
    const float* W1, const float* b1, const float* lng, const float* lnb,
    const float* W2, const float* b2, const float* W3, const float* b3, float* out) {
  __shared__ float fus[256];
  __shared__ float m1[128];
  __shared__ float m2[64];
  __shared__ float red[4];
  int t = threadIdx.x;
  fus[t] = (t < 128) ? high[t] * (1.f / KK) : hlast[t - 128];
  __syncthreads();
  if (t < 128) {
    float a = b1[t];
    for (int k = 0; k < 256; k++) a += W1[t * 256 + k] * fus[k];
    m1[t] = fmaxf(a, 0.f);
  }
  __syncthreads();
  if (t < 128) {
    float x = m1[t];
    float s = wred(x), s2 = wred(x * x);
    if ((t & 63) == 0) { red[t >> 6] = s; red[2 + (t >> 6)] = s2; }
  }
  __syncthreads();
  if (t < 128) {
    float mean = (red[0] + red[1]) * (1.f / 128.f);
    float var = (red[2] + red[3]) * (1.f / 128.f) - mean * mean;
    float xn = (m1[t] - mean) * rsqrtf(var + 1e-5f) * lng[t] + lnb[t];
    __syncthreads();
    m1[t] = xn;
  } else {
    __syncthreads();
  }
  __syncthreads();
  if (t < 64) {
    float a = b2[t];
    for (int k = 0; k < 128; k++) a += W2[t * 128 + k] * m1[k];
    m2[t] = fmaxf(a, 0.f);
  }
  __syncthreads();
  if (t < 64) {
    float a = W3[t] * m2[t];
    a = wred(a);
    if (t == 0) {
      out[0] = a + b3[0];
      out[1] = -acc[3] * (1.f / NN);
    }
  }
}

// ---------- host ----------

extern "C" void kernel_launch(void* const* d_in, const int* in_sizes, int n_in,
                              void* d_out, int out_size, void* d_ws, size_t ws_size,
                              hipStream_t stream) {
  const float* x_seq = (const float*)d_in[0];
  const float* h0    = (const float*)d_in[1];
  const float* c0    = (const float*)d_in[2];
  const float* ts    = (const float*)d_in[3];
  const float* Wx    = (const float*)d_in[4];
  const float* bx    = (const float*)d_in[5];
  const float* Wh    = (const float*)d_in[6];
  const float* bh    = (const float*)d_in[7];
  const float* lng   = (const float*)d_in[8];
  const float* lnb   = (const float*)d_in[9];
  const float* mapW  = (const float*)d_in[10];
  const float* pv    = (const float*)d_in[11];
  const float* Wih   = (const float*)d_in[12];
  const float* Whh   = (const float*)d_in[13];
  const float* bih   = (const float*)d_in[14];
  const float* bhh   = (const float*)d_in[15];
  const float* W1    = (const float*)d_in[16];
  const float* b1    = (const float*)d_in[17];
  const float* mlng  = (const float*)d_in[18];
  const float* mlnb  = (const float*)d_in[19];
  const float* W2    = (const float*)d_in[20];
  const float* b2    = (const float*)d_in[21];
  const float* W3    = (const float*)d_in[22];
  const float* b3    = (const float*)d_in[23];
  const int*   ei    = (const int*)d_in[24];

  char* wsp = (char*)d_ws;
  size_t off = 0;
  auto carve = [&](size_t bytes) -> char* {
    char* p = wsp + off;
    off += (bytes + 255) & ~(size_t)255;
    return p;
  };
  float* Wcomb   = (float*)carve((size_t)KIN * G4 * 4);
  float* biasC   = (float*)carve(G4 * 4);
  float* mapWr   = (float*)carve(3 * HH * HH * 4);
  int*   degi    = (int*)carve(NN * 4);
  int*   cursor  = (int*)carve(NN * 4);
  int*   rankb   = (int*)carve(NN * 4);
  int*   row_ptr = (int*)carve((NN + 1) * 4);
  float* dis     = (float*)carve(NN * 4);
  float* self_n  = (float*)carve(NN * 4);
  int*   col_src = (int*)carve(EE * 4);
  float* col_w   = (float*)carve(EE * 4);
  float* hA      = (float*)carve((size_t)NN * HH * 4);
  float* cA      = (float*)carve((size_t)NN * HH * 4);
  float* hBC     = (float*)carve((size_t)2 * NN * HH * 4);
  float* cBC     = (float*)carve((size_t)2 * NN * HH * 4);
  float* uagg    = (float*)carve((size_t)2 * NN * KIN * 4);
  float* pre     = (float*)carve((size_t)2 * NN * G4 * 4);
  float* hidden  = (float*)carve((size_t)NN * HH * 4);
  float* sc      = (float*)carve(NN * 4);
  float* sig     = (float*)carve(NN * 4);
  float* acc     = (float*)carve(16 * 4);
  float* high    = (float*)carve(128 * 4);
  float* zpre    = (float*)carve((size_t)TSS * G4 * 4);
  float* hlast   = (float*)carve(128 * 4);

  // setup
  k_setup_w<<<384, 256, 0, stream>>>(Wx, Wh, bx, bh, mapW, Wcomb, biasC, mapWr);
  k_zero<<<40, 256, 0, stream>>>(degi, cursor, rankb, acc, high);
  k_deg<<<625, 256, 0, stream>>>(ei, degi);
  k_norm<<<40, 256, 0, stream>>>(degi, dis, self_n);
  k_scan<<<1, 1024, 0, stream>>>(degi, row_ptr, NN);
  k_fill<<<625, 256, 0, stream>>>(ei, row_ptr, cursor, dis, col_src, col_w);
  k_init_state<<<5000, 256, 0, stream>>>(h0, c0, hA, cA, hBC, cBC);

  // chain A (p=1): t = 0..7
  for (int t = 0; t < TSTEPS; t++) {
    const float* xt = x_seq + (size_t)t * NN * FF;
    k_aggx<<<NN, 192, 0, stream>>>(xt, xt, hA, row_ptr, col_src, col_w, self_n, uagg, NN);
    k_pre<<<dim3(79, 8), 256, 0, stream>>>(uagg, Wcomb, biasC, pre, NN);
    k_gates<<<NN, 128, 0, stream>>>(pre, lng, lnb, hA, cA, NN);
  }
  // chains B (even t) and C (odd t) batched: k = 0..3
  for (int k = 0; k < 4; k++) {
    const float* xe = x_seq + (size_t)(2 * k) * NN * FF;
    const float* xo = x_seq + (size_t)(2 * k + 1) * NN * FF;
    k_aggx<<<2 * NN, 192, 0, stream>>>(xe, xo, hBC, row_ptr, col_src, col_w, self_n, uagg, 2 * NN);
    k_pre<<<dim3(157, 8), 256, 0, stream>>>(uagg, Wcomb, biasC, pre, 2 * NN);
    k_gates<<<2 * NN, 128, 0, stream>>>(pre, lng, lnb, hBC, cBC, 2 * NN);
  }

  // hidden combine + pool
  k_hidden<<<dim3(79, 2), 256, 0, stream>>>(hA, hBC, hBC + (size_t)NN * HH, mapWr, hidden);
  k_vnorm<<<1, 128, 0, stream>>>(pv, acc);
  k_sc<<<2500, 256, 0, stream>>>(hidden, pv, acc, sc);
  k_sig<<<40, 256, 0, stream>>>(sc, acc, sig);
  k_rank<<<dim3(40, 10), 256, 0, stream>>>(sc, rankb);
  k_plogs<<<40, 256, 0, stream>>>(sig, rankb, acc);
  k_high<<<79, 128, 0, stream>>>(hidden, sig, rankb, high);

  // LSTM branch
  k_zpre<<<dim3(25, 8), 256, 0, stream>>>(Wih, ts, zpre);
  k_lstm<<<1, 512, 0, stream>>>(Whh, bih, bhh, zpre, hlast);

  // head
  k_mlp<<<1, 256, 0, stream>>>(high, hlast, acc, W1, b1, mlng, mlnb, W2, b2, W3, b3,
                               (float*)d_out);
}

// Round 2
// 1951.189 us; speedup vs baseline: 1.3950x; 1.3950x over previous
//
#include <hip/hip_runtime.h>
#include <math.h>

#define NN 10000
#define FF 64
#define TSTEPS 8
#define EE 160000
#define TSS 200
#define HH 128
#define KK 5000
#define G4 512
#define KIN 192
#define EPSF 1e-8f

__device__ inline float wred(float v){
  #pragma unroll
  for (int off = 32; off > 0; off >>= 1) v += __shfl_xor(v, off);
  return v;
}

// ---------- setup kernels ----------

__global__ void k_setup_w(const float* Wx, const float* Wh, const float* bx, const float* bh,
                          const float* mapW, float* Wcomb, float* biasC, float* mapWr) {
  int idx = blockIdx.x * 256 + threadIdx.x;
  if (idx < KIN * G4) {
    int k = idx / G4, gh = idx % G4;
    int g = gh >> 7, hh = gh & 127;
    float v = (k < FF) ? Wx[(g * HH + hh) * FF + k] : Wh[(g * HH + hh) * HH + (k - FF)];
    Wcomb[idx] = v;
  }
  if (idx < G4) biasC[idx] = bx[idx] + bh[idx];
  if (idx < 3 * HH * HH) {
    int s = idx / (HH * HH), r = idx % (HH * HH);
    int d = r / HH, j = r % HH;
    mapWr[idx] = mapW[(s * HH + j) * HH + d];   // mapWr[(s*H+d)][j] = mapW[s][j][d]
  }
}

__global__ void k_zero(int* deg, int* cursor, int* rank, float* acc, float* high) {
  int i = blockIdx.x * 256 + threadIdx.x;
  if (i < NN) { deg[i] = 0; cursor[i] = 0; rank[i] = 0; }
  if (i < 16) acc[i] = 0.f;
  if (i < 128) high[i] = 0.f;
}

__global__ void k_deg(const int* ei, int* deg) {
  int e = blockIdx.x * 256 + threadIdx.x;
  if (e < EE) atomicAdd(&deg[ei[EE + e]], 1);
}

__global__ void k_norm(const int* deg, float* dis, float* self_norm) {
  int n = blockIdx.x * 256 + threadIdx.x;
  if (n < NN) {
    float d = 1.0f + (float)deg[n];
    float r = rsqrtf(d);
    dis[n] = r;
    self_norm[n] = 1.0f / d;
  }
}

__global__ void k_scan(const int* deg, int* row_ptr, int n) {
  __shared__ int buf[1024];
  __shared__ int carry;
  if (threadIdx.x == 0) carry = 0;
  __syncthreads();
  for (int base = 0; base < n; base += 1024) {
    int i = base + threadIdx.x;
    int v = (i < n) ? deg[i] : 0;
    buf[threadIdx.x] = v;
    __syncthreads();
    for (int off = 1; off < 1024; off <<= 1) {
      int t = (threadIdx.x >= off) ? buf[threadIdx.x - off] : 0;
      __syncthreads();
      buf[threadIdx.x] += t;
      __syncthreads();
    }
    if (i < n) row_ptr[i] = carry + buf[threadIdx.x] - v;  // exclusive
    __syncthreads();
    if (threadIdx.x == 1023) carry += buf[1023];
    __syncthreads();
  }
  if (threadIdx.x == 0) row_ptr[n] = carry;
}

__global__ void k_fill(const int* ei, const int* row_ptr, int* cursor, const float* dis,
                       int* col_src, float* col_w) {
  int e = blockIdx.x * 256 + threadIdx.x;
  if (e < EE) {
    int s = ei[e], d = ei[EE + e];
    int pos = row_ptr[d] + atomicAdd(&cursor[d], 1);
    col_src[pos] = s;
    col_w[pos] = dis[s] * dis[d];
  }
}

__global__ void k_init_state(const float* h0, const float* c0, float* hA, float* cA,
                             float* hBC, float* cBC) {
  int i = blockIdx.x * 256 + threadIdx.x;
  if (i < NN * HH) {
    float h = h0[i], c = c0[i];
    hA[i] = h; cA[i] = c;
    hBC[i] = h; hBC[NN * HH + i] = h;
    cBC[i] = c; cBC[NN * HH + i] = c;
  }
}

// ---------- GNN cell kernels ----------

// Aggregate [x|h] (192-dim) over graph with GCN norm.  grid = M blocks, 192 threads.
__global__ void __launch_bounds__(192) k_aggx(const float* xA, const float* xB, const float* h,
    const int* row_ptr, const int* col_src, const float* col_w, const float* self_norm,
    float* uagg, int M) {
  int b = blockIdx.x;
  int ch = threadIdx.x;
  int n = (b < NN) ? b : b - NN;
  const float* xr = (b < NN) ? xA : xB;
  int hbase = (b < NN) ? 0 : NN;
  int e0 = row_ptr[n], e1 = row_ptr[n + 1];
  bool isx = ch < FF;
  int chh = ch - FF;
  float acc = 0.f;
  for (int e = e0; e < e1; e++) {
    int s = col_src[e];
    float w = col_w[e];
    float v = isx ? xr[(size_t)s * FF + ch] : h[(size_t)(hbase + s) * HH + chh];
    acc += v * w;
  }
  float sn = self_norm[n];
  float vs = isx ? xr[(size_t)n * FF + ch] : h[(size_t)b * HH + chh];
  acc += vs * sn;
  uagg[(size_t)b * KIN + ch] = acc;
}

// pre = uagg(Mx192) @ Wcomb(192x512) + bias.  BM=128, BN=64, 256 threads, 8x4 micro.
__global__ void __launch_bounds__(256) k_pre(const float* uagg, const float* Wc, const float* biasC,
                                             float* pre, int M) {
  __shared__ __align__(16) float As[8][128];
  __shared__ __align__(16) float Bs[8][64];
  int m0 = blockIdx.x * 128, n0 = blockIdx.y * 64;
  int tid = threadIdx.x;
  int tx = tid & 15, ty = tid >> 4;
  float acc[8][4] = {};
  for (int kc = 0; kc < 24; kc++) {
    int k0 = kc * 8;
    {
      int ml = tid >> 1, kq = (tid & 1) * 4;
      int m = m0 + ml;
      float4 v = make_float4(0.f, 0.f, 0.f, 0.f);
      if (m < M) v = *(const float4*)(uagg + (size_t)m * KIN + k0 + kq);
      As[kq + 0][ml] = v.x; As[kq + 1][ml] = v.y; As[kq + 2][ml] = v.z; As[kq + 3][ml] = v.w;
    }
    #pragma unroll
    for (int q = 0; q < 2; q++) {
      int e = tid + q * 256;
      int kl = e >> 6, nl = e & 63;
      Bs[kl][nl] = Wc[(size_t)(k0 + kl) * G4 + n0 + nl];
    }
    __syncthreads();
    #pragma unroll
    for (int k = 0; k < 8; k++) {
      float4 a0 = *(const float4*)&As[k][ty * 4];
      float4 a1 = *(const float4*)&As[k][64 + ty * 4];
      float4 b0 = *(const float4*)&Bs[k][tx * 4];
      const float av0[4] = {a0.x, a0.y, a0.z, a0.w};
      const float av1[4] = {a1.x, a1.y, a1.z, a1.w};
      const float bv[4] = {b0.x, b0.y, b0.z, b0.w};
      #pragma unroll
      for (int i = 0; i < 4; i++)
        #pragma unroll
        for (int j = 0; j < 4; j++) {
          acc[i][j] += av0[i] * bv[j];
          acc[4 + i][j] += av1[i] * bv[j];
        }
    }
    __syncthreads();
  }
  #pragma unroll
  for (int g = 0; g < 2; g++)
    #pragma unroll
    for (int i = 0; i < 4; i++) {
      int m = m0 + g * 64 + ty * 4 + i;
      if (m < M) {
        const float* bb = biasC + n0 + tx * 4;
        float4 r;
        r.x = acc[g * 4 + i][0] + bb[0];
        r.y = acc[g * 4 + i][1] + bb[1];
        r.z = acc[g * 4 + i][2] + bb[2];
        r.w = acc[g * 4 + i][3] + bb[3];
        *(float4*)(pre + (size_t)m * G4 + n0 + tx * 4) = r;
      }
    }
}

// gates + LN + state update.  grid = M blocks, 128 threads.
__global__ void __launch_bounds__(128) k_gates(const float* pre, const float* lng, const float* lnb,
                                               float* h, float* c, int M) {
  int b = blockIdx.x;
  int j = threadIdx.x;
  const float* p = pre + (size_t)b * G4;
  float iv = p[j], fv = p[128 + j], ov = p[256 + j], gv = p[384 + j];
  float s = wred(gv), s2 = wred(gv * gv);
  __shared__ float sh[4];
  int wid = j >> 6;
  if ((j & 63) == 0) { sh[wid] = s; sh[2 + wid] = s2; }
  __syncthreads();
  float mean = (sh[0] + sh[1]) * (1.f / 128.f);
  float var = (sh[2] + sh[3]) * (1.f / 128.f) - mean * mean;
  float gn = (gv - mean) * rsqrtf(var + 1e-5f) * lng[j] + lnb[j];
  float gt = tanhf(gn);
  float ii = fmaxf(iv, 0.f), ff = fmaxf(fv, 0.f), oo = fmaxf(ov, 0.f);
  size_t ci = (size_t)b * HH + j;
  float cn = ff * c[ci] + ii * gt;
  c[ci] = cn;
  h[ci] = oo * tanhf(cn);
}

// hidden = hA@W0^T + hB@W1^T + hC@W2^T  via K=384 GEMM.  BM=128, BN=64.
__global__ void __launch_bounds__(256) k_hidden(const float* hA, const float* hB, const float* hC,
                                                const float* Wr, float* out) {
  __shared__ __align__(16) float As[8][128];
  __shared__ __align__(16) float Bs[8][64];
  int m0 = blockIdx.x * 128, n0 = blockIdx.y * 64;
  int tid = threadIdx.x;
  int tx = tid & 15, ty = tid >> 4;
  float acc[8][4] = {};
  for (int kc = 0; kc < 48; kc++) {
    int k0 = kc * 8;
    const float* S = (k0 < 128) ? hA : (k0 < 256 ? hB : hC);
    int koff = k0 & 127;
    {
      int ml = tid >> 1, kq = (tid & 1) * 4;
      int m = m0 + ml;
      float4 v = make_float4(0.f, 0.f, 0.f, 0.f);
      if (m < NN) v = *(const float4*)(S + (size_t)m * HH + koff + kq);
      As[kq + 0][ml] = v.x; As[kq + 1][ml] = v.y; As[kq + 2][ml] = v.z; As[kq + 3][ml] = v.w;
    }
    #pragma unroll
    for (int q = 0; q < 2; q++) {
      int e = tid + q * 256;
      int kl = e >> 6, nl = e & 63;
      Bs[kl][nl] = Wr[(size_t)(k0 + kl) * HH + n0 + nl];
    }
    __syncthreads();
    #pragma unroll
    for (int k = 0; k < 8; k++) {
      float4 a0 = *(const float4*)&As[k][ty * 4];
      float4 a1 = *(const float4*)&As[k][64 + ty * 4];
      float4 b0 = *(const float4*)&Bs[k][tx * 4];
      const float av0[4] = {a0.x, a0.y, a0.z, a0.w};
      const float av1[4] = {a1.x, a1.y, a1.z, a1.w};
      const float bv[4] = {b0.x, b0.y, b0.z, b0.w};
      #pragma unroll
      for (int i = 0; i < 4; i++)
        #pragma unroll
        for (int j = 0; j < 4; j++) {
          acc[i][j] += av0[i] * bv[j];
          acc[4 + i][j] += av1[i] * bv[j];
        }
    }
    __syncthreads();
  }
  #pragma unroll
  for (int g = 0; g < 2; g++)
    #pragma unroll
    for (int i = 0; i < 4; i++) {
      int m = m0 + g * 64 + ty * 4 + i;
      if (m < NN) {
        float4 r;
        r.x = acc[g * 4 + i][0]; r.y = acc[g * 4 + i][1];
        r.z = acc[g * 4 + i][2]; r.w = acc[g * 4 + i][3];
        *(float4*)(out + (size_t)m * HH + n0 + tx * 4) = r;
      }
    }
}

// ---------- pool kernels ----------

__global__ void k_vnorm(const float* pv, float* acc) {
  int t = threadIdx.x;  // 128
  float v = pv[t];
  float s = wred(v * v);
  __shared__ float sh[2];
  if ((t & 63) == 0) sh[t >> 6] = s;
  __syncthreads();
  if (t == 0) acc[0] = 1.0f / (sqrtf(sh[0] + sh[1]) + EPSF);
}

__global__ void __launch_bounds__(256) k_sc(const float* hidden, const float* pv, float* acc,
                                            float* sc) {
  int wid = threadIdx.x >> 6, lane = threadIdx.x & 63;
  int n = blockIdx.x * 4 + wid;
  float dot = 0.f;
  if (n < NN) {
    float2 hv = *(const float2*)(hidden + (size_t)n * HH + lane * 2);
    float2 vv = *(const float2*)(pv + lane * 2);
    dot = hv.x * vv.x + hv.y * vv.y;
  }
  dot = wred(dot);
  if (lane == 0 && n < NN) {
    float s = dot * acc[0];
    sc[n] = s;
    atomicAdd(&acc[1], s);
    atomicAdd(&acc[2], s * s);
  }
}

__global__ void k_sig(const float* sc, const float* acc, float* sig) {
  int n = blockIdx.x * 256 + threadIdx.x;
  if (n < NN) {
    float mean = acc[1] * (1.f / NN);
    float var = acc[2] * (1.f / NN) - mean * mean;
    float sd = sqrtf(fmaxf(var, 0.f)) + EPSF;
    float z = (sc[n] - mean) / sd;
    sig[n] = 1.f / (1.f + expf(-z));
  }
}

__global__ void __launch_bounds__(256) k_rank(const float* sc, int* rank) {
  __shared__ float sj[1024];
  int i = blockIdx.x * 256 + threadIdx.x;
  int j0 = blockIdx.y * 1024;
  for (int k = threadIdx.x; k < 1024; k += 256) {
    int j = j0 + k;
    sj[k] = (j < NN) ? sc[j] : -3.0e38f;
  }
  __syncthreads();
  float si = (i < NN) ? sc[i] : 0.f;
  int jmax = NN - j0; if (jmax > 1024) jmax = 1024;
  int cnt = 0;
  for (int k = 0; k < jmax; k++) {
    float v = sj[k];
    int j = j0 + k;
    cnt += (v > si) || (v == si && j < i);
  }
  if (i < NN && cnt) atomicAdd(&rank[i], cnt);
}

__global__ void __launch_bounds__(256) k_plogs(const float* sig, const int* rank, float* acc) {
  int i = blockIdx.x * 256 + threadIdx.x;
  float v = 0.f;
  if (i < NN) {
    float s = sig[i];
    v = (rank[i] < KK) ? logf(s + EPSF) : logf(1.f - s + EPSF);
  }
  v = wred(v);
  __shared__ float sh[4];
  if ((threadIdx.x & 63) == 0) sh[threadIdx.x >> 6] = v;
  __syncthreads();
  if (threadIdx.x == 0) atomicAdd(&acc[3], sh[0] + sh[1] + sh[2] + sh[3]);
}

__global__ void __launch_bounds__(128) k_high(const float* hidden, const float* sig,
                                              const int* rank, float* high) {
  int ch = threadIdx.x;
  int n0 = blockIdx.x * 128;
  float a = 0.f;
  for (int q = 0; q < 128; q++) {
    int n = n0 + q;
    if (n >= NN) break;
    if (rank[n] < KK) a += hidden[(size_t)n * HH + ch] * sig[n];
  }
  atomicAdd(&high[ch], a);
}

// ---------- LSTM kernels ----------

// Split-K NT-GEMM: part[ks][r][t] = sum_{k in split ks} Wih[r][k] * ts[t][k]
// C is 512 x 256 (t padded, masked).  BM=64, BN=64, BK=16, 4x4 micro, grid (8,4,16).
__global__ void __launch_bounds__(256) k_zpre2(const float* Wih, const float* ts, float* part) {
  __shared__ __align__(16) float As[16][64];
  __shared__ __align__(16) float Bs[16][64];
  int m0 = blockIdx.x * 64;          // over 512 rows of Wih
  int n0 = blockIdx.y * 64;          // over 256 (t padded; valid t < 200)
  int ks = blockIdx.z;               // 16 K-splits
  int kbeg = ks * 624;
  int kend = (ks == 15) ? NN : kbeg + 624;   // 15*624 + 640 = 10000, all %16==0
  int tid = threadIdx.x;
  int tx = tid & 15, ty = tid >> 4;
  int lm = tid >> 2, kq = (tid & 3) * 4;
  bool bvalid = (n0 + lm) < TSS;
  float acc[4][4] = {};
  for (int k0 = kbeg; k0 < kend; k0 += 16) {
    {
      float4 v = *(const float4*)(Wih + (size_t)(m0 + lm) * NN + k0 + kq);
      As[kq + 0][lm] = v.x; As[kq + 1][lm] = v.y; As[kq + 2][lm] = v.z; As[kq + 3][lm] = v.w;
    }
    {
      float4 v = make_float4(0.f, 0.f, 0.f, 0.f);
      if (bvalid) v = *(const float4*)(ts + (size_t)(n0 + lm) * NN + k0 + kq);
      Bs[kq + 0][lm] = v.x; Bs[kq + 1][lm] = v.y; Bs[kq + 2][lm] = v.z; Bs[kq + 3][lm] = v.w;
    }
    __syncthreads();
    #pragma unroll
    for (int k = 0; k < 16; k++) {
      float4 a0 = *(const float4*)&As[k][ty * 4];
      float4 b0 = *(const float4*)&Bs[k][tx * 4];
      const float av[4] = {a0.x, a0.y, a0.z, a0.w};
      const float bv[4] = {b0.x, b0.y, b0.z, b0.w};
      #pragma unroll
      for (int i = 0; i < 4; i++)
        #pragma unroll
        for (int j = 0; j < 4; j++)
          acc[i][j] += av[i] * bv[j];
    }
    __syncthreads();
  }
  float* pd = part + ((size_t)ks << 17);   // 512*256 per split
  #pragma unroll
  for (int i = 0; i < 4; i++) {
    float4 r4 = make_float4(acc[i][0], acc[i][1], acc[i][2], acc[i][3]);
    *(float4*)(pd + (size_t)(m0 + ty * 4 + i) * 256 + n0 + tx * 4) = r4;
  }
}

// reduce 16 partials; write zpre[t][r] (t<200).
__global__ void __launch_bounds__(256) k_zred(const float* part, float* zpre) {
  int r = blockIdx.x;          // 512
  int t = threadIdx.x;         // 256
  int base = r * 256 + t;
  float s = 0.f;
  #pragma unroll
  for (int k = 0; k < 16; k++) s += part[(k << 17) + base];
  if (t < TSS) zpre[(size_t)t * G4 + r] = s;
}

// serial recurrence: 1 block, 512 threads, Whh rows in registers.
__global__ void __launch_bounds__(512) k_lstm(const float* Whh, const float* bih, const float* bhh,
                                              const float* zpre, float* h_last) {
  __shared__ __align__(16) float hs[128];
  __shared__ float gact[4][128];
  int r = threadIdx.x;
  float w[128];
  #pragma unroll
  for (int k = 0; k < 32; k++) {
    float4 wv = *(const float4*)(Whh + (size_t)r * 128 + 4 * k);
    w[4 * k] = wv.x; w[4 * k + 1] = wv.y; w[4 * k + 2] = wv.z; w[4 * k + 3] = wv.w;
  }
  float bias = bih[r] + bhh[r];
  if (r < 128) hs[r] = 0.f;
  float cc = 0.f;
  int gate = r >> 7, j = r & 127;
  __syncthreads();
  for (int t = 0; t < TSS; t++) {
    float d = bias + zpre[(size_t)t * G4 + r];
    float d0 = 0.f, d1 = 0.f, d2 = 0.f, d3 = 0.f;
    #pragma unroll
    for (int k = 0; k < 32; k++) {
      float4 hv = *(const float4*)&hs[4 * k];
      d0 += w[4 * k] * hv.x;
      d1 += w[4 * k + 1] * hv.y;
      d2 += w[4 * k + 2] * hv.z;
      d3 += w[4 * k + 3] * hv.w;
    }
    d += (d0 + d1) + (d2 + d3);
    float a = (gate == 2) ? tanhf(d) : (1.f / (1.f + expf(-d)));
    gact[gate][j] = a;
    __syncthreads();
    if (r < 128) {
      cc = gact[1][r] * cc + gact[0][r] * gact[2][r];
      hs[r] = gact[3][r] * tanhf(cc);
    }
    __syncthreads();
  }
  if (r < 128) h_last[r] = hs[r];
}

// ---------- final MLP ----------

__global__ void __launch_bounds__(256) k_mlp(const float* high, const float* hlast, const float* acc,
    const float* W1, const float* b1, const float* lng, const float* lnb,
    const float* W2, const float* b2, const float* W3, const float* b3, float* out) {
  __shared__ float fus[256];
  __shared__ float m1[128];
  __shared__ float m2[64];
  __shared__ float red[4];
  int t = threadIdx.x;
  fus[t] = (t < 128) ? high[t] * (1.f / KK) : hlast[t - 128];
  __syncthreads();
  if (t < 128) {
    float a = b1[t];
    for (int k = 0; k < 256; k++) a += W1[t * 256 + k] * fus[k];
    m1[t] = fmaxf(a, 0.f);
  }
  __syncthreads();
  if (t < 128) {
    float x = m1[t];
    float s = wred(x), s2 = wred(x * x);
    if ((t & 63) == 0) { red[t >> 6] = s; red[2 + (t >> 6)] = s2; }
  }
  __syncthreads();
  if (t < 128) {
    float mean = (red[0] + red[1]) * (1.f / 128.f);
    float var = (red[2] + red[3]) * (1.f / 128.f) - mean * mean;
    float xn = (m1[t] - mean) * rsqrtf(var + 1e-5f) * lng[t] + lnb[t];
    __syncthreads();
    m1[t] = xn;
  } else {
    __syncthreads();
  }
  __syncthreads();
  if (t < 64) {
    float a = b2[t];
    for (int k = 0; k < 128; k++) a += W2[t * 128 + k] * m1[k];
    m2[t] = fmaxf(a, 0.f);
  }
  __syncthreads();
  if (t < 64) {
    float a = W3[t] * m2[t];
    a = wred(a);
    if (t == 0) {
      out[0] = a + b3[0];
      out[1] = -acc[3] * (1.f / NN);
    }
  }
}

// ---------- host ----------

extern "C" void kernel_launch(void* const* d_in, const int* in_sizes, int n_in,
                              void* d_out, int out_size, void* d_ws, size_t ws_size,
                              hipStream_t stream) {
  const float* x_seq = (const float*)d_in[0];
  const float* h0    = (const float*)d_in[1];
  const float* c0    = (const float*)d_in[2];
  const float* ts    = (const float*)d_in[3];
  const float* Wx    = (const float*)d_in[4];
  const float* bx    = (const float*)d_in[5];
  const float* Wh    = (const float*)d_in[6];
  const float* bh    = (const float*)d_in[7];
  const float* lng   = (const float*)d_in[8];
  const float* lnb   = (const float*)d_in[9];
  const float* mapW  = (const float*)d_in[10];
  const float* pv    = (const float*)d_in[11];
  const float* Wih   = (const float*)d_in[12];
  const float* Whh   = (const float*)d_in[13];
  const float* bih   = (const float*)d_in[14];
  const float* bhh   = (const float*)d_in[15];
  const float* W1    = (const float*)d_in[16];
  const float* b1    = (const float*)d_in[17];
  const float* mlng  = (const float*)d_in[18];
  const float* mlnb  = (const float*)d_in[19];
  const float* W2    = (const float*)d_in[20];
  const float* b2    = (const float*)d_in[21];
  const float* W3    = (const float*)d_in[22];
  const float* b3    = (const float*)d_in[23];
  const int*   ei    = (const int*)d_in[24];

  char* wsp = (char*)d_ws;
  size_t off = 0;
  auto carve = [&](size_t bytes) -> char* {
    char* p = wsp + off;
    off += (bytes + 255) & ~(size_t)255;
    return p;
  };
  float* Wcomb   = (float*)carve((size_t)KIN * G4 * 4);
  float* biasC   = (float*)carve(G4 * 4);
  float* mapWr   = (float*)carve(3 * HH * HH * 4);
  int*   degi    = (int*)carve(NN * 4);
  int*   cursor  = (int*)carve(NN * 4);
  int*   rankb   = (int*)carve(NN * 4);
  int*   row_ptr = (int*)carve((NN + 1) * 4);
  float* dis     = (float*)carve(NN * 4);
  float* self_n  = (float*)carve(NN * 4);
  int*   col_src = (int*)carve(EE * 4);
  float* col_w   = (float*)carve(EE * 4);
  float* hA      = (float*)carve((size_t)NN * HH * 4);
  float* cA      = (float*)carve((size_t)NN * HH * 4);
  float* hBC     = (float*)carve((size_t)2 * NN * HH * 4);
  float* cBC     = (float*)carve((size_t)2 * NN * HH * 4);
  float* uagg    = (float*)carve((size_t)2 * NN * KIN * 4);
  float* pre     = (float*)carve((size_t)2 * NN * G4 * 4);
  float* hidden  = (float*)carve((size_t)NN * HH * 4);
  float* sc      = (float*)carve(NN * 4);
  float* sig     = (float*)carve(NN * 4);
  float* acc     = (float*)carve(16 * 4);
  float* high    = (float*)carve(128 * 4);
  float* zpre    = (float*)carve((size_t)TSS * G4 * 4);
  float* hlast   = (float*)carve(128 * 4);

  // setup
  k_setup_w<<<384, 256, 0, stream>>>(Wx, Wh, bx, bh, mapW, Wcomb, biasC, mapWr);
  k_zero<<<40, 256, 0, stream>>>(degi, cursor, rankb, acc, high);
  k_deg<<<625, 256, 0, stream>>>(ei, degi);
  k_norm<<<40, 256, 0, stream>>>(degi, dis, self_n);
  k_scan<<<1, 1024, 0, stream>>>(degi, row_ptr, NN);
  k_fill<<<625, 256, 0, stream>>>(ei, row_ptr, cursor, dis, col_src, col_w);
  k_init_state<<<5000, 256, 0, stream>>>(h0, c0, hA, cA, hBC, cBC);

  // chain A (p=1): t = 0..7
  for (int t = 0; t < TSTEPS; t++) {
    const float* xt = x_seq + (size_t)t * NN * FF;
    k_aggx<<<NN, 192, 0, stream>>>(xt, xt, hA, row_ptr, col_src, col_w, self_n, uagg, NN);
    k_pre<<<dim3(79, 8), 256, 0, stream>>>(uagg, Wcomb, biasC, pre, NN);
    k_gates<<<NN, 128, 0, stream>>>(pre, lng, lnb, hA, cA, NN);
  }
  // chains B (even t) and C (odd t) batched: k = 0..3
  for (int k = 0; k < 4; k++) {
    const float* xe = x_seq + (size_t)(2 * k) * NN * FF;
    const float* xo = x_seq + (size_t)(2 * k + 1) * NN * FF;
    k_aggx<<<2 * NN, 192, 0, stream>>>(xe, xo, hBC, row_ptr, col_src, col_w, self_n, uagg, 2 * NN);
    k_pre<<<dim3(157, 8), 256, 0, stream>>>(uagg, Wcomb, biasC, pre, 2 * NN);
    k_gates<<<2 * NN, 128, 0, stream>>>(pre, lng, lnb, hBC, cBC, 2 * NN);
  }

  // hidden combine + pool
  k_hidden<<<dim3(79, 2), 256, 0, stream>>>(hA, hBC, hBC + (size_t)NN * HH, mapWr, hidden);
  k_vnorm<<<1, 128, 0, stream>>>(pv, acc);
  k_sc<<<2500, 256, 0, stream>>>(hidden, pv, acc, sc);
  k_sig<<<40, 256, 0, stream>>>(sc, acc, sig);
  k_rank<<<dim3(40, 10), 256, 0, stream>>>(sc, rankb);
  k_plogs<<<40, 256, 0, stream>>>(sig, rankb, acc);
  k_high<<<79, 128, 0, stream>>>(hidden, sig, rankb, high);

  // LSTM branch: split-K GEMM into `pre` scratch (free after GNN loops), then reduce
  k_zpre2<<<dim3(8, 4, 16), 256, 0, stream>>>(Wih, ts, pre);
  k_zred<<<512, 256, 0, stream>>>(pre, zpre);
  k_lstm<<<1, 512, 0, stream>>>(Whh, bih, bhh, zpre, hlast);

  // head
  k_mlp<<<1, 256, 0, stream>>>(high, hlast, acc, W1, b1, mlng, mlnb, W2, b2, W3, b3,
                               (float*)d_out);
}

// Round 3
// 1709.347 us; speedup vs baseline: 1.5924x; 1.1415x over previous
//
#include <hip/hip_runtime.h>
#include <math.h>

#define NN 10000
#define FF 64
#define TSTEPS 8
#define EE 160000
#define TSS 200
#define HH 128
#define KK 5000
#define G4 512
#define KIN 192
#define EPSF 1e-8f

__device__ inline float wred(float v){
  #pragma unroll
  for (int off = 32; off > 0; off >>= 1) v += __shfl_xor(v, off);
  return v;
}

// ---------- setup kernels ----------

__global__ void k_setup_w(const float* Wx, const float* Wh, const float* bx, const float* bh,
                          const float* mapW, float* Wcomb, float* biasC, float* mapWr) {
  int idx = blockIdx.x * 256 + threadIdx.x;
  if (idx < KIN * G4) {
    int k = idx / G4, gh = idx % G4;
    int g = gh >> 7, hh = gh & 127;
    float v = (k < FF) ? Wx[(g * HH + hh) * FF + k] : Wh[(g * HH + hh) * HH + (k - FF)];
    Wcomb[idx] = v;
  }
  if (idx < G4) biasC[idx] = bx[idx] + bh[idx];
  if (idx < 3 * HH * HH) {
    int s = idx / (HH * HH), r = idx % (HH * HH);
    int d = r / HH, j = r % HH;
    mapWr[idx] = mapW[(s * HH + j) * HH + d];   // mapWr[(s*H+d)][j] = mapW[s][j][d]
  }
}

__global__ void k_zero(int* deg, int* cursor, int* rank, float* acc, float* high) {
  int i = blockIdx.x * 256 + threadIdx.x;
  if (i < NN) { deg[i] = 0; cursor[i] = 0; rank[i] = 0; }
  if (i < 16) acc[i] = 0.f;
  if (i < 128) high[i] = 0.f;
}

__global__ void k_deg(const int* ei, int* deg) {
  int e = blockIdx.x * 256 + threadIdx.x;
  if (e < EE) atomicAdd(&deg[ei[EE + e]], 1);
}

__global__ void k_norm(const int* deg, float* dis, float* self_norm) {
  int n = blockIdx.x * 256 + threadIdx.x;
  if (n < NN) {
    float d = 1.0f + (float)deg[n];
    float r = rsqrtf(d);
    dis[n] = r;
    self_norm[n] = 1.0f / d;
  }
}

__global__ void k_scan(const int* deg, int* row_ptr, int n) {
  __shared__ int buf[1024];
  __shared__ int carry;
  if (threadIdx.x == 0) carry = 0;
  __syncthreads();
  for (int base = 0; base < n; base += 1024) {
    int i = base + threadIdx.x;
    int v = (i < n) ? deg[i] : 0;
    buf[threadIdx.x] = v;
    __syncthreads();
    for (int off = 1; off < 1024; off <<= 1) {
      int t = (threadIdx.x >= off) ? buf[threadIdx.x - off] : 0;
      __syncthreads();
      buf[threadIdx.x] += t;
      __syncthreads();
    }
    if (i < n) row_ptr[i] = carry + buf[threadIdx.x] - v;  // exclusive
    __syncthreads();
    if (threadIdx.x == 1023) carry += buf[1023];
    __syncthreads();
  }
  if (threadIdx.x == 0) row_ptr[n] = carry;
}

__global__ void k_fill(const int* ei, const int* row_ptr, int* cursor, const float* dis,
                       int* col_src, float* col_w) {
  int e = blockIdx.x * 256 + threadIdx.x;
  if (e < EE) {
    int s = ei[e], d = ei[EE + e];
    int pos = row_ptr[d] + atomicAdd(&cursor[d], 1);
    col_src[pos] = s;
    col_w[pos] = dis[s] * dis[d];
  }
}

__global__ void k_init_state(const float* h0, const float* c0, float* hA, float* cA,
                             float* hBC, float* cBC) {
  int i = blockIdx.x * 256 + threadIdx.x;
  if (i < NN * HH) {
    float h = h0[i], c = c0[i];
    hA[i] = h; cA[i] = c;
    hBC[i] = h; hBC[NN * HH + i] = h;
    cBC[i] = c; cBC[NN * HH + i] = c;
  }
}

// ---------- GNN cell kernels ----------

// Aggregate [x|h] (192-dim) over graph with GCN norm.  grid = M blocks, 192 threads.
__global__ void __launch_bounds__(192) k_aggx(const float* xA, const float* xB, const float* h,
    const int* row_ptr, const int* col_src, const float* col_w, const float* self_norm,
    float* uagg, int M) {
  int b = blockIdx.x;
  int ch = threadIdx.x;
  int n = (b < NN) ? b : b - NN;
  const float* xr = (b < NN) ? xA : xB;
  int hbase = (b < NN) ? 0 : NN;
  int e0 = row_ptr[n], e1 = row_ptr[n + 1];
  bool isx = ch < FF;
  int chh = ch - FF;
  float acc = 0.f;
  for (int e = e0; e < e1; e++) {
    int s = col_src[e];
    float w = col_w[e];
    float v = isx ? xr[(size_t)s * FF + ch] : h[(size_t)(hbase + s) * HH + chh];
    acc += v * w;
  }
  float sn = self_norm[n];
  float vs = isx ? xr[(size_t)n * FF + ch] : h[(size_t)b * HH + chh];
  acc += vs * sn;
  uagg[(size_t)b * KIN + ch] = acc;
}

// pre = uagg(Mx192) @ Wcomb(192x512) + bias.  BM=128, BN=64, 256 threads, 8x4 micro.
__global__ void __launch_bounds__(256) k_pre(const float* uagg, const float* Wc, const float* biasC,
                                             float* pre, int M) {
  __shared__ __align__(16) float As[8][128];
  __shared__ __align__(16) float Bs[8][64];
  int m0 = blockIdx.x * 128, n0 = blockIdx.y * 64;
  int tid = threadIdx.x;
  int tx = tid & 15, ty = tid >> 4;
  float acc[8][4] = {};
  for (int kc = 0; kc < 24; kc++) {
    int k0 = kc * 8;
    {
      int ml = tid >> 1, kq = (tid & 1) * 4;
      int m = m0 + ml;
      float4 v = make_float4(0.f, 0.f, 0.f, 0.f);
      if (m < M) v = *(const float4*)(uagg + (size_t)m * KIN + k0 + kq);
      As[kq + 0][ml] = v.x; As[kq + 1][ml] = v.y; As[kq + 2][ml] = v.z; As[kq + 3][ml] = v.w;
    }
    #pragma unroll
    for (int q = 0; q < 2; q++) {
      int e = tid + q * 256;
      int kl = e >> 6, nl = e & 63;
      Bs[kl][nl] = Wc[(size_t)(k0 + kl) * G4 + n0 + nl];
    }
    __syncthreads();
    #pragma unroll
    for (int k = 0; k < 8; k++) {
      float4 a0 = *(const float4*)&As[k][ty * 4];
      float4 a1 = *(const float4*)&As[k][64 + ty * 4];
      float4 b0 = *(const float4*)&Bs[k][tx * 4];
      const float av0[4] = {a0.x, a0.y, a0.z, a0.w};
      const float av1[4] = {a1.x, a1.y, a1.z, a1.w};
      const float bv[4] = {b0.x, b0.y, b0.z, b0.w};
      #pragma unroll
      for (int i = 0; i < 4; i++)
        #pragma unroll
        for (int j = 0; j < 4; j++) {
          acc[i][j] += av0[i] * bv[j];
          acc[4 + i][j] += av1[i] * bv[j];
        }
    }
    __syncthreads();
  }
  #pragma unroll
  for (int g = 0; g < 2; g++)
    #pragma unroll
    for (int i = 0; i < 4; i++) {
      int m = m0 + g * 64 + ty * 4 + i;
      if (m < M) {
        const float* bb = biasC + n0 + tx * 4;
        float4 r;
        r.x = acc[g * 4 + i][0] + bb[0];
        r.y = acc[g * 4 + i][1] + bb[1];
        r.z = acc[g * 4 + i][2] + bb[2];
        r.w = acc[g * 4 + i][3] + bb[3];
        *(float4*)(pre + (size_t)m * G4 + n0 + tx * 4) = r;
      }
    }
}

// gates + LN + state update.  grid = M blocks, 128 threads.
__global__ void __launch_bounds__(128) k_gates(const float* pre, const float* lng, const float* lnb,
                                               float* h, float* c, int M) {
  int b = blockIdx.x;
  int j = threadIdx.x;
  const float* p = pre + (size_t)b * G4;
  float iv = p[j], fv = p[128 + j], ov = p[256 + j], gv = p[384 + j];
  float s = wred(gv), s2 = wred(gv * gv);
  __shared__ float sh[4];
  int wid = j >> 6;
  if ((j & 63) == 0) { sh[wid] = s; sh[2 + wid] = s2; }
  __syncthreads();
  float mean = (sh[0] + sh[1]) * (1.f / 128.f);
  float var = (sh[2] + sh[3]) * (1.f / 128.f) - mean * mean;
  float gn = (gv - mean) * rsqrtf(var + 1e-5f) * lng[j] + lnb[j];
  float gt = tanhf(gn);
  float ii = fmaxf(iv, 0.f), ff = fmaxf(fv, 0.f), oo = fmaxf(ov, 0.f);
  size_t ci = (size_t)b * HH + j;
  float cn = ff * c[ci] + ii * gt;
  c[ci] = cn;
  h[ci] = oo * tanhf(cn);
}

// hidden = hA@W0^T + hB@W1^T + hC@W2^T  via K=384 GEMM.  BM=128, BN=64.
__global__ void __launch_bounds__(256) k_hidden(const float* hA, const float* hB, const float* hC,
                                                const float* Wr, float* out) {
  __shared__ __align__(16) float As[8][128];
  __shared__ __align__(16) float Bs[8][64];
  int m0 = blockIdx.x * 128, n0 = blockIdx.y * 64;
  int tid = threadIdx.x;
  int tx = tid & 15, ty = tid >> 4;
  float acc[8][4] = {};
  for (int kc = 0; kc < 48; kc++) {
    int k0 = kc * 8;
    const float* S = (k0 < 128) ? hA : (k0 < 256 ? hB : hC);
    int koff = k0 & 127;
    {
      int ml = tid >> 1, kq = (tid & 1) * 4;
      int m = m0 + ml;
      float4 v = make_float4(0.f, 0.f, 0.f, 0.f);
      if (m < NN) v = *(const float4*)(S + (size_t)m * HH + koff + kq);
      As[kq + 0][ml] = v.x; As[kq + 1][ml] = v.y; As[kq + 2][ml] = v.z; As[kq + 3][ml] = v.w;
    }
    #pragma unroll
    for (int q = 0; q < 2; q++) {
      int e = tid + q * 256;
      int kl = e >> 6, nl = e & 63;
      Bs[kl][nl] = Wr[(size_t)(k0 + kl) * HH + n0 + nl];
    }
    __syncthreads();
    #pragma unroll
    for (int k = 0; k < 8; k++) {
      float4 a0 = *(const float4*)&As[k][ty * 4];
      float4 a1 = *(const float4*)&As[k][64 + ty * 4];
      float4 b0 = *(const float4*)&Bs[k][tx * 4];
      const float av0[4] = {a0.x, a0.y, a0.z, a0.w};
      const float av1[4] = {a1.x, a1.y, a1.z, a1.w};
      const float bv[4] = {b0.x, b0.y, b0.z, b0.w};
      #pragma unroll
      for (int i = 0; i < 4; i++)
        #pragma unroll
        for (int j = 0; j < 4; j++) {
          acc[i][j] += av0[i] * bv[j];
          acc[4 + i][j] += av1[i] * bv[j];
        }
    }
    __syncthreads();
  }
  #pragma unroll
  for (int g = 0; g < 2; g++)
    #pragma unroll
    for (int i = 0; i < 4; i++) {
      int m = m0 + g * 64 + ty * 4 + i;
      if (m < NN) {
        float4 r;
        r.x = acc[g * 4 + i][0]; r.y = acc[g * 4 + i][1];
        r.z = acc[g * 4 + i][2]; r.w = acc[g * 4 + i][3];
        *(float4*)(out + (size_t)m * HH + n0 + tx * 4) = r;
      }
    }
}

// ---------- pool kernels ----------

__global__ void k_vnorm(const float* pv, float* acc) {
  int t = threadIdx.x;  // 128
  float v = pv[t];
  float s = wred(v * v);
  __shared__ float sh[2];
  if ((t & 63) == 0) sh[t >> 6] = s;
  __syncthreads();
  if (t == 0) acc[0] = 1.0f / (sqrtf(sh[0] + sh[1]) + EPSF);
}

// grid-stride: 250 blocks x 4 waves; per-block partial reduce, 2 atomics per block.
__global__ void __launch_bounds__(256) k_sc(const float* hidden, const float* pv, float* acc,
                                            float* sc) {
  int wid = threadIdx.x >> 6, lane = threadIdx.x & 63;
  float2 vv = *(const float2*)(pv + lane * 2);
  float inv = acc[0];
  float ls = 0.f, ls2 = 0.f;
  for (int n = blockIdx.x * 4 + wid; n < NN; n += gridDim.x * 4) {
    float2 hv = *(const float2*)(hidden + (size_t)n * HH + lane * 2);
    float dot = hv.x * vv.x + hv.y * vv.y;
    dot = wred(dot);
    if (lane == 0) {
      float s = dot * inv;
      sc[n] = s;
      ls += s;
      ls2 += s * s;
    }
  }
  __shared__ float sh[8];
  if (lane == 0) { sh[wid] = ls; sh[4 + wid] = ls2; }
  __syncthreads();
  if (threadIdx.x == 0) {
    atomicAdd(&acc[1], sh[0] + sh[1] + sh[2] + sh[3]);
    atomicAdd(&acc[2], sh[4] + sh[5] + sh[6] + sh[7]);
  }
}

__global__ void k_sig(const float* sc, const float* acc, float* sig) {
  int n = blockIdx.x * 256 + threadIdx.x;
  if (n < NN) {
    float mean = acc[1] * (1.f / NN);
    float var = acc[2] * (1.f / NN) - mean * mean;
    float sd = sqrtf(fmaxf(var, 0.f)) + EPSF;
    float z = (sc[n] - mean) / sd;
    sig[n] = 1.f / (1.f + expf(-z));
  }
}

__global__ void __launch_bounds__(256) k_rank(const float* sc, int* rank) {
  __shared__ float sj[1024];
  int i = blockIdx.x * 256 + threadIdx.x;
  int j0 = blockIdx.y * 1024;
  for (int k = threadIdx.x; k < 1024; k += 256) {
    int j = j0 + k;
    sj[k] = (j < NN) ? sc[j] : -3.0e38f;
  }
  __syncthreads();
  float si = (i < NN) ? sc[i] : 0.f;
  int jmax = NN - j0; if (jmax > 1024) jmax = 1024;
  int cnt = 0;
  for (int k = 0; k < jmax; k++) {
    float v = sj[k];
    int j = j0 + k;
    cnt += (v > si) || (v == si && j < i);
  }
  if (i < NN && cnt) atomicAdd(&rank[i], cnt);
}

__global__ void __launch_bounds__(256) k_plogs(const float* sig, const int* rank, float* acc) {
  int i = blockIdx.x * 256 + threadIdx.x;
  float v = 0.f;
  if (i < NN) {
    float s = sig[i];
    v = (rank[i] < KK) ? logf(s + EPSF) : logf(1.f - s + EPSF);
  }
  v = wred(v);
  __shared__ float sh[4];
  if ((threadIdx.x & 63) == 0) sh[threadIdx.x >> 6] = v;
  __syncthreads();
  if (threadIdx.x == 0) atomicAdd(&acc[3], sh[0] + sh[1] + sh[2] + sh[3]);
}

__global__ void __launch_bounds__(128) k_high(const float* hidden, const float* sig,
                                              const int* rank, float* high) {
  int ch = threadIdx.x;
  int n0 = blockIdx.x * 128;
  float a = 0.f;
  for (int q = 0; q < 128; q++) {
    int n = n0 + q;
    if (n >= NN) break;
    if (rank[n] < KK) a += hidden[(size_t)n * HH + ch] * sig[n];
  }
  atomicAdd(&high[ch], a);
}

// ---------- LSTM kernels ----------

// Split-K NT-GEMM: part[ks][r][t] = sum_{k in split ks} Wih[r][k] * ts[t][k]
// C is 512 x 256 (t padded, masked).  BM=64, BN=64, BK=16, 4x4 micro, grid (8,4,16).
__global__ void __launch_bounds__(256) k_zpre2(const float* Wih, const float* ts, float* part) {
  __shared__ __align__(16) float As[16][64];
  __shared__ __align__(16) float Bs[16][64];
  int m0 = blockIdx.x * 64;          // over 512 rows of Wih
  int n0 = blockIdx.y * 64;          // over 256 (t padded; valid t < 200)
  int ks = blockIdx.z;               // 16 K-splits
  int kbeg = ks * 624;
  int kend = (ks == 15) ? NN : kbeg + 624;   // 15*624 + 640 = 10000, all %16==0
  int tid = threadIdx.x;
  int tx = tid & 15, ty = tid >> 4;
  int lm = tid >> 2, kq = (tid & 3) * 4;
  bool bvalid = (n0 + lm) < TSS;
  float acc[4][4] = {};
  for (int k0 = kbeg; k0 < kend; k0 += 16) {
    {
      float4 v = *(const float4*)(Wih + (size_t)(m0 + lm) * NN + k0 + kq);
      As[kq + 0][lm] = v.x; As[kq + 1][lm] = v.y; As[kq + 2][lm] = v.z; As[kq + 3][lm] = v.w;
    }
    {
      float4 v = make_float4(0.f, 0.f, 0.f, 0.f);
      if (bvalid) v = *(const float4*)(ts + (size_t)(n0 + lm) * NN + k0 + kq);
      Bs[kq + 0][lm] = v.x; Bs[kq + 1][lm] = v.y; Bs[kq + 2][lm] = v.z; Bs[kq + 3][lm] = v.w;
    }
    __syncthreads();
    #pragma unroll
    for (int k = 0; k < 16; k++) {
      float4 a0 = *(const float4*)&As[k][ty * 4];
      float4 b0 = *(const float4*)&Bs[k][tx * 4];
      const float av[4] = {a0.x, a0.y, a0.z, a0.w};
      const float bv[4] = {b0.x, b0.y, b0.z, b0.w};
      #pragma unroll
      for (int i = 0; i < 4; i++)
        #pragma unroll
        for (int j = 0; j < 4; j++)
          acc[i][j] += av[i] * bv[j];
    }
    __syncthreads();
  }
  float* pd = part + ((size_t)ks << 17);   // 512*256 per split
  #pragma unroll
  for (int i = 0; i < 4; i++) {
    float4 r4 = make_float4(acc[i][0], acc[i][1], acc[i][2], acc[i][3]);
    *(float4*)(pd + (size_t)(m0 + ty * 4 + i) * 256 + n0 + tx * 4) = r4;
  }
}

// reduce 16 partials; write zpre[t][r] (t<200).
__global__ void __launch_bounds__(256) k_zred(const float* part, float* zpre) {
  int r = blockIdx.x;          // 512
  int t = threadIdx.x;         // 256
  int base = r * 256 + t;
  float s = 0.f;
  #pragma unroll
  for (int k = 0; k < 16; k++) s += part[(k << 17) + base];
  if (t < TSS) zpre[(size_t)t * G4 + r] = s;
}

// serial recurrence: 1 block, 512 threads, Whh rows in registers.
__global__ void __launch_bounds__(512) k_lstm(const float* Whh, const float* bih, const float* bhh,
                                              const float* zpre, float* h_last) {
  __shared__ __align__(16) float hs[128];
  __shared__ float gact[4][128];
  int r = threadIdx.x;
  float w[128];
  #pragma unroll
  for (int k = 0; k < 32; k++) {
    float4 wv = *(const float4*)(Whh + (size_t)r * 128 + 4 * k);
    w[4 * k] = wv.x; w[4 * k + 1] = wv.y; w[4 * k + 2] = wv.z; w[4 * k + 3] = wv.w;
  }
  float bias = bih[r] + bhh[r];
  if (r < 128) hs[r] = 0.f;
  float cc = 0.f;
  int gate = r >> 7, j = r & 127;
  __syncthreads();
  for (int t = 0; t < TSS; t++) {
    float d = bias + zpre[(size_t)t * G4 + r];
    float d0 = 0.f, d1 = 0.f, d2 = 0.f, d3 = 0.f;
    #pragma unroll
    for (int k = 0; k < 32; k++) {
      float4 hv = *(const float4*)&hs[4 * k];
      d0 += w[4 * k] * hv.x;
      d1 += w[4 * k + 1] * hv.y;
      d2 += w[4 * k + 2] * hv.z;
      d3 += w[4 * k + 3] * hv.w;
    }
    d += (d0 + d1) + (d2 + d3);
    float a = (gate == 2) ? tanhf(d) : (1.f / (1.f + expf(-d)));
    gact[gate][j] = a;
    __syncthreads();
    if (r < 128) {
      cc = gact[1][r] * cc + gact[0][r] * gact[2][r];
      hs[r] = gact[3][r] * tanhf(cc);
    }
    __syncthreads();
  }
  if (r < 128) h_last[r] = hs[r];
}

// ---------- final MLP ----------

__global__ void __launch_bounds__(256) k_mlp(const float* high, const float* hlast, const float* acc,
    const float* W1, const float* b1, const float* lng, const float* lnb,
    const float* W2, const float* b2, const float* W3, const float* b3, float* out) {
  __shared__ float fus[256];
  __shared__ float m1[128];
  __shared__ float m2[64];
  __shared__ float red[4];
  int t = threadIdx.x;
  fus[t] = (t < 128) ? high[t] * (1.f / KK) : hlast[t - 128];
  __syncthreads();
  if (t < 128) {
    float a = b1[t];
    for (int k = 0; k < 256; k++) a += W1[t * 256 + k] * fus[k];
    m1[t] = fmaxf(a, 0.f);
  }
  __syncthreads();
  if (t < 128) {
    float x = m1[t];
    float s = wred(x), s2 = wred(x * x);
    if ((t & 63) == 0) { red[t >> 6] = s; red[2 + (t >> 6)] = s2; }
  }
  __syncthreads();
  if (t < 128) {
    float mean = (red[0] + red[1]) * (1.f / 128.f);
    float var = (red[2] + red[3]) * (1.f / 128.f) - mean * mean;
    float xn = (m1[t] - mean) * rsqrtf(var + 1e-5f) * lng[t] + lnb[t];
    __syncthreads();
    m1[t] = xn;
  } else {
    __syncthreads();
  }
  __syncthreads();
  if (t < 64) {
    float a = b2[t];
    for (int k = 0; k < 128; k++) a += W2[t * 128 + k] * m1[k];
    m2[t] = fmaxf(a, 0.f);
  }
  __syncthreads();
  if (t < 64) {
    float a = W3[t] * m2[t];
    a = wred(a);
    if (t == 0) {
      out[0] = a + b3[0];
      out[1] = -acc[3] * (1.f / NN);
    }
  }
}

// ---------- host ----------

extern "C" void kernel_launch(void* const* d_in, const int* in_sizes, int n_in,
                              void* d_out, int out_size, void* d_ws, size_t ws_size,
                              hipStream_t stream) {
  const float* x_seq = (const float*)d_in[0];
  const float* h0    = (const float*)d_in[1];
  const float* c0    = (const float*)d_in[2];
  const float* ts    = (const float*)d_in[3];
  const float* Wx    = (const float*)d_in[4];
  const float* bx    = (const float*)d_in[5];
  const float* Wh    = (const float*)d_in[6];
  const float* bh    = (const float*)d_in[7];
  const float* lng   = (const float*)d_in[8];
  const float* lnb   = (const float*)d_in[9];
  const float* mapW  = (const float*)d_in[10];
  const float* pv    = (const float*)d_in[11];
  const float* Wih   = (const float*)d_in[12];
  const float* Whh   = (const float*)d_in[13];
  const float* bih   = (const float*)d_in[14];
  const float* bhh   = (const float*)d_in[15];
  const float* W1    = (const float*)d_in[16];
  const float* b1    = (const float*)d_in[17];
  const float* mlng  = (const float*)d_in[18];
  const float* mlnb  = (const float*)d_in[19];
  const float* W2    = (const float*)d_in[20];
  const float* b2    = (const float*)d_in[21];
  const float* W3    = (const float*)d_in[22];
  const float* b3    = (const float*)d_in[23];
  const int*   ei    = (const int*)d_in[24];

  char* wsp = (char*)d_ws;
  size_t off = 0;
  auto carve = [&](size_t bytes) -> char* {
    char* p = wsp + off;
    off += (bytes + 255) & ~(size_t)255;
    return p;
  };
  float* Wcomb   = (float*)carve((size_t)KIN * G4 * 4);
  float* biasC   = (float*)carve(G4 * 4);
  float* mapWr   = (float*)carve(3 * HH * HH * 4);
  int*   degi    = (int*)carve(NN * 4);
  int*   cursor  = (int*)carve(NN * 4);
  int*   rankb   = (int*)carve(NN * 4);
  int*   row_ptr = (int*)carve((NN + 1) * 4);
  float* dis     = (float*)carve(NN * 4);
  float* self_n  = (float*)carve(NN * 4);
  int*   col_src = (int*)carve(EE * 4);
  float* col_w   = (float*)carve(EE * 4);
  float* hA      = (float*)carve((size_t)NN * HH * 4);
  float* cA      = (float*)carve((size_t)NN * HH * 4);
  float* hBC     = (float*)carve((size_t)2 * NN * HH * 4);
  float* cBC     = (float*)carve((size_t)2 * NN * HH * 4);
  float* uagg    = (float*)carve((size_t)2 * NN * KIN * 4);
  float* pre     = (float*)carve((size_t)2 * NN * G4 * 4);
  float* hidden  = (float*)carve((size_t)NN * HH * 4);
  float* sc      = (float*)carve(NN * 4);
  float* sig     = (float*)carve(NN * 4);
  float* acc     = (float*)carve(16 * 4);
  float* high    = (float*)carve(128 * 4);
  float* zpre    = (float*)carve((size_t)TSS * G4 * 4);
  float* hlast   = (float*)carve(128 * 4);

  // setup
  k_setup_w<<<384, 256, 0, stream>>>(Wx, Wh, bx, bh, mapW, Wcomb, biasC, mapWr);
  k_zero<<<40, 256, 0, stream>>>(degi, cursor, rankb, acc, high);
  k_deg<<<625, 256, 0, stream>>>(ei, degi);
  k_norm<<<40, 256, 0, stream>>>(degi, dis, self_n);
  k_scan<<<1, 1024, 0, stream>>>(degi, row_ptr, NN);
  k_fill<<<625, 256, 0, stream>>>(ei, row_ptr, cursor, dis, col_src, col_w);
  k_init_state<<<5000, 256, 0, stream>>>(h0, c0, hA, cA, hBC, cBC);

  // chain A (p=1): t = 0..7
  for (int t = 0; t < TSTEPS; t++) {
    const float* xt = x_seq + (size_t)t * NN * FF;
    k_aggx<<<NN, 192, 0, stream>>>(xt, xt, hA, row_ptr, col_src, col_w, self_n, uagg, NN);
    k_pre<<<dim3(79, 8), 256, 0, stream>>>(uagg, Wcomb, biasC, pre, NN);
    k_gates<<<NN, 128, 0, stream>>>(pre, lng, lnb, hA, cA, NN);
  }
  // chains B (even t) and C (odd t) batched: k = 0..3
  for (int k = 0; k < 4; k++) {
    const float* xe = x_seq + (size_t)(2 * k) * NN * FF;
    const float* xo = x_seq + (size_t)(2 * k + 1) * NN * FF;
    k_aggx<<<2 * NN, 192, 0, stream>>>(xe, xo, hBC, row_ptr, col_src, col_w, self_n, uagg, 2 * NN);
    k_pre<<<dim3(157, 8), 256, 0, stream>>>(uagg, Wcomb, biasC, pre, 2 * NN);
    k_gates<<<2 * NN, 128, 0, stream>>>(pre, lng, lnb, hBC, cBC, 2 * NN);
  }

  // hidden combine + pool
  k_hidden<<<dim3(79, 2), 256, 0, stream>>>(hA, hBC, hBC + (size_t)NN * HH, mapWr, hidden);
  k_vnorm<<<1, 128, 0, stream>>>(pv, acc);
  k_sc<<<250, 256, 0, stream>>>(hidden, pv, acc, sc);
  k_sig<<<40, 256, 0, stream>>>(sc, acc, sig);
  k_rank<<<dim3(40, 10), 256, 0, stream>>>(sc, rankb);
  k_plogs<<<40, 256, 0, stream>>>(sig, rankb, acc);
  k_high<<<79, 128, 0, stream>>>(hidden, sig, rankb, high);

  // LSTM branch: split-K GEMM into `pre` scratch (free after GNN loops), then reduce
  k_zpre2<<<dim3(8, 4, 16), 256, 0, stream>>>(Wih, ts, pre);
  k_zred<<<512, 256, 0, stream>>>(pre, zpre);
  k_lstm<<<1, 512, 0, stream>>>(Whh, bih, bhh, zpre, hlast);

  // head
  k_mlp<<<1, 256, 0, stream>>>(high, hlast, acc, W1, b1, mlng, mlnb, W2, b2, W3, b3,
                               (float*)d_out);
}

// Round 4
// 1607.658 us; speedup vs baseline: 1.6931x; 1.0633x over previous
//
#include <hip/hip_runtime.h>
#include <math.h>

#define NN 10000
#define FF 64
#define TSTEPS 8
#define EE 160000
#define TSS 200
#define HH 128
#define KK 5000
#define G4 512
#define KIN 192
#define EPSF 1e-8f

__device__ inline float wred(float v){
  #pragma unroll
  for (int off = 32; off > 0; off >>= 1) v += __shfl_xor(v, off);
  return v;
}

// ---------- setup kernels ----------

__global__ void k_setup_w(const float* Wx, const float* Wh, const float* bx, const float* bh,
                          const float* mapW, float* Wcomb, float* biasC, float* mapWr) {
  int idx = blockIdx.x * 256 + threadIdx.x;
  if (idx < KIN * G4) {
    int k = idx / G4, gh = idx % G4;
    int g = gh >> 7, hh = gh & 127;
    float v = (k < FF) ? Wx[(g * HH + hh) * FF + k] : Wh[(g * HH + hh) * HH + (k - FF)];
    Wcomb[idx] = v;
  }
  if (idx < G4) biasC[idx] = bx[idx] + bh[idx];
  if (idx < 3 * HH * HH) {
    int s = idx / (HH * HH), r = idx % (HH * HH);
    int d = r / HH, j = r % HH;
    mapWr[idx] = mapW[(s * HH + j) * HH + d];   // mapWr[(s*H+d)][j] = mapW[s][j][d]
  }
}

__global__ void k_zero(int* deg, int* cursor, int* rank, float* acc, float* high) {
  int i = blockIdx.x * 256 + threadIdx.x;
  if (i < NN) { deg[i] = 0; cursor[i] = 0; rank[i] = 0; }
  if (i < 16) acc[i] = 0.f;
  if (i < 128) high[i] = 0.f;
}

__global__ void k_deg(const int* ei, int* deg) {
  int e = blockIdx.x * 256 + threadIdx.x;
  if (e < EE) atomicAdd(&deg[ei[EE + e]], 1);
}

__global__ void k_norm(const int* deg, float* dis, float* self_norm) {
  int n = blockIdx.x * 256 + threadIdx.x;
  if (n < NN) {
    float d = 1.0f + (float)deg[n];
    float r = rsqrtf(d);
    dis[n] = r;
    self_norm[n] = 1.0f / d;
  }
}

__global__ void k_scan(const int* deg, int* row_ptr, int n) {
  __shared__ int buf[1024];
  __shared__ int carry;
  if (threadIdx.x == 0) carry = 0;
  __syncthreads();
  for (int base = 0; base < n; base += 1024) {
    int i = base + threadIdx.x;
    int v = (i < n) ? deg[i] : 0;
    buf[threadIdx.x] = v;
    __syncthreads();
    for (int off = 1; off < 1024; off <<= 1) {
      int t = (threadIdx.x >= off) ? buf[threadIdx.x - off] : 0;
      __syncthreads();
      buf[threadIdx.x] += t;
      __syncthreads();
    }
    if (i < n) row_ptr[i] = carry + buf[threadIdx.x] - v;  // exclusive
    __syncthreads();
    if (threadIdx.x == 1023) carry += buf[1023];
    __syncthreads();
  }
  if (threadIdx.x == 0) row_ptr[n] = carry;
}

__global__ void k_fill(const int* ei, const int* row_ptr, int* cursor, const float* dis,
                       int* col_src, float* col_w) {
  int e = blockIdx.x * 256 + threadIdx.x;
  if (e < EE) {
    int s = ei[e], d = ei[EE + e];
    int pos = row_ptr[d] + atomicAdd(&cursor[d], 1);
    col_src[pos] = s;
    col_w[pos] = dis[s] * dis[d];
  }
}

// hAll/cAll hold 3 chains: rows [0,NN)=A, [NN,2NN)=B, [2NN,3NN)=C
__global__ void k_init3(const float* h0, const float* c0, float* hAll, float* cAll) {
  int i = blockIdx.x * 256 + threadIdx.x;
  if (i < NN * HH) {
    float h = h0[i], c = c0[i];
    hAll[i] = h; hAll[NN * HH + i] = h; hAll[2 * NN * HH + i] = h;
    cAll[i] = c; cAll[NN * HH + i] = c; cAll[2 * NN * HH + i] = c;
  }
}

// ---------- GNN cell kernels ----------

// Precompute x-aggregation for all 8 timesteps: aggX[t*NN+n][64].
// 256 thr = 4 waves, 1 (t,n) pair per wave.  grid = 8NN/4 = 20000.
__global__ void __launch_bounds__(256) k_aggx8(const float* x_seq, const int* row_ptr,
    const int* col_src, const float* col_w, const float* self_n, float* aggX) {
  __shared__ int es[4][64];
  __shared__ float ew[4][64];
  int wv = threadIdx.x >> 6, lane = threadIdx.x & 63;
  int p = blockIdx.x * 4 + wv;          // < 8*NN
  int t = p / NN, n = p - t * NN;
  int e0 = row_ptr[n], e1 = row_ptr[n + 1];
  float acc = 0.f;
  for (int eb = e0; eb < e1; eb += 64) {
    int cnt = min(64, e1 - eb);
    if (lane < cnt) { es[wv][lane] = col_src[eb + lane]; ew[wv][lane] = col_w[eb + lane]; }
    __builtin_amdgcn_wave_barrier();
    for (int i = 0; i < cnt; i++)
      acc += x_seq[((size_t)t * NN + es[wv][i]) * FF + lane] * ew[wv][i];
    __builtin_amdgcn_wave_barrier();
  }
  acc += x_seq[((size_t)t * NN + n) * FF + lane] * self_n[n];
  aggX[(size_t)p * FF + lane] = acc;
}

// h-aggregation for M rows of hAll (chain-aware).  256 thr = 2 nodes x 128 ch.
__global__ void __launch_bounds__(256) k_aggh(const float* hAll, const int* row_ptr,
    const int* col_src, const float* col_w, const float* self_n, float* aggH, int M) {
  __shared__ int es[4][64];
  __shared__ float ew[4][64];
  int w = threadIdx.x >> 6, lane = threadIdx.x & 63;
  int m = blockIdx.x * 2 + (w >> 1);
  if (m >= M) return;
  int ch = (w & 1) * 64 + lane;
  int c = (m >= 2 * NN) ? 2 : (m >= NN ? 1 : 0);
  int n = m - c * NN;
  int e0 = row_ptr[n], e1 = row_ptr[n + 1];
  const float* hb = hAll + (size_t)c * NN * HH;
  float acc = 0.f;
  for (int eb = e0; eb < e1; eb += 64) {
    int cnt = min(64, e1 - eb);
    if (lane < cnt) { es[w][lane] = col_src[eb + lane]; ew[w][lane] = col_w[eb + lane]; }
    __builtin_amdgcn_wave_barrier();
    for (int i = 0; i < cnt; i++)
      acc += hb[(size_t)es[w][i] * HH + ch] * ew[w][i];
    __builtin_amdgcn_wave_barrier();
  }
  acc += hAll[(size_t)m * HH + ch] * self_n[n];
  aggH[(size_t)m * HH + ch] = acc;
}

// Fused cell GEMM + gates + LN + state update.
// BM=64, BN=512(full), K=192 (x-part from aggX by per-row t, h-part from aggH).
// 512 threads = 8 waves; wave ty owns rows ty*8..+8, lane l owns cols l*8..+8.
// Epilogue: LN over g-gate via 16-lane shfl reduce, cross-gate exchange via shfl,
// writes hAll/cAll directly (no pre buffer).
__global__ void __launch_bounds__(512) k_precell(const float* aggX, const float* aggH,
    const float* Wc, const float* biasC, const float* lng, const float* lnb,
    float* hAll, float* cAll, int M, int r) {
  __shared__ __align__(16) float As[8][68];
  __shared__ __align__(16) float Bs[8][512];
  int m0 = blockIdx.x * 64;
  int tid = threadIdx.x;
  int ty = tid >> 6;         // wave = row-group
  int l  = tid & 63;         // lane = col-group
  float acc[8][8] = {};
  // staging mapping
  int srow = tid >> 3, skk = tid & 7;
  int sm = m0 + srow;
  int sc_ = (sm >= 2 * NN) ? 2 : (sm >= NN ? 1 : 0);
  int sn = sm - sc_ * NN;
  int st = (sc_ == 0) ? r : (2 * r + sc_ - 1);
  const float* xsrc = aggX + ((size_t)st * NN + sn) * FF;
  const float* hsrc = aggH + (size_t)sm * HH;
  bool srowok = sm < M;
  for (int kc = 0; kc < 24; kc++) {
    float av = 0.f;
    if (srowok) av = (kc < 8) ? xsrc[kc * 8 + skk] : hsrc[(kc - 8) * 8 + skk];
    As[skk][srow] = av;
    {
      const float* wr = Wc + (size_t)(kc * 8 + ty) * G4 + l * 8;
      *(float4*)&Bs[ty][l * 8]     = *(const float4*)wr;
      *(float4*)&Bs[ty][l * 8 + 4] = *(const float4*)(wr + 4);
    }
    __syncthreads();
    #pragma unroll
    for (int k = 0; k < 8; k++) {
      float4 a0 = *(const float4*)&As[k][ty * 8];
      float4 a1 = *(const float4*)&As[k][ty * 8 + 4];
      float4 b0 = *(const float4*)&Bs[k][l * 8];
      float4 b1 = *(const float4*)&Bs[k][l * 8 + 4];
      const float aa[8] = {a0.x, a0.y, a0.z, a0.w, a1.x, a1.y, a1.z, a1.w};
      const float bb[8] = {b0.x, b0.y, b0.z, b0.w, b1.x, b1.y, b1.z, b1.w};
      #pragma unroll
      for (int rr = 0; rr < 8; rr++)
        #pragma unroll
        for (int cc2 = 0; cc2 < 8; cc2++)
          acc[rr][cc2] += aa[rr] * bb[cc2];
    }
    __syncthreads();
  }
  // epilogue
  int gate = l >> 4;
  int jb = (l & 15) * 8;     // col within gate
  int base = l & 15;
  float bias8[8], lg8[8], lb8[8];
  *(float4*)&bias8[0] = *(const float4*)(biasC + l * 8);
  *(float4*)&bias8[4] = *(const float4*)(biasC + l * 8 + 4);
  *(float4*)&lg8[0] = *(const float4*)(lng + jb);
  *(float4*)&lg8[4] = *(const float4*)(lng + jb + 4);
  *(float4*)&lb8[0] = *(const float4*)(lnb + jb);
  *(float4*)&lb8[4] = *(const float4*)(lnb + jb + 4);
  #pragma unroll
  for (int rr = 0; rr < 8; rr++) {
    int m = m0 + ty * 8 + rr;
    float xv[8];
    float s1 = 0.f, s2 = 0.f;
    #pragma unroll
    for (int cc2 = 0; cc2 < 8; cc2++) {
      xv[cc2] = acc[rr][cc2] + bias8[cc2];
      s1 += xv[cc2]; s2 += xv[cc2] * xv[cc2];
    }
    // reduce over the 16-lane gate group (masks 1,2,4,8 stay in group)
    #pragma unroll
    for (int msk = 1; msk <= 8; msk <<= 1) {
      s1 += __shfl_xor(s1, msk);
      s2 += __shfl_xor(s2, msk);
    }
    float mean = s1 * (1.f / 128.f);
    float var = s2 * (1.f / 128.f) - mean * mean;
    float inv = rsqrtf(var + 1e-5f);
    float act[8];
    if (gate == 3) {
      #pragma unroll
      for (int cc2 = 0; cc2 < 8; cc2++)
        act[cc2] = tanhf((xv[cc2] - mean) * inv * lg8[cc2] + lb8[cc2]);
    } else {
      #pragma unroll
      for (int cc2 = 0; cc2 < 8; cc2++)
        act[cc2] = fmaxf(xv[cc2], 0.f);
    }
    float ffv[8], oov[8], ggv[8];
    #pragma unroll
    for (int cc2 = 0; cc2 < 8; cc2++) {
      float av = act[cc2];
      ffv[cc2] = __shfl(av, base + 16);
      oov[cc2] = __shfl(av, base + 32);
      ggv[cc2] = __shfl(av, base + 48);
    }
    if (gate == 0 && m < M) {
      float* cp = cAll + (size_t)m * HH + jb;
      float* hp = hAll + (size_t)m * HH + jb;
      float cold[8];
      *(float4*)&cold[0] = *(const float4*)cp;
      *(float4*)&cold[4] = *(const float4*)(cp + 4);
      float cnew[8], hnew[8];
      #pragma unroll
      for (int cc2 = 0; cc2 < 8; cc2++) {
        cnew[cc2] = ffv[cc2] * cold[cc2] + act[cc2] * ggv[cc2];
        hnew[cc2] = oov[cc2] * tanhf(cnew[cc2]);
      }
      *(float4*)cp       = *(float4*)&cnew[0];
      *(float4*)(cp + 4) = *(float4*)&cnew[4];
      *(float4*)hp       = *(float4*)&hnew[0];
      *(float4*)(hp + 4) = *(float4*)&hnew[4];
    }
  }
}

// hidden = hA@W0^T + hB@W1^T + hC@W2^T  via K=384 GEMM.  BM=128, BN=64.
__global__ void __launch_bounds__(256) k_hidden(const float* hA, const float* hB, const float* hC,
                                                const float* Wr, float* out) {
  __shared__ __align__(16) float As[8][128];
  __shared__ __align__(16) float Bs[8][64];
  int m0 = blockIdx.x * 128, n0 = blockIdx.y * 64;
  int tid = threadIdx.x;
  int tx = tid & 15, ty = tid >> 4;
  float acc[8][4] = {};
  for (int kc = 0; kc < 48; kc++) {
    int k0 = kc * 8;
    const float* S = (k0 < 128) ? hA : (k0 < 256 ? hB : hC);
    int koff = k0 & 127;
    {
      int ml = tid >> 1, kq = (tid & 1) * 4;
      int m = m0 + ml;
      float4 v = make_float4(0.f, 0.f, 0.f, 0.f);
      if (m < NN) v = *(const float4*)(S + (size_t)m * HH + koff + kq);
      As[kq + 0][ml] = v.x; As[kq + 1][ml] = v.y; As[kq + 2][ml] = v.z; As[kq + 3][ml] = v.w;
    }
    #pragma unroll
    for (int q = 0; q < 2; q++) {
      int e = tid + q * 256;
      int kl = e >> 6, nl = e & 63;
      Bs[kl][nl] = Wr[(size_t)(k0 + kl) * HH + n0 + nl];
    }
    __syncthreads();
    #pragma unroll
    for (int k = 0; k < 8; k++) {
      float4 a0 = *(const float4*)&As[k][ty * 4];
      float4 a1 = *(const float4*)&As[k][64 + ty * 4];
      float4 b0 = *(const float4*)&Bs[k][tx * 4];
      const float av0[4] = {a0.x, a0.y, a0.z, a0.w};
      const float av1[4] = {a1.x, a1.y, a1.z, a1.w};
      const float bv[4] = {b0.x, b0.y, b0.z, b0.w};
      #pragma unroll
      for (int i = 0; i < 4; i++)
        #pragma unroll
        for (int j = 0; j < 4; j++) {
          acc[i][j] += av0[i] * bv[j];
          acc[4 + i][j] += av1[i] * bv[j];
        }
    }
    __syncthreads();
  }
  #pragma unroll
  for (int g = 0; g < 2; g++)
    #pragma unroll
    for (int i = 0; i < 4; i++) {
      int m = m0 + g * 64 + ty * 4 + i;
      if (m < NN) {
        float4 r;
        r.x = acc[g * 4 + i][0]; r.y = acc[g * 4 + i][1];
        r.z = acc[g * 4 + i][2]; r.w = acc[g * 4 + i][3];
        *(float4*)(out + (size_t)m * HH + n0 + tx * 4) = r;
      }
    }
}

// ---------- pool kernels ----------

__global__ void k_vnorm(const float* pv, float* acc) {
  int t = threadIdx.x;  // 128
  float v = pv[t];
  float s = wred(v * v);
  __shared__ float sh[2];
  if ((t & 63) == 0) sh[t >> 6] = s;
  __syncthreads();
  if (t == 0) acc[0] = 1.0f / (sqrtf(sh[0] + sh[1]) + EPSF);
}

// grid-stride: per-block partial reduce, 2 atomics per block.
__global__ void __launch_bounds__(256) k_sc(const float* hidden, const float* pv, float* acc,
                                            float* sc) {
  int wid = threadIdx.x >> 6, lane = threadIdx.x & 63;
  float2 vv = *(const float2*)(pv + lane * 2);
  float inv = acc[0];
  float ls = 0.f, ls2 = 0.f;
  for (int n = blockIdx.x * 4 + wid; n < NN; n += gridDim.x * 4) {
    float2 hv = *(const float2*)(hidden + (size_t)n * HH + lane * 2);
    float dot = hv.x * vv.x + hv.y * vv.y;
    dot = wred(dot);
    if (lane == 0) {
      float s = dot * inv;
      sc[n] = s;
      ls += s;
      ls2 += s * s;
    }
  }
  __shared__ float sh[8];
  if (lane == 0) { sh[wid] = ls; sh[4 + wid] = ls2; }
  __syncthreads();
  if (threadIdx.x == 0) {
    atomicAdd(&acc[1], sh[0] + sh[1] + sh[2] + sh[3]);
    atomicAdd(&acc[2], sh[4] + sh[5] + sh[6] + sh[7]);
  }
}

__global__ void k_sig(const float* sc, const float* acc, float* sig) {
  int n = blockIdx.x * 256 + threadIdx.x;
  if (n < NN) {
    float mean = acc[1] * (1.f / NN);
    float var = acc[2] * (1.f / NN) - mean * mean;
    float sd = sqrtf(fmaxf(var, 0.f)) + EPSF;
    float z = (sc[n] - mean) / sd;
    sig[n] = 1.f / (1.f + expf(-z));
  }
}

__global__ void __launch_bounds__(256) k_rank(const float* sc, int* rank) {
  __shared__ float sj[1024];
  int i = blockIdx.x * 256 + threadIdx.x;
  int j0 = blockIdx.y * 1024;
  for (int k = threadIdx.x; k < 1024; k += 256) {
    int j = j0 + k;
    sj[k] = (j < NN) ? sc[j] : -3.0e38f;
  }
  __syncthreads();
  float si = (i < NN) ? sc[i] : 0.f;
  int jmax = NN - j0; if (jmax > 1024) jmax = 1024;
  int cnt = 0;
  for (int k = 0; k < jmax; k++) {
    float v = sj[k];
    int j = j0 + k;
    cnt += (v > si) || (v == si && j < i);
  }
  if (i < NN && cnt) atomicAdd(&rank[i], cnt);
}

__global__ void __launch_bounds__(256) k_plogs(const float* sig, const int* rank, float* acc) {
  int i = blockIdx.x * 256 + threadIdx.x;
  float v = 0.f;
  if (i < NN) {
    float s = sig[i];
    v = (rank[i] < KK) ? logf(s + EPSF) : logf(1.f - s + EPSF);
  }
  v = wred(v);
  __shared__ float sh[4];
  if ((threadIdx.x & 63) == 0) sh[threadIdx.x >> 6] = v;
  __syncthreads();
  if (threadIdx.x == 0) atomicAdd(&acc[3], sh[0] + sh[1] + sh[2] + sh[3]);
}

__global__ void __launch_bounds__(128) k_high(const float* hidden, const float* sig,
                                              const int* rank, float* high) {
  int ch = threadIdx.x;
  int n0 = blockIdx.x * 128;
  float a = 0.f;
  for (int q = 0; q < 128; q++) {
    int n = n0 + q;
    if (n >= NN) break;
    if (rank[n] < KK) a += hidden[(size_t)n * HH + ch] * sig[n];
  }
  atomicAdd(&high[ch], a);
}

// ---------- LSTM kernels ----------

// Split-K NT-GEMM: part[ks][r][t] = sum_{k in split ks} Wih[r][k] * ts[t][k]
__global__ void __launch_bounds__(256) k_zpre2(const float* Wih, const float* ts, float* part) {
  __shared__ __align__(16) float As[16][64];
  __shared__ __align__(16) float Bs[16][64];
  int m0 = blockIdx.x * 64;
  int n0 = blockIdx.y * 64;
  int ks = blockIdx.z;
  int kbeg = ks * 624;
  int kend = (ks == 15) ? NN : kbeg + 624;
  int tid = threadIdx.x;
  int tx = tid & 15, ty = tid >> 4;
  int lm = tid >> 2, kq = (tid & 3) * 4;
  bool bvalid = (n0 + lm) < TSS;
  float acc[4][4] = {};
  for (int k0 = kbeg; k0 < kend; k0 += 16) {
    {
      float4 v = *(const float4*)(Wih + (size_t)(m0 + lm) * NN + k0 + kq);
      As[kq + 0][lm] = v.x; As[kq + 1][lm] = v.y; As[kq + 2][lm] = v.z; As[kq + 3][lm] = v.w;
    }
    {
      float4 v = make_float4(0.f, 0.f, 0.f, 0.f);
      if (bvalid) v = *(const float4*)(ts + (size_t)(n0 + lm) * NN + k0 + kq);
      Bs[kq + 0][lm] = v.x; Bs[kq + 1][lm] = v.y; Bs[kq + 2][lm] = v.z; Bs[kq + 3][lm] = v.w;
    }
    __syncthreads();
    #pragma unroll
    for (int k = 0; k < 16; k++) {
      float4 a0 = *(const float4*)&As[k][ty * 4];
      float4 b0 = *(const float4*)&Bs[k][tx * 4];
      const float av[4] = {a0.x, a0.y, a0.z, a0.w};
      const float bv[4] = {b0.x, b0.y, b0.z, b0.w};
      #pragma unroll
      for (int i = 0; i < 4; i++)
        #pragma unroll
        for (int j = 0; j < 4; j++)
          acc[i][j] += av[i] * bv[j];
    }
    __syncthreads();
  }
  float* pd = part + ((size_t)ks << 17);
  #pragma unroll
  for (int i = 0; i < 4; i++) {
    float4 r4 = make_float4(acc[i][0], acc[i][1], acc[i][2], acc[i][3]);
    *(float4*)(pd + (size_t)(m0 + ty * 4 + i) * 256 + n0 + tx * 4) = r4;
  }
}

__global__ void __launch_bounds__(256) k_zred(const float* part, float* zpre) {
  int r = blockIdx.x;
  int t = threadIdx.x;
  int base = r * 256 + t;
  float s = 0.f;
  #pragma unroll
  for (int k = 0; k < 16; k++) s += part[(k << 17) + base];
  if (t < TSS) zpre[(size_t)t * G4 + r] = s;
}

// serial recurrence, split-K across waves: wave w owns k-slice [16w,16w+16).
// Per step per wave: 4 broadcast b128 reads of hs (vs 32), partial reduce via LDS.
__global__ void __launch_bounds__(512) k_lstm(const float* Whh, const float* bih, const float* bhh,
                                              const float* zpre, float* h_last) {
  __shared__ __align__(16) float hs[128];
  __shared__ float part[8][512];
  __shared__ float gact[512];
  int tid = threadIdx.x;
  int w = tid >> 6, l = tid & 63;
  float wreg[128];   // wreg[i*16+k'] = Whh[l+64i][16w+k']
  #pragma unroll
  for (int i = 0; i < 8; i++)
    #pragma unroll
    for (int q = 0; q < 4; q++) {
      float4 v = *(const float4*)(Whh + (size_t)(l + 64 * i) * HH + 16 * w + 4 * q);
      wreg[i * 16 + 4 * q + 0] = v.x; wreg[i * 16 + 4 * q + 1] = v.y;
      wreg[i * 16 + 4 * q + 2] = v.z; wreg[i * 16 + 4 * q + 3] = v.w;
    }
  float bias = bih[tid] + bhh[tid];
  if (tid < 128) hs[tid] = 0.f;
  float cc = 0.f;
  __syncthreads();
  for (int t = 0; t < TSS; t++) {
    float hv[16];
    #pragma unroll
    for (int q = 0; q < 4; q++) *(float4*)&hv[4 * q] = *(const float4*)&hs[16 * w + 4 * q];
    #pragma unroll
    for (int i = 0; i < 8; i++) {
      float p = 0.f;
      #pragma unroll
      for (int k = 0; k < 16; k++) p += wreg[i * 16 + k] * hv[k];
      part[w][l + 64 * i] = p;
    }
    __syncthreads();
    float d = bias + zpre[(size_t)t * G4 + tid];
    #pragma unroll
    for (int q = 0; q < 8; q++) d += part[q][tid];
    float a = ((tid >> 7) == 2) ? tanhf(d) : (1.f / (1.f + expf(-d)));
    gact[tid] = a;
    __syncthreads();
    if (tid < 128) {
      cc = gact[128 + tid] * cc + gact[tid] * gact[256 + tid];
      hs[tid] = gact[384 + tid] * tanhf(cc);
    }
    __syncthreads();
  }
  if (tid < 128) h_last[tid] = hs[tid];
}

// ---------- final MLP ----------

__global__ void __launch_bounds__(256) k_mlp(const float* high, const float* hlast, const float* acc,
    const float* W1, const float* b1, const float* lng, const float* lnb,
    const float* W2, const float* b2, const float* W3, const float* b3, float* out) {
  __shared__ float fus[256];
  __shared__ float m1[128];
  __shared__ float m2[64];
  __shared__ float red[4];
  int t = threadIdx.x;
  fus[t] = (t < 128) ? high[t] * (1.f / KK) : hlast[t - 128];
  __syncthreads();
  if (t < 128) {
    float a = b1[t];
    for (int k = 0; k < 256; k++) a += W1[t * 256 + k] * fus[k];
    m1[t] = fmaxf(a, 0.f);
  }
  __syncthreads();
  if (t < 128) {
    float x = m1[t];
    float s = wred(x), s2 = wred(x * x);
    if ((t & 63) == 0) { red[t >> 6] = s; red[2 + (t >> 6)] = s2; }
  }
  __syncthreads();
  if (t < 128) {
    float mean = (red[0] + red[1]) * (1.f / 128.f);
    float var = (red[2] + red[3]) * (1.f / 128.f) - mean * mean;
    float xn = (m1[t] - mean) * rsqrtf(var + 1e-5f) * lng[t] + lnb[t];
    __syncthreads();
    m1[t] = xn;
  } else {
    __syncthreads();
  }
  __syncthreads();
  if (t < 64) {
    float a = b2[t];
    for (int k = 0; k < 128; k++) a += W2[t * 128 + k] * m1[k];
    m2[t] = fmaxf(a, 0.f);
  }
  __syncthreads();
  if (t < 64) {
    float a = W3[t] * m2[t];
    a = wred(a);
    if (t == 0) {
      out[0] = a + b3[0];
      out[1] = -acc[3] * (1.f / NN);
    }
  }
}

// ---------- host ----------

extern "C" void kernel_launch(void* const* d_in, const int* in_sizes, int n_in,
                              void* d_out, int out_size, void* d_ws, size_t ws_size,
                              hipStream_t stream) {
  const float* x_seq = (const float*)d_in[0];
  const float* h0    = (const float*)d_in[1];
  const float* c0    = (const float*)d_in[2];
  const float* ts    = (const float*)d_in[3];
  const float* Wx    = (const float*)d_in[4];
  const float* bx    = (const float*)d_in[5];
  const float* Wh    = (const float*)d_in[6];
  const float* bh    = (const float*)d_in[7];
  const float* lng   = (const float*)d_in[8];
  const float* lnb   = (const float*)d_in[9];
  const float* mapW  = (const float*)d_in[10];
  const float* pv    = (const float*)d_in[11];
  const float* Wih   = (const float*)d_in[12];
  const float* Whh   = (const float*)d_in[13];
  const float* bih   = (const float*)d_in[14];
  const float* bhh   = (const float*)d_in[15];
  const float* W1    = (const float*)d_in[16];
  const float* b1    = (const float*)d_in[17];
  const float* mlng  = (const float*)d_in[18];
  const float* mlnb  = (const float*)d_in[19];
  const float* W2    = (const float*)d_in[20];
  const float* b2    = (const float*)d_in[21];
  const float* W3    = (const float*)d_in[22];
  const float* b3    = (const float*)d_in[23];
  const int*   ei    = (const int*)d_in[24];

  char* wsp = (char*)d_ws;
  size_t off = 0;
  auto carve = [&](size_t bytes) -> char* {
    char* p = wsp + off;
    off += (bytes + 255) & ~(size_t)255;
    return p;
  };
  float* Wcomb   = (float*)carve((size_t)KIN * G4 * 4);
  float* biasC   = (float*)carve(G4 * 4);
  float* mapWr   = (float*)carve(3 * HH * HH * 4);
  int*   degi    = (int*)carve(NN * 4);
  int*   cursor  = (int*)carve(NN * 4);
  int*   rankb   = (int*)carve(NN * 4);
  int*   row_ptr = (int*)carve((NN + 1) * 4);
  float* dis     = (float*)carve(NN * 4);
  float* self_n  = (float*)carve(NN * 4);
  int*   col_src = (int*)carve(EE * 4);
  float* col_w   = (float*)carve(EE * 4);
  float* hAll    = (float*)carve((size_t)3 * NN * HH * 4);
  float* cAll    = (float*)carve((size_t)3 * NN * HH * 4);
  float* aggX    = (float*)carve((size_t)8 * NN * FF * 4);
  float* aggH    = (float*)carve((size_t)3 * NN * HH * 4);   // reused as zpre2 partials
  float* hidden  = (float*)carve((size_t)NN * HH * 4);
  float* sc      = (float*)carve(NN * 4);
  float* sig     = (float*)carve(NN * 4);
  float* acc     = (float*)carve(16 * 4);
  float* high    = (float*)carve(128 * 4);
  float* zpre    = (float*)carve((size_t)TSS * G4 * 4);
  float* hlast   = (float*)carve(128 * 4);

  // setup
  k_setup_w<<<384, 256, 0, stream>>>(Wx, Wh, bx, bh, mapW, Wcomb, biasC, mapWr);
  k_zero<<<40, 256, 0, stream>>>(degi, cursor, rankb, acc, high);
  k_deg<<<625, 256, 0, stream>>>(ei, degi);
  k_norm<<<40, 256, 0, stream>>>(degi, dis, self_n);
  k_scan<<<1, 1024, 0, stream>>>(degi, row_ptr, NN);
  k_fill<<<625, 256, 0, stream>>>(ei, row_ptr, cursor, dis, col_src, col_w);
  k_init3<<<5000, 256, 0, stream>>>(h0, c0, hAll, cAll);

  // precompute x-aggregation for all 8 timesteps
  k_aggx8<<<20000, 256, 0, stream>>>(x_seq, row_ptr, col_src, col_w, self_n, aggX);

  // 8 fused rounds: rounds 0-3 run chains A+B+C (M=3NN), rounds 4-7 chain A only
  for (int r = 0; r < TSTEPS; r++) {
    int M = (r < 4) ? 3 * NN : NN;
    k_aggh<<<M / 2, 256, 0, stream>>>(hAll, row_ptr, col_src, col_w, self_n, aggH, M);
    k_precell<<<(M + 63) / 64, 512, 0, stream>>>(aggX, aggH, Wcomb, biasC, lng, lnb,
                                                 hAll, cAll, M, r);
  }

  // hidden combine + pool
  k_hidden<<<dim3(79, 2), 256, 0, stream>>>(hAll, hAll + (size_t)NN * HH,
                                            hAll + (size_t)2 * NN * HH, mapWr, hidden);
  k_vnorm<<<1, 128, 0, stream>>>(pv, acc);
  k_sc<<<250, 256, 0, stream>>>(hidden, pv, acc, sc);
  k_sig<<<40, 256, 0, stream>>>(sc, acc, sig);
  k_rank<<<dim3(40, 10), 256, 0, stream>>>(sc, rankb);
  k_plogs<<<40, 256, 0, stream>>>(sig, rankb, acc);
  k_high<<<79, 128, 0, stream>>>(hidden, sig, rankb, high);

  // LSTM branch: split-K GEMM into aggH scratch (free after GNN rounds), reduce, recur
  k_zpre2<<<dim3(8, 4, 16), 256, 0, stream>>>(Wih, ts, aggH);
  k_zred<<<512, 256, 0, stream>>>(aggH, zpre);
  k_lstm<<<1, 512, 0, stream>>>(Whh, bih, bhh, zpre, hlast);

  // head
  k_mlp<<<1, 256, 0, stream>>>(high, hlast, acc, W1, b1, mlng, mlnb, W2, b2, W3, b3,
                               (float*)d_out);
}

// Round 5
// 1218.647 us; speedup vs baseline: 2.2335x; 1.3192x over previous
//
#include <hip/hip_runtime.h>
#include <hip/hip_bf16.h>
#include <math.h>

#define NN 10000
#define FF 64
#define TSTEPS 8
#define EE 160000
#define TSS 200
#define HH 128
#define KK 5000
#define G4 512
#define KIN 192
#define EPSF 1e-8f

typedef __attribute__((ext_vector_type(8))) short short8v;
typedef __attribute__((ext_vector_type(4))) float f32x4;

__device__ inline float wred(float v){
  #pragma unroll
  for (int off = 32; off > 0; off >>= 1) v += __shfl_xor(v, off);
  return v;
}

__device__ inline unsigned short f2b(float f) {
  union { __hip_bfloat16 h; unsigned short u; } cv;
  cv.h = __float2bfloat16(f);
  return cv.u;
}
__device__ inline float b2f(unsigned short u) {
  return __uint_as_float(((unsigned int)u) << 16);
}

// ---------- setup kernels ----------

// biasC, mapWr, and the MFMA-fragment-ordered bf16 weight table Wfrag.
// Wfrag[((ks*32+ntg)*64+l)*8+jj] = bf16(W[k=ks*32+(l>>4)*8+jj][col=ntg*16+(l&15)])
__global__ void k_setup_w(const float* Wx, const float* Wh, const float* bx, const float* bh,
                          const float* mapW, unsigned short* Wfrag, float* biasC, float* mapWr) {
  int idx = blockIdx.x * 256 + threadIdx.x;   // grid 384*256 = 98304 = 6*32*64*8
  {
    int jj = idx & 7, l = (idx >> 3) & 63, ntg = (idx >> 9) & 31, ks = idx >> 14;
    int k = ks * 32 + ((l >> 4) << 3) + jj;
    int gh = ntg * 16 + (l & 15);
    int g = gh >> 7, hh = gh & 127;
    float v = (k < FF) ? Wx[(g * HH + hh) * FF + k] : Wh[(g * HH + hh) * HH + (k - FF)];
    Wfrag[idx] = f2b(v);
  }
  if (idx < G4) biasC[idx] = bx[idx] + bh[idx];
  if (idx < 3 * HH * HH) {
    int s = idx / (HH * HH), r = idx % (HH * HH);
    int d = r / HH, j = r % HH;
    mapWr[idx] = mapW[(s * HH + j) * HH + d];
  }
}

__global__ void k_zero(int* deg, int* cursor, int* rank, float* acc, float* high) {
  int i = blockIdx.x * 256 + threadIdx.x;
  if (i < NN) { deg[i] = 0; cursor[i] = 0; rank[i] = 0; }
  if (i < 16) acc[i] = 0.f;
  if (i < 128) high[i] = 0.f;
}

__global__ void k_deg(const int* ei, int* deg) {
  int e = blockIdx.x * 256 + threadIdx.x;
  if (e < EE) atomicAdd(&deg[ei[EE + e]], 1);
}

__global__ void k_norm(const int* deg, float* dis, float* self_norm) {
  int n = blockIdx.x * 256 + threadIdx.x;
  if (n < NN) {
    float d = 1.0f + (float)deg[n];
    dis[n] = rsqrtf(d);
    self_norm[n] = 1.0f / d;
  }
}

__global__ void k_scan(const int* deg, int* row_ptr, int n) {
  __shared__ int buf[1024];
  __shared__ int carry;
  if (threadIdx.x == 0) carry = 0;
  __syncthreads();
  for (int base = 0; base < n; base += 1024) {
    int i = base + threadIdx.x;
    int v = (i < n) ? deg[i] : 0;
    buf[threadIdx.x] = v;
    __syncthreads();
    for (int off = 1; off < 1024; off <<= 1) {
      int t = (threadIdx.x >= off) ? buf[threadIdx.x - off] : 0;
      __syncthreads();
      buf[threadIdx.x] += t;
      __syncthreads();
    }
    if (i < n) row_ptr[i] = carry + buf[threadIdx.x] - v;
    __syncthreads();
    if (threadIdx.x == 1023) carry += buf[1023];
    __syncthreads();
  }
  if (threadIdx.x == 0) row_ptr[n] = carry;
}

__global__ void k_fill(const int* ei, const int* row_ptr, int* cursor, const float* dis,
                       int* col_src, float* col_w) {
  int e = blockIdx.x * 256 + threadIdx.x;
  if (e < EE) {
    int s = ei[e], d = ei[EE + e];
    int pos = row_ptr[d] + atomicAdd(&cursor[d], 1);
    col_src[pos] = s;
    col_w[pos] = dis[s] * dis[d];
  }
}

// hAll bf16 (3 chains), cAll fp32
__global__ void k_init3(const float* h0, const float* c0, unsigned short* hAll, float* cAll) {
  int i = blockIdx.x * 256 + threadIdx.x;
  if (i < NN * HH) {
    unsigned short h = f2b(h0[i]);
    float c = c0[i];
    hAll[i] = h; hAll[NN * HH + i] = h; hAll[2 * NN * HH + i] = h;
    cAll[i] = c; cAll[NN * HH + i] = c; cAll[2 * NN * HH + i] = c;
  }
}

// cast x_seq to bf16 once (halves gather traffic in k_aggx8)
__global__ void k_xcast(const float* x, unsigned short* xb) {
  int i = blockIdx.x * 256 + threadIdx.x;   // 1,280,000 float4s
  float4 v = *(const float4*)(x + (size_t)i * 4);
  ushort4 u;
  u.x = f2b(v.x); u.y = f2b(v.y); u.z = f2b(v.z); u.w = f2b(v.w);
  *(ushort4*)(xb + (size_t)i * 4) = u;
}

// ---------- GNN cell kernels ----------

// x-aggregation for all 8 timesteps: aggX[t*NN+n][64] bf16.
__global__ void __launch_bounds__(256) k_aggx8(const unsigned short* xb, const int* row_ptr,
    const int* col_src, const float* col_w, const float* self_n, unsigned short* aggX) {
  __shared__ int es[4][64];
  __shared__ float ew[4][64];
  int wv = threadIdx.x >> 6, lane = threadIdx.x & 63;
  int p = blockIdx.x * 4 + wv;          // < 8*NN
  int t = p / NN, n = p - t * NN;
  int e0 = row_ptr[n], e1 = row_ptr[n + 1];
  float acc = 0.f;
  for (int eb = e0; eb < e1; eb += 64) {
    int cnt = min(64, e1 - eb);
    if (lane < cnt) { es[wv][lane] = col_src[eb + lane]; ew[wv][lane] = col_w[eb + lane]; }
    __builtin_amdgcn_wave_barrier();
    for (int i = 0; i < cnt; i++)
      acc += b2f(xb[((size_t)t * NN + es[wv][i]) * FF + lane]) * ew[wv][i];
    __builtin_amdgcn_wave_barrier();
  }
  acc += b2f(xb[((size_t)t * NN + n) * FF + lane]) * self_n[n];
  aggX[(size_t)p * FF + lane] = f2b(acc);
}

// h-aggregation (bf16 in/out), M rows of hAll.
__global__ void __launch_bounds__(256) k_aggh(const unsigned short* hAll, const int* row_ptr,
    const int* col_src, const float* col_w, const float* self_n, unsigned short* aggH, int M) {
  __shared__ int es[4][64];
  __shared__ float ew[4][64];
  int w = threadIdx.x >> 6, lane = threadIdx.x & 63;
  int m = blockIdx.x * 2 + (w >> 1);
  if (m >= M) return;
  int ch = (w & 1) * 64 + lane;
  int c = (m >= 2 * NN) ? 2 : (m >= NN ? 1 : 0);
  int n = m - c * NN;
  int e0 = row_ptr[n], e1 = row_ptr[n + 1];
  const unsigned short* hb = hAll + (size_t)c * NN * HH;
  float acc = 0.f;
  for (int eb = e0; eb < e1; eb += 64) {
    int cnt = min(64, e1 - eb);
    if (lane < cnt) { es[w][lane] = col_src[eb + lane]; ew[w][lane] = col_w[eb + lane]; }
    __builtin_amdgcn_wave_barrier();
    for (int i = 0; i < cnt; i++)
      acc += b2f(hb[(size_t)es[w][i] * HH + ch]) * ew[w][i];
    __builtin_amdgcn_wave_barrier();
  }
  acc += b2f(hAll[(size_t)m * HH + ch]) * self_n[n];
  aggH[(size_t)m * HH + ch] = f2b(acc);
}

// MFMA bf16 cell GEMM: pre[M x 512] (bf16) = [aggX|aggH](M x 192) @ W(192x512) + bias.
// BM=64, BN=256, 512 thr = 8 waves (wm 0..1 x wn 0..3); 16x16x32 fragments.
// A staged in LDS in fragment order (per-lane contiguous 16B -> conflict-free b128);
// B read from the pre-permuted global Wfrag table (L2-hot, 196KB).
__global__ void __launch_bounds__(512) k_premm(const unsigned short* aggX,
    const unsigned short* aggH, const unsigned short* Wfrag, const float* biasC,
    unsigned short* preB, int M, int r) {
  __shared__ unsigned short Af[1536 * 8];   // [mt 0..3][ks 0..5][lane 0..63][8] = 24KB
  int m0 = blockIdx.x * 64;
  int n0 = blockIdx.y * 256;
  int tid = threadIdx.x;
  int l = tid & 63, wid = tid >> 6;
  int wm = wid >> 2, wn = wid & 3;
  #pragma unroll
  for (int q = 0; q < 3; q++) {
    int chunk = tid + q * 512;
    int mt = chunk / 384, rem = chunk - mt * 384;
    int ks = rem >> 6, cl = rem & 63;
    int row = m0 + mt * 16 + (cl & 15);
    int kk = ks * 32 + ((cl >> 4) << 3);
    short8v v = {};
    if (row < M) {
      const unsigned short* src;
      if (kk < FF) {
        int ch = (row >= 2 * NN) ? 2 : (row >= NN ? 1 : 0);
        int n = row - ch * NN;
        int t = (ch == 0) ? r : (2 * r + ch - 1);
        src = aggX + ((size_t)t * NN + n) * FF + kk;
      } else {
        src = aggH + (size_t)row * HH + (kk - FF);
      }
      v = *(const short8v*)src;
    }
    *(short8v*)&Af[chunk * 8] = v;
  }
  __syncthreads();
  f32x4 acc[2][4];
  #pragma unroll
  for (int i = 0; i < 2; i++)
    #pragma unroll
    for (int j = 0; j < 4; j++) acc[i][j] = (f32x4){0.f, 0.f, 0.f, 0.f};
  #pragma unroll
  for (int ks = 0; ks < 6; ks++) {
    short8v a0 = *(const short8v*)&Af[(((wm * 2 + 0) * 6 + ks) * 64 + l) * 8];
    short8v a1 = *(const short8v*)&Af[(((wm * 2 + 1) * 6 + ks) * 64 + l) * 8];
    #pragma unroll
    for (int j = 0; j < 4; j++) {
      int ntg = (n0 >> 4) + wn * 4 + j;
      short8v b = *(const short8v*)(Wfrag + (((size_t)ks * 32 + ntg) * 64 + l) * 8);
      acc[0][j] = __builtin_amdgcn_mfma_f32_16x16x32_bf16(a0, b, acc[0][j], 0, 0, 0);
      acc[1][j] = __builtin_amdgcn_mfma_f32_16x16x32_bf16(a1, b, acc[1][j], 0, 0, 0);
    }
  }
  // C/D layout: col = lane&15, row = (lane>>4)*4 + reg  [verified mapping]
  #pragma unroll
  for (int i = 0; i < 2; i++)
    #pragma unroll
    for (int j = 0; j < 4; j++) {
      int colg = n0 + wn * 64 + j * 16 + (l & 15);
      float bv = biasC[colg];
      #pragma unroll
      for (int rg = 0; rg < 4; rg++) {
        int row = m0 + wm * 32 + i * 16 + ((l >> 4) * 4) + rg;
        if (row < M) preB[(size_t)row * G4 + colg] = f2b(acc[i][j][rg] + bv);
      }
    }
}

// gates + LN + state update (bf16 pre/h, fp32 c/math).  grid = M blocks, 128 threads.
__global__ void __launch_bounds__(128) k_gates(const unsigned short* preB, const float* lng,
                                               const float* lnb, unsigned short* h, float* c,
                                               int M) {
  int b = blockIdx.x;
  int j = threadIdx.x;
  const unsigned short* p = preB + (size_t)b * G4;
  float iv = b2f(p[j]), fv = b2f(p[128 + j]), ov = b2f(p[256 + j]), gv = b2f(p[384 + j]);
  float s = wred(gv), s2 = wred(gv * gv);
  __shared__ float sh[4];
  int wid = j >> 6;
  if ((j & 63) == 0) { sh[wid] = s; sh[2 + wid] = s2; }
  __syncthreads();
  float mean = (sh[0] + sh[1]) * (1.f / 128.f);
  float var = (sh[2] + sh[3]) * (1.f / 128.f) - mean * mean;
  float gn = (gv - mean) * rsqrtf(var + 1e-5f) * lng[j] + lnb[j];
  float gt = tanhf(gn);
  float ii = fmaxf(iv, 0.f), ff = fmaxf(fv, 0.f), oo = fmaxf(ov, 0.f);
  size_t ci = (size_t)b * HH + j;
  float cn = ff * c[ci] + ii * gt;
  c[ci] = cn;
  h[ci] = f2b(oo * tanhf(cn));
}

// hidden = hA@W0^T + hB@W1^T + hC@W2^T (h bf16, W fp32, out fp32).  BM=128, BN=64.
__global__ void __launch_bounds__(256) k_hidden(const unsigned short* hA, const unsigned short* hB,
                                                const unsigned short* hC, const float* Wr,
                                                float* out) {
  __shared__ __align__(16) float As[8][128];
  __shared__ __align__(16) float Bs[8][64];
  int m0 = blockIdx.x * 128, n0 = blockIdx.y * 64;
  int tid = threadIdx.x;
  int tx = tid & 15, ty = tid >> 4;
  float acc[8][4] = {};
  for (int kc = 0; kc < 48; kc++) {
    int k0 = kc * 8;
    const unsigned short* S = (k0 < 128) ? hA : (k0 < 256 ? hB : hC);
    int koff = k0 & 127;
    {
      int ml = tid >> 1, kq = (tid & 1) * 4;
      int m = m0 + ml;
      float4 v = make_float4(0.f, 0.f, 0.f, 0.f);
      if (m < NN) {
        ushort4 u = *(const ushort4*)(S + (size_t)m * HH + koff + kq);
        v.x = b2f(u.x); v.y = b2f(u.y); v.z = b2f(u.z); v.w = b2f(u.w);
      }
      As[kq + 0][ml] = v.x; As[kq + 1][ml] = v.y; As[kq + 2][ml] = v.z; As[kq + 3][ml] = v.w;
    }
    #pragma unroll
    for (int q = 0; q < 2; q++) {
      int e = tid + q * 256;
      int kl = e >> 6, nl = e & 63;
      Bs[kl][nl] = Wr[(size_t)(k0 + kl) * HH + n0 + nl];
    }
    __syncthreads();
    #pragma unroll
    for (int k = 0; k < 8; k++) {
      float4 a0 = *(const float4*)&As[k][ty * 4];
      float4 a1 = *(const float4*)&As[k][64 + ty * 4];
      float4 b0 = *(const float4*)&Bs[k][tx * 4];
      const float av0[4] = {a0.x, a0.y, a0.z, a0.w};
      const float av1[4] = {a1.x, a1.y, a1.z, a1.w};
      const float bv[4] = {b0.x, b0.y, b0.z, b0.w};
      #pragma unroll
      for (int i = 0; i < 4; i++)
        #pragma unroll
        for (int j = 0; j < 4; j++) {
          acc[i][j] += av0[i] * bv[j];
          acc[4 + i][j] += av1[i] * bv[j];
        }
    }
    __syncthreads();
  }
  #pragma unroll
  for (int g = 0; g < 2; g++)
    #pragma unroll
    for (int i = 0; i < 4; i++) {
      int m = m0 + g * 64 + ty * 4 + i;
      if (m < NN) {
        float4 r;
        r.x = acc[g * 4 + i][0]; r.y = acc[g * 4 + i][1];
        r.z = acc[g * 4 + i][2]; r.w = acc[g * 4 + i][3];
        *(float4*)(out + (size_t)m * HH + n0 + tx * 4) = r;
      }
    }
}

// ---------- pool kernels ----------

__global__ void k_vnorm(const float* pv, float* acc) {
  int t = threadIdx.x;  // 128
  float v = pv[t];
  float s = wred(v * v);
  __shared__ float sh[2];
  if ((t & 63) == 0) sh[t >> 6] = s;
  __syncthreads();
  if (t == 0) acc[0] = 1.0f / (sqrtf(sh[0] + sh[1]) + EPSF);
}

__global__ void __launch_bounds__(256) k_sc(const float* hidden, const float* pv, float* acc,
                                            float* sc) {
  int wid = threadIdx.x >> 6, lane = threadIdx.x & 63;
  float2 vv = *(const float2*)(pv + lane * 2);
  float inv = acc[0];
  float ls = 0.f, ls2 = 0.f;
  for (int n = blockIdx.x * 4 + wid; n < NN; n += gridDim.x * 4) {
    float2 hv = *(const float2*)(hidden + (size_t)n * HH + lane * 2);
    float dot = hv.x * vv.x + hv.y * vv.y;
    dot = wred(dot);
    if (lane == 0) {
      float s = dot * inv;
      sc[n] = s;
      ls += s;
      ls2 += s * s;
    }
  }
  __shared__ float sh[8];
  if (lane == 0) { sh[wid] = ls; sh[4 + wid] = ls2; }
  __syncthreads();
  if (threadIdx.x == 0) {
    atomicAdd(&acc[1], sh[0] + sh[1] + sh[2] + sh[3]);
    atomicAdd(&acc[2], sh[4] + sh[5] + sh[6] + sh[7]);
  }
}

__global__ void k_sig(const float* sc, const float* acc, float* sig) {
  int n = blockIdx.x * 256 + threadIdx.x;
  if (n < NN) {
    float mean = acc[1] * (1.f / NN);
    float var = acc[2] * (1.f / NN) - mean * mean;
    float sd = sqrtf(fmaxf(var, 0.f)) + EPSF;
    float z = (sc[n] - mean) / sd;
    sig[n] = 1.f / (1.f + expf(-z));
  }
}

__global__ void __launch_bounds__(256) k_rank(const float* sc, int* rank) {
  __shared__ float sj[1024];
  int i = blockIdx.x * 256 + threadIdx.x;
  int j0 = blockIdx.y * 1024;
  for (int k = threadIdx.x; k < 1024; k += 256) {
    int j = j0 + k;
    sj[k] = (j < NN) ? sc[j] : -3.0e38f;
  }
  __syncthreads();
  float si = (i < NN) ? sc[i] : 0.f;
  int jmax = NN - j0; if (jmax > 1024) jmax = 1024;
  int cnt = 0;
  for (int k = 0; k < jmax; k++) {
    float v = sj[k];
    int j = j0 + k;
    cnt += (v > si) || (v == si && j < i);
  }
  if (i < NN && cnt) atomicAdd(&rank[i], cnt);
}

__global__ void __launch_bounds__(256) k_plogs(const float* sig, const int* rank, float* acc) {
  int i = blockIdx.x * 256 + threadIdx.x;
  float v = 0.f;
  if (i < NN) {
    float s = sig[i];
    v = (rank[i] < KK) ? logf(s + EPSF) : logf(1.f - s + EPSF);
  }
  v = wred(v);
  __shared__ float sh[4];
  if ((threadIdx.x & 63) == 0) sh[threadIdx.x >> 6] = v;
  __syncthreads();
  if (threadIdx.x == 0) atomicAdd(&acc[3], sh[0] + sh[1] + sh[2] + sh[3]);
}

__global__ void __launch_bounds__(128) k_high(const float* hidden, const float* sig,
                                              const int* rank, float* high) {
  int ch = threadIdx.x;
  int n0 = blockIdx.x * 128;
  float a = 0.f;
  for (int q = 0; q < 128; q++) {
    int n = n0 + q;
    if (n >= NN) break;
    if (rank[n] < KK) a += hidden[(size_t)n * HH + ch] * sig[n];
  }
  atomicAdd(&high[ch], a);
}

// ---------- LSTM kernels ----------

__global__ void __launch_bounds__(256) k_zpre2(const float* Wih, const float* ts, float* part) {
  __shared__ __align__(16) float As[16][64];
  __shared__ __align__(16) float Bs[16][64];
  int m0 = blockIdx.x * 64;
  int n0 = blockIdx.y * 64;
  int ks = blockIdx.z;
  int kbeg = ks * 624;
  int kend = (ks == 15) ? NN : kbeg + 624;
  int tid = threadIdx.x;
  int tx = tid & 15, ty = tid >> 4;
  int lm = tid >> 2, kq = (tid & 3) * 4;
  bool bvalid = (n0 + lm) < TSS;
  float acc[4][4] = {};
  for (int k0 = kbeg; k0 < kend; k0 += 16) {
    {
      float4 v = *(const float4*)(Wih + (size_t)(m0 + lm) * NN + k0 + kq);
      As[kq + 0][lm] = v.x; As[kq + 1][lm] = v.y; As[kq + 2][lm] = v.z; As[kq + 3][lm] = v.w;
    }
    {
      float4 v = make_float4(0.f, 0.f, 0.f, 0.f);
      if (bvalid) v = *(const float4*)(ts + (size_t)(n0 + lm) * NN + k0 + kq);
      Bs[kq + 0][lm] = v.x; Bs[kq + 1][lm] = v.y; Bs[kq + 2][lm] = v.z; Bs[kq + 3][lm] = v.w;
    }
    __syncthreads();
    #pragma unroll
    for (int k = 0; k < 16; k++) {
      float4 a0 = *(const float4*)&As[k][ty * 4];
      float4 b0 = *(const float4*)&Bs[k][tx * 4];
      const float av[4] = {a0.x, a0.y, a0.z, a0.w};
      const float bv[4] = {b0.x, b0.y, b0.z, b0.w};
      #pragma unroll
      for (int i = 0; i < 4; i++)
        #pragma unroll
        for (int j = 0; j < 4; j++)
          acc[i][j] += av[i] * bv[j];
    }
    __syncthreads();
  }
  float* pd = part + ((size_t)ks << 17);
  #pragma unroll
  for (int i = 0; i < 4; i++) {
    float4 r4 = make_float4(acc[i][0], acc[i][1], acc[i][2], acc[i][3]);
    *(float4*)(pd + (size_t)(m0 + ty * 4 + i) * 256 + n0 + tx * 4) = r4;
  }
}

__global__ void __launch_bounds__(256) k_zred(const float* part, float* zpre) {
  int r = blockIdx.x;
  int t = threadIdx.x;
  int base = r * 256 + t;
  float s = 0.f;
  #pragma unroll
  for (int k = 0; k < 16; k++) s += part[(k << 17) + base];
  if (t < TSS) zpre[(size_t)t * G4 + r] = s;
}

// serial recurrence: 512 threads, weights in VGPRs (waves_per_eu cap lifted),
// h broadcast via v_readlane (2 h-elems per lane, replicated per wave) -> ~no DS.
__global__ void __attribute__((amdgpu_waves_per_eu(1, 2))) __launch_bounds__(512)
k_lstm(const float* Whh, const float* bih, const float* bhh,
       const float* zpre, float* h_last) {
  __shared__ float gI[128], gF[128], gG[128], gO[128];
  int tid = threadIdx.x;
  int w = tid >> 6, l = tid & 63;
  int gate = w >> 1;                 // zpre rows: [i|f|g|o]
  int colbase = (w & 1) * 64;
  float wreg[128];
  #pragma unroll
  for (int q = 0; q < 32; q++) {
    float4 v = *(const float4*)(Whh + (size_t)tid * HH + 4 * q);
    wreg[4 * q + 0] = v.x; wreg[4 * q + 1] = v.y;
    wreg[4 * q + 2] = v.z; wreg[4 * q + 3] = v.w;
  }
  float bias = bih[tid] + bhh[tid];
  float h2a = 0.f, h2b = 0.f;        // h[2l], h[2l+1] (identical across waves)
  float cc0 = 0.f, cc1 = 0.f;
  for (int t = 0; t < TSS; t++) {
    float d = bias + zpre[(size_t)t * G4 + tid];
    #pragma unroll
    for (int k = 0; k < 128; k += 2) {
      float ha = __uint_as_float(__builtin_amdgcn_readlane(__float_as_uint(h2a), k >> 1));
      float hb = __uint_as_float(__builtin_amdgcn_readlane(__float_as_uint(h2b), k >> 1));
      d += wreg[k] * ha + wreg[k + 1] * hb;
    }
    float a = (gate == 2) ? tanhf(d) : (1.f / (1.f + expf(-d)));
    if (gate == 0) gI[colbase + l] = a;
    else if (gate == 1) gF[colbase + l] = a;
    else if (gate == 2) gG[colbase + l] = a;
    else gO[colbase + l] = a;
    __syncthreads();
    float2 iv = *(const float2*)&gI[2 * l];
    float2 fv = *(const float2*)&gF[2 * l];
    float2 gv = *(const float2*)&gG[2 * l];
    float2 ov = *(const float2*)&gO[2 * l];
    cc0 = fv.x * cc0 + iv.x * gv.x;
    cc1 = fv.y * cc1 + iv.y * gv.y;
    h2a = ov.x * tanhf(cc0);
    h2b = ov.y * tanhf(cc1);
    __syncthreads();
  }
  if (tid < 64) { h_last[2 * tid] = h2a; h_last[2 * tid + 1] = h2b; }
}

// ---------- final MLP ----------

__global__ void __launch_bounds__(256) k_mlp(const float* high, const float* hlast, const float* acc,
    const float* W1, const float* b1, const float* lng, const float* lnb,
    const float* W2, const float* b2, const float* W3, const float* b3, float* out) {
  __shared__ float fus[256];
  __shared__ float m1[128];
  __shared__ float m2[64];
  __shared__ float red[4];
  int t = threadIdx.x;
  fus[t] = (t < 128) ? high[t] * (1.f / KK) : hlast[t - 128];
  __syncthreads();
  if (t < 128) {
    float a = b1[t];
    for (int k = 0; k < 256; k++) a += W1[t * 256 + k] * fus[k];
    m1[t] = fmaxf(a, 0.f);
  }
  __syncthreads();
  if (t < 128) {
    float x = m1[t];
    float s = wred(x), s2 = wred(x * x);
    if ((t & 63) == 0) { red[t >> 6] = s; red[2 + (t >> 6)] = s2; }
  }
  __syncthreads();
  if (t < 128) {
    float mean = (red[0] + red[1]) * (1.f / 128.f);
    float var = (red[2] + red[3]) * (1.f / 128.f) - mean * mean;
    float xn = (m1[t] - mean) * rsqrtf(var + 1e-5f) * lng[t] + lnb[t];
    __syncthreads();
    m1[t] = xn;
  } else {
    __syncthreads();
  }
  __syncthreads();
  if (t < 64) {
    float a = b2[t];
    for (int k = 0; k < 128; k++) a += W2[t * 128 + k] * m1[k];
    m2[t] = fmaxf(a, 0.f);
  }
  __syncthreads();
  if (t < 64) {
    float a = W3[t] * m2[t];
    a = wred(a);
    if (t == 0) {
      out[0] = a + b3[0];
      out[1] = -acc[3] * (1.f / NN);
    }
  }
}

// ---------- host ----------

extern "C" void kernel_launch(void* const* d_in, const int* in_sizes, int n_in,
                              void* d_out, int out_size, void* d_ws, size_t ws_size,
                              hipStream_t stream) {
  const float* x_seq = (const float*)d_in[0];
  const float* h0    = (const float*)d_in[1];
  const float* c0    = (const float*)d_in[2];
  const float* ts    = (const float*)d_in[3];
  const float* Wx    = (const float*)d_in[4];
  const float* bx    = (const float*)d_in[5];
  const float* Wh    = (const float*)d_in[6];
  const float* bh    = (const float*)d_in[7];
  const float* lng   = (const float*)d_in[8];
  const float* lnb   = (const float*)d_in[9];
  const float* mapW  = (const float*)d_in[10];
  const float* pv    = (const float*)d_in[11];
  const float* Wih   = (const float*)d_in[12];
  const float* Whh   = (const float*)d_in[13];
  const float* bih   = (const float*)d_in[14];
  const float* bhh   = (const float*)d_in[15];
  const float* W1    = (const float*)d_in[16];
  const float* b1    = (const float*)d_in[17];
  const float* mlng  = (const float*)d_in[18];
  const float* mlnb  = (const float*)d_in[19];
  const float* W2    = (const float*)d_in[20];
  const float* b2    = (const float*)d_in[21];
  const float* W3    = (const float*)d_in[22];
  const float* b3    = (const float*)d_in[23];
  const int*   ei    = (const int*)d_in[24];

  char* wsp = (char*)d_ws;
  size_t off = 0;
  auto carve = [&](size_t bytes) -> char* {
    char* p = wsp + off;
    off += (bytes + 255) & ~(size_t)255;
    return p;
  };
  unsigned short* Wfrag = (unsigned short*)carve(98304 * 2);
  float* biasC   = (float*)carve(G4 * 4);
  float* mapWr   = (float*)carve(3 * HH * HH * 4);
  int*   degi    = (int*)carve(NN * 4);
  int*   cursor  = (int*)carve(NN * 4);
  int*   rankb   = (int*)carve(NN * 4);
  int*   row_ptr = (int*)carve((NN + 1) * 4);
  float* dis     = (float*)carve(NN * 4);
  float* self_n  = (float*)carve(NN * 4);
  int*   col_src = (int*)carve(EE * 4);
  float* col_w   = (float*)carve(EE * 4);
  unsigned short* hAll = (unsigned short*)carve((size_t)3 * NN * HH * 2);
  float*          cAll = (float*)carve((size_t)3 * NN * HH * 4);
  unsigned short* x2b  = (unsigned short*)carve((size_t)TSTEPS * NN * FF * 2);
  unsigned short* aggX = (unsigned short*)carve((size_t)TSTEPS * NN * FF * 2);
  unsigned short* aggH = (unsigned short*)carve((size_t)3 * NN * HH * 2);
  unsigned short* preB = (unsigned short*)carve((size_t)3 * NN * G4 * 2);  // also zpre2 scratch
  float* hidden  = (float*)carve((size_t)NN * HH * 4);
  float* sc      = (float*)carve(NN * 4);
  float* sig     = (float*)carve(NN * 4);
  float* acc     = (float*)carve(16 * 4);
  float* high    = (float*)carve(128 * 4);
  float* zpre    = (float*)carve((size_t)TSS * G4 * 4);
  float* hlast   = (float*)carve(128 * 4);

  // setup
  k_setup_w<<<384, 256, 0, stream>>>(Wx, Wh, bx, bh, mapW, Wfrag, biasC, mapWr);
  k_zero<<<40, 256, 0, stream>>>(degi, cursor, rankb, acc, high);
  k_deg<<<625, 256, 0, stream>>>(ei, degi);
  k_norm<<<40, 256, 0, stream>>>(degi, dis, self_n);
  k_scan<<<1, 1024, 0, stream>>>(degi, row_ptr, NN);
  k_fill<<<625, 256, 0, stream>>>(ei, row_ptr, cursor, dis, col_src, col_w);
  k_init3<<<5000, 256, 0, stream>>>(h0, c0, hAll, cAll);
  k_xcast<<<5000, 256, 0, stream>>>(x_seq, x2b);

  // x-aggregation for all 8 timesteps (bf16)
  k_aggx8<<<20000, 256, 0, stream>>>(x2b, row_ptr, col_src, col_w, self_n, aggX);

  // 8 fused rounds: rounds 0-3 chains A+B+C (M=3NN), rounds 4-7 chain A only
  for (int r = 0; r < TSTEPS; r++) {
    int M = (r < 4) ? 3 * NN : NN;
    k_aggh<<<M / 2, 256, 0, stream>>>(hAll, row_ptr, col_src, col_w, self_n, aggH, M);
    k_premm<<<dim3((M + 63) / 64, 2), 512, 0, stream>>>(aggX, aggH, Wfrag, biasC, preB, M, r);
    k_gates<<<M, 128, 0, stream>>>(preB, lng, lnb, hAll, cAll, M);
  }

  // hidden combine + pool
  k_hidden<<<dim3(79, 2), 256, 0, stream>>>(hAll, hAll + (size_t)NN * HH,
                                            hAll + (size_t)2 * NN * HH, mapWr, hidden);
  k_vnorm<<<1, 128, 0, stream>>>(pv, acc);
  k_sc<<<250, 256, 0, stream>>>(hidden, pv, acc, sc);
  k_sig<<<40, 256, 0, stream>>>(sc, acc, sig);
  k_rank<<<dim3(40, 10), 256, 0, stream>>>(sc, rankb);
  k_plogs<<<40, 256, 0, stream>>>(sig, rankb, acc);
  k_high<<<79, 128, 0, stream>>>(hidden, sig, rankb, high);

  // LSTM branch (zpre2 partials in preB scratch, free after GNN rounds)
  k_zpre2<<<dim3(8, 4, 16), 256, 0, stream>>>(Wih, ts, (float*)preB);
  k_zred<<<512, 256, 0, stream>>>((float*)preB, zpre);
  k_lstm<<<1, 512, 0, stream>>>(Whh, bih, bhh, zpre, hlast);

  // head
  k_mlp<<<1, 256, 0, stream>>>(high, hlast, acc, W1, b1, mlng, mlnb, W2, b2, W3, b3,
                               (float*)d_out);
}

// Round 6
// 1176.579 us; speedup vs baseline: 2.3134x; 1.0358x over previous
//
#include <hip/hip_runtime.h>
#include <hip/hip_bf16.h>
#include <math.h>

#define NN 10000
#define FF 64
#define TSTEPS 8
#define EE 160000
#define TSS 200
#define HH 128
#define KK 5000
#define G4 512
#define KIN 192
#define EPSF 1e-8f

typedef __attribute__((ext_vector_type(8))) short short8v;
typedef __attribute__((ext_vector_type(4))) float f32x4;

__device__ inline float wred(float v){
  #pragma unroll
  for (int off = 32; off > 0; off >>= 1) v += __shfl_xor(v, off);
  return v;
}

__device__ inline unsigned short f2b(float f) {
  union { __hip_bfloat16 h; unsigned short u; } cv;
  cv.h = __float2bfloat16(f);
  return cv.u;
}
__device__ inline float b2f(unsigned short u) {
  return __uint_as_float(((unsigned int)u) << 16);
}

// ---------- setup kernels ----------

// biasC, mapWr, and the MFMA-fragment-ordered bf16 weight table Wfrag.
// Wfrag[((ks*32+ntg)*64+l)*8+jj] = bf16(W[k=ks*32+(l>>4)*8+jj][col=ntg*16+(l&15)])
__global__ void k_setup_w(const float* Wx, const float* Wh, const float* bx, const float* bh,
                          const float* mapW, unsigned short* Wfrag, float* biasC, float* mapWr) {
  int idx = blockIdx.x * 256 + threadIdx.x;   // grid 384*256 = 98304 = 6*32*64*8
  {
    int jj = idx & 7, l = (idx >> 3) & 63, ntg = (idx >> 9) & 31, ks = idx >> 14;
    int k = ks * 32 + ((l >> 4) << 3) + jj;
    int gh = ntg * 16 + (l & 15);
    int g = gh >> 7, hh = gh & 127;
    float v = (k < FF) ? Wx[(g * HH + hh) * FF + k] : Wh[(g * HH + hh) * HH + (k - FF)];
    Wfrag[idx] = f2b(v);
  }
  if (idx < G4) biasC[idx] = bx[idx] + bh[idx];
  if (idx < 3 * HH * HH) {
    int s = idx / (HH * HH), r = idx % (HH * HH);
    int d = r / HH, j = r % HH;
    mapWr[idx] = mapW[(s * HH + j) * HH + d];
  }
}

__global__ void k_zero(int* deg, int* cursor, int* rank, float* acc, float* high) {
  int i = blockIdx.x * 256 + threadIdx.x;
  if (i < NN) { deg[i] = 0; cursor[i] = 0; rank[i] = 0; }
  if (i < 16) acc[i] = 0.f;
  if (i < 128) high[i] = 0.f;
}

__global__ void k_deg(const int* ei, int* deg) {
  int e = blockIdx.x * 256 + threadIdx.x;
  if (e < EE) atomicAdd(&deg[ei[EE + e]], 1);
}

__global__ void k_norm(const int* deg, float* dis, float* self_norm) {
  int n = blockIdx.x * 256 + threadIdx.x;
  if (n < NN) {
    float d = 1.0f + (float)deg[n];
    dis[n] = rsqrtf(d);
    self_norm[n] = 1.0f / d;
  }
}

__global__ void k_scan(const int* deg, int* row_ptr, int n) {
  __shared__ int buf[1024];
  __shared__ int carry;
  if (threadIdx.x == 0) carry = 0;
  __syncthreads();
  for (int base = 0; base < n; base += 1024) {
    int i = base + threadIdx.x;
    int v = (i < n) ? deg[i] : 0;
    buf[threadIdx.x] = v;
    __syncthreads();
    for (int off = 1; off < 1024; off <<= 1) {
      int t = (threadIdx.x >= off) ? buf[threadIdx.x - off] : 0;
      __syncthreads();
      buf[threadIdx.x] += t;
      __syncthreads();
    }
    if (i < n) row_ptr[i] = carry + buf[threadIdx.x] - v;
    __syncthreads();
    if (threadIdx.x == 1023) carry += buf[1023];
    __syncthreads();
  }
  if (threadIdx.x == 0) row_ptr[n] = carry;
}

__global__ void k_fill(const int* ei, const int* row_ptr, int* cursor, const float* dis,
                       int* col_src, float* col_w) {
  int e = blockIdx.x * 256 + threadIdx.x;
  if (e < EE) {
    int s = ei[e], d = ei[EE + e];
    int pos = row_ptr[d] + atomicAdd(&cursor[d], 1);
    col_src[pos] = s;
    col_w[pos] = dis[s] * dis[d];
  }
}

// hAll bf16 (3 chains), cAll fp32
__global__ void k_init3(const float* h0, const float* c0, unsigned short* hAll, float* cAll) {
  int i = blockIdx.x * 256 + threadIdx.x;
  if (i < NN * HH) {
    unsigned short h = f2b(h0[i]);
    float c = c0[i];
    hAll[i] = h; hAll[NN * HH + i] = h; hAll[2 * NN * HH + i] = h;
    cAll[i] = c; cAll[NN * HH + i] = c; cAll[2 * NN * HH + i] = c;
  }
}

// cast x_seq to bf16 once (halves gather traffic in k_aggx8)
__global__ void k_xcast(const float* x, unsigned short* xb) {
  int i = blockIdx.x * 256 + threadIdx.x;   // 1,280,000 float4s
  float4 v = *(const float4*)(x + (size_t)i * 4);
  ushort4 u;
  u.x = f2b(v.x); u.y = f2b(v.y); u.z = f2b(v.z); u.w = f2b(v.w);
  *(ushort4*)(xb + (size_t)i * 4) = u;
}

// ---------- GNN cell kernels ----------

// x-aggregation for all 8 timesteps: aggX[t*NN+n][64] bf16.
__global__ void __launch_bounds__(256) k_aggx8(const unsigned short* xb, const int* row_ptr,
    const int* col_src, const float* col_w, const float* self_n, unsigned short* aggX) {
  __shared__ int es[4][64];
  __shared__ float ew[4][64];
  int wv = threadIdx.x >> 6, lane = threadIdx.x & 63;
  int p = blockIdx.x * 4 + wv;          // < 8*NN
  int t = p / NN, n = p - t * NN;
  int e0 = row_ptr[n], e1 = row_ptr[n + 1];
  float acc = 0.f;
  for (int eb = e0; eb < e1; eb += 64) {
    int cnt = min(64, e1 - eb);
    if (lane < cnt) { es[wv][lane] = col_src[eb + lane]; ew[wv][lane] = col_w[eb + lane]; }
    __builtin_amdgcn_wave_barrier();
    for (int i = 0; i < cnt; i++)
      acc += b2f(xb[((size_t)t * NN + es[wv][i]) * FF + lane]) * ew[wv][i];
    __builtin_amdgcn_wave_barrier();
  }
  acc += b2f(xb[((size_t)t * NN + n) * FF + lane]) * self_n[n];
  aggX[(size_t)p * FF + lane] = f2b(acc);
}

// h-aggregation (bf16 in/out), M rows of hAll.
__global__ void __launch_bounds__(256) k_aggh(const unsigned short* hAll, const int* row_ptr,
    const int* col_src, const float* col_w, const float* self_n, unsigned short* aggH, int M) {
  __shared__ int es[4][64];
  __shared__ float ew[4][64];
  int w = threadIdx.x >> 6, lane = threadIdx.x & 63;
  int m = blockIdx.x * 2 + (w >> 1);
  if (m >= M) return;
  int ch = (w & 1) * 64 + lane;
  int c = (m >= 2 * NN) ? 2 : (m >= NN ? 1 : 0);
  int n = m - c * NN;
  int e0 = row_ptr[n], e1 = row_ptr[n + 1];
  const unsigned short* hb = hAll + (size_t)c * NN * HH;
  float acc = 0.f;
  for (int eb = e0; eb < e1; eb += 64) {
    int cnt = min(64, e1 - eb);
    if (lane < cnt) { es[w][lane] = col_src[eb + lane]; ew[w][lane] = col_w[eb + lane]; }
    __builtin_amdgcn_wave_barrier();
    for (int i = 0; i < cnt; i++)
      acc += b2f(hb[(size_t)es[w][i] * HH + ch]) * ew[w][i];
    __builtin_amdgcn_wave_barrier();
  }
  acc += b2f(hAll[(size_t)m * HH + ch]) * self_n[n];
  aggH[(size_t)m * HH + ch] = f2b(acc);
}

// MFMA bf16 cell GEMM: pre[M x 512] (bf16) = [aggX|aggH](M x 192) @ W(192x512) + bias.
__global__ void __launch_bounds__(512) k_premm(const unsigned short* aggX,
    const unsigned short* aggH, const unsigned short* Wfrag, const float* biasC,
    unsigned short* preB, int M, int r) {
  __shared__ unsigned short Af[1536 * 8];   // [mt 0..3][ks 0..5][lane 0..63][8] = 24KB
  int m0 = blockIdx.x * 64;
  int n0 = blockIdx.y * 256;
  int tid = threadIdx.x;
  int l = tid & 63, wid = tid >> 6;
  int wm = wid >> 2, wn = wid & 3;
  #pragma unroll
  for (int q = 0; q < 3; q++) {
    int chunk = tid + q * 512;
    int mt = chunk / 384, rem = chunk - mt * 384;
    int ks = rem >> 6, cl = rem & 63;
    int row = m0 + mt * 16 + (cl & 15);
    int kk = ks * 32 + ((cl >> 4) << 3);
    short8v v = {};
    if (row < M) {
      const unsigned short* src;
      if (kk < FF) {
        int ch = (row >= 2 * NN) ? 2 : (row >= NN ? 1 : 0);
        int n = row - ch * NN;
        int t = (ch == 0) ? r : (2 * r + ch - 1);
        src = aggX + ((size_t)t * NN + n) * FF + kk;
      } else {
        src = aggH + (size_t)row * HH + (kk - FF);
      }
      v = *(const short8v*)src;
    }
    *(short8v*)&Af[chunk * 8] = v;
  }
  __syncthreads();
  f32x4 acc[2][4];
  #pragma unroll
  for (int i = 0; i < 2; i++)
    #pragma unroll
    for (int j = 0; j < 4; j++) acc[i][j] = (f32x4){0.f, 0.f, 0.f, 0.f};
  #pragma unroll
  for (int ks = 0; ks < 6; ks++) {
    short8v a0 = *(const short8v*)&Af[(((wm * 2 + 0) * 6 + ks) * 64 + l) * 8];
    short8v a1 = *(const short8v*)&Af[(((wm * 2 + 1) * 6 + ks) * 64 + l) * 8];
    #pragma unroll
    for (int j = 0; j < 4; j++) {
      int ntg = (n0 >> 4) + wn * 4 + j;
      short8v b = *(const short8v*)(Wfrag + (((size_t)ks * 32 + ntg) * 64 + l) * 8);
      acc[0][j] = __builtin_amdgcn_mfma_f32_16x16x32_bf16(a0, b, acc[0][j], 0, 0, 0);
      acc[1][j] = __builtin_amdgcn_mfma_f32_16x16x32_bf16(a1, b, acc[1][j], 0, 0, 0);
    }
  }
  #pragma unroll
  for (int i = 0; i < 2; i++)
    #pragma unroll
    for (int j = 0; j < 4; j++) {
      int colg = n0 + wn * 64 + j * 16 + (l & 15);
      float bv = biasC[colg];
      #pragma unroll
      for (int rg = 0; rg < 4; rg++) {
        int row = m0 + wm * 32 + i * 16 + ((l >> 4) * 4) + rg;
        if (row < M) preB[(size_t)row * G4 + colg] = f2b(acc[i][j][rg] + bv);
      }
    }
}

// gates + LN + state update (bf16 pre/h, fp32 c/math).  grid = M blocks, 128 threads.
__global__ void __launch_bounds__(128) k_gates(const unsigned short* preB, const float* lng,
                                               const float* lnb, unsigned short* h, float* c,
                                               int M) {
  int b = blockIdx.x;
  int j = threadIdx.x;
  const unsigned short* p = preB + (size_t)b * G4;
  float iv = b2f(p[j]), fv = b2f(p[128 + j]), ov = b2f(p[256 + j]), gv = b2f(p[384 + j]);
  float s = wred(gv), s2 = wred(gv * gv);
  __shared__ float sh[4];
  int wid = j >> 6;
  if ((j & 63) == 0) { sh[wid] = s; sh[2 + wid] = s2; }
  __syncthreads();
  float mean = (sh[0] + sh[1]) * (1.f / 128.f);
  float var = (sh[2] + sh[3]) * (1.f / 128.f) - mean * mean;
  float gn = (gv - mean) * rsqrtf(var + 1e-5f) * lng[j] + lnb[j];
  float gt = tanhf(gn);
  float ii = fmaxf(iv, 0.f), ff = fmaxf(fv, 0.f), oo = fmaxf(ov, 0.f);
  size_t ci = (size_t)b * HH + j;
  float cn = ff * c[ci] + ii * gt;
  c[ci] = cn;
  h[ci] = f2b(oo * tanhf(cn));
}

// hidden = hA@W0^T + hB@W1^T + hC@W2^T (h bf16, W fp32, out fp32).  BM=128, BN=64.
__global__ void __launch_bounds__(256) k_hidden(const unsigned short* hA, const unsigned short* hB,
                                                const unsigned short* hC, const float* Wr,
                                                float* out) {
  __shared__ __align__(16) float As[8][128];
  __shared__ __align__(16) float Bs[8][64];
  int m0 = blockIdx.x * 128, n0 = blockIdx.y * 64;
  int tid = threadIdx.x;
  int tx = tid & 15, ty = tid >> 4;
  float acc[8][4] = {};
  for (int kc = 0; kc < 48; kc++) {
    int k0 = kc * 8;
    const unsigned short* S = (k0 < 128) ? hA : (k0 < 256 ? hB : hC);
    int koff = k0 & 127;
    {
      int ml = tid >> 1, kq = (tid & 1) * 4;
      int m = m0 + ml;
      float4 v = make_float4(0.f, 0.f, 0.f, 0.f);
      if (m < NN) {
        ushort4 u = *(const ushort4*)(S + (size_t)m * HH + koff + kq);
        v.x = b2f(u.x); v.y = b2f(u.y); v.z = b2f(u.z); v.w = b2f(u.w);
      }
      As[kq + 0][ml] = v.x; As[kq + 1][ml] = v.y; As[kq + 2][ml] = v.z; As[kq + 3][ml] = v.w;
    }
    #pragma unroll
    for (int q = 0; q < 2; q++) {
      int e = tid + q * 256;
      int kl = e >> 6, nl = e & 63;
      Bs[kl][nl] = Wr[(size_t)(k0 + kl) * HH + n0 + nl];
    }
    __syncthreads();
    #pragma unroll
    for (int k = 0; k < 8; k++) {
      float4 a0 = *(const float4*)&As[k][ty * 4];
      float4 a1 = *(const float4*)&As[k][64 + ty * 4];
      float4 b0 = *(const float4*)&Bs[k][tx * 4];
      const float av0[4] = {a0.x, a0.y, a0.z, a0.w};
      const float av1[4] = {a1.x, a1.y, a1.z, a1.w};
      const float bv[4] = {b0.x, b0.y, b0.z, b0.w};
      #pragma unroll
      for (int i = 0; i < 4; i++)
        #pragma unroll
        for (int j = 0; j < 4; j++) {
          acc[i][j] += av0[i] * bv[j];
          acc[4 + i][j] += av1[i] * bv[j];
        }
    }
    __syncthreads();
  }
  #pragma unroll
  for (int g = 0; g < 2; g++)
    #pragma unroll
    for (int i = 0; i < 4; i++) {
      int m = m0 + g * 64 + ty * 4 + i;
      if (m < NN) {
        float4 r;
        r.x = acc[g * 4 + i][0]; r.y = acc[g * 4 + i][1];
        r.z = acc[g * 4 + i][2]; r.w = acc[g * 4 + i][3];
        *(float4*)(out + (size_t)m * HH + n0 + tx * 4) = r;
      }
    }
}

// ---------- pool kernels ----------

__global__ void k_vnorm(const float* pv, float* acc) {
  int t = threadIdx.x;  // 128
  float v = pv[t];
  float s = wred(v * v);
  __shared__ float sh[2];
  if ((t & 63) == 0) sh[t >> 6] = s;
  __syncthreads();
  if (t == 0) acc[0] = 1.0f / (sqrtf(sh[0] + sh[1]) + EPSF);
}

__global__ void __launch_bounds__(256) k_sc(const float* hidden, const float* pv, float* acc,
                                            float* sc) {
  int wid = threadIdx.x >> 6, lane = threadIdx.x & 63;
  float2 vv = *(const float2*)(pv + lane * 2);
  float inv = acc[0];
  float ls = 0.f, ls2 = 0.f;
  for (int n = blockIdx.x * 4 + wid; n < NN; n += gridDim.x * 4) {
    float2 hv = *(const float2*)(hidden + (size_t)n * HH + lane * 2);
    float dot = hv.x * vv.x + hv.y * vv.y;
    dot = wred(dot);
    if (lane == 0) {
      float s = dot * inv;
      sc[n] = s;
      ls += s;
      ls2 += s * s;
    }
  }
  __shared__ float sh[8];
  if (lane == 0) { sh[wid] = ls; sh[4 + wid] = ls2; }
  __syncthreads();
  if (threadIdx.x == 0) {
    atomicAdd(&acc[1], sh[0] + sh[1] + sh[2] + sh[3]);
    atomicAdd(&acc[2], sh[4] + sh[5] + sh[6] + sh[7]);
  }
}

__global__ void k_sig(const float* sc, const float* acc, float* sig) {
  int n = blockIdx.x * 256 + threadIdx.x;
  if (n < NN) {
    float mean = acc[1] * (1.f / NN);
    float var = acc[2] * (1.f / NN) - mean * mean;
    float sd = sqrtf(fmaxf(var, 0.f)) + EPSF;
    float z = (sc[n] - mean) / sd;
    sig[n] = 1.f / (1.f + expf(-z));
  }
}

__global__ void __launch_bounds__(256) k_rank(const float* sc, int* rank) {
  __shared__ float sj[1024];
  int i = blockIdx.x * 256 + threadIdx.x;
  int j0 = blockIdx.y * 1024;
  for (int k = threadIdx.x; k < 1024; k += 256) {
    int j = j0 + k;
    sj[k] = (j < NN) ? sc[j] : -3.0e38f;
  }
  __syncthreads();
  float si = (i < NN) ? sc[i] : 0.f;
  int jmax = NN - j0; if (jmax > 1024) jmax = 1024;
  int cnt = 0;
  for (int k = 0; k < jmax; k++) {
    float v = sj[k];
    int j = j0 + k;
    cnt += (v > si) || (v == si && j < i);
  }
  if (i < NN && cnt) atomicAdd(&rank[i], cnt);
}

__global__ void __launch_bounds__(256) k_plogs(const float* sig, const int* rank, float* acc) {
  int i = blockIdx.x * 256 + threadIdx.x;
  float v = 0.f;
  if (i < NN) {
    float s = sig[i];
    v = (rank[i] < KK) ? logf(s + EPSF) : logf(1.f - s + EPSF);
  }
  v = wred(v);
  __shared__ float sh[4];
  if ((threadIdx.x & 63) == 0) sh[threadIdx.x >> 6] = v;
  __syncthreads();
  if (threadIdx.x == 0) atomicAdd(&acc[3], sh[0] + sh[1] + sh[2] + sh[3]);
}

__global__ void __launch_bounds__(128) k_high(const float* hidden, const float* sig,
                                              const int* rank, float* high) {
  int ch = threadIdx.x;
  int n0 = blockIdx.x * 128;
  float a = 0.f;
  for (int q = 0; q < 128; q++) {
    int n = n0 + q;
    if (n >= NN) break;
    if (rank[n] < KK) a += hidden[(size_t)n * HH + ch] * sig[n];
  }
  atomicAdd(&high[ch], a);
}

// ---------- LSTM kernels ----------

__global__ void __launch_bounds__(256) k_zpre2(const float* Wih, const float* ts, float* part) {
  __shared__ __align__(16) float As[16][64];
  __shared__ __align__(16) float Bs[16][64];
  int m0 = blockIdx.x * 64;
  int n0 = blockIdx.y * 64;
  int ks = blockIdx.z;
  int kbeg = ks * 624;
  int kend = (ks == 15) ? NN : kbeg + 624;
  int tid = threadIdx.x;
  int tx = tid & 15, ty = tid >> 4;
  int lm = tid >> 2, kq = (tid & 3) * 4;
  bool bvalid = (n0 + lm) < TSS;
  float acc[4][4] = {};
  for (int k0 = kbeg; k0 < kend; k0 += 16) {
    {
      float4 v = *(const float4*)(Wih + (size_t)(m0 + lm) * NN + k0 + kq);
      As[kq + 0][lm] = v.x; As[kq + 1][lm] = v.y; As[kq + 2][lm] = v.z; As[kq + 3][lm] = v.w;
    }
    {
      float4 v = make_float4(0.f, 0.f, 0.f, 0.f);
      if (bvalid) v = *(const float4*)(ts + (size_t)(n0 + lm) * NN + k0 + kq);
      Bs[kq + 0][lm] = v.x; Bs[kq + 1][lm] = v.y; Bs[kq + 2][lm] = v.z; Bs[kq + 3][lm] = v.w;
    }
    __syncthreads();
    #pragma unroll
    for (int k = 0; k < 16; k++) {
      float4 a0 = *(const float4*)&As[k][ty * 4];
      float4 b0 = *(const float4*)&Bs[k][tx * 4];
      const float av[4] = {a0.x, a0.y, a0.z, a0.w};
      const float bv[4] = {b0.x, b0.y, b0.z, b0.w};
      #pragma unroll
      for (int i = 0; i < 4; i++)
        #pragma unroll
        for (int j = 0; j < 4; j++)
          acc[i][j] += av[i] * bv[j];
    }
    __syncthreads();
  }
  float* pd = part + ((size_t)ks << 17);
  #pragma unroll
  for (int i = 0; i < 4; i++) {
    float4 r4 = make_float4(acc[i][0], acc[i][1], acc[i][2], acc[i][3]);
    *(float4*)(pd + (size_t)(m0 + ty * 4 + i) * 256 + n0 + tx * 4) = r4;
  }
}

__global__ void __launch_bounds__(256) k_zred(const float* part, float* zpre) {
  int r = blockIdx.x;
  int t = threadIdx.x;
  int base = r * 256 + t;
  float s = 0.f;
  #pragma unroll
  for (int k = 0; k < 16; k++) s += part[(k << 17) + base];
  if (t < TSS) zpre[(size_t)t * G4 + r] = s;
}

// serial recurrence: 1024 threads, thread (r, half) owns HALF a Whh row (64 floats
// = 64 VGPRs -> fits the 128-VGPR cap of a 1024-thread block, no spill).
// h broadcast: each wave's lane l holds h[64*half + l] in a register; the 64-wide
// partial dot uses readlane (VALU) -- no DS traffic in the matvec.
__global__ void __launch_bounds__(1024) k_lstm(const float* Whh, const float* bih, const float* bhh,
                                               const float* zpre, float* h_last) {
  __shared__ float part[2][512];
  __shared__ float gact[512];
  int tid = threadIdx.x;
  int half = tid >> 9;                 // 0/1: which 64-wide k-slice of the row
  int r = tid & 511;                   // row of Whh / zpre
  int w = tid >> 6, l = tid & 63;
  float w64[64];
  #pragma unroll
  for (int q = 0; q < 16; q++) {
    float4 v = *(const float4*)(Whh + (size_t)r * HH + 64 * half + 4 * q);
    w64[4 * q + 0] = v.x; w64[4 * q + 1] = v.y;
    w64[4 * q + 2] = v.z; w64[4 * q + 3] = v.w;
  }
  float bias = bih[r] + bhh[r];
  int jbase = (w >= 8) ? 64 : 0;       // wave's h-slice base (== 64*half)
  float hreg = 0.f, creg = 0.f;        // lane l: h[jbase+l], c[jbase+l]
  for (int t = 0; t < TSS; t++) {
    float d = 0.f;
    #pragma unroll
    for (int j = 0; j < 64; j++) {
      float hj = __uint_as_float(__builtin_amdgcn_readlane(__float_as_uint(hreg), j));
      d += w64[j] * hj;
    }
    part[half][r] = d;
    __syncthreads();
    if (tid < 512) {
      float dd = part[0][r] + part[1][r] + bias + zpre[(size_t)t * G4 + r];
      float a = ((r >> 7) == 2) ? tanhf(dd) : (1.f / (1.f + expf(-dd)));
      gact[r] = a;
    }
    __syncthreads();
    int j = jbase + l;
    creg = gact[128 + j] * creg + gact[j] * gact[256 + j];
    hreg = gact[384 + j] * tanhf(creg);
  }
  if (w == 0) h_last[l] = hreg;
  else if (w == 8) h_last[64 + l] = hreg;
}

// ---------- final MLP ----------

__global__ void __launch_bounds__(256) k_mlp(const float* high, const float* hlast, const float* acc,
    const float* W1, const float* b1, const float* lng, const float* lnb,
    const float* W2, const float* b2, const float* W3, const float* b3, float* out) {
  __shared__ float fus[256];
  __shared__ float m1[128];
  __shared__ float m2[64];
  __shared__ float red[4];
  int t = threadIdx.x;
  fus[t] = (t < 128) ? high[t] * (1.f / KK) : hlast[t - 128];
  __syncthreads();
  if (t < 128) {
    float a = b1[t];
    for (int k = 0; k < 256; k++) a += W1[t * 256 + k] * fus[k];
    m1[t] = fmaxf(a, 0.f);
  }
  __syncthreads();
  if (t < 128) {
    float x = m1[t];
    float s = wred(x), s2 = wred(x * x);
    if ((t & 63) == 0) { red[t >> 6] = s; red[2 + (t >> 6)] = s2; }
  }
  __syncthreads();
  if (t < 128) {
    float mean = (red[0] + red[1]) * (1.f / 128.f);
    float var = (red[2] + red[3]) * (1.f / 128.f) - mean * mean;
    float xn = (m1[t] - mean) * rsqrtf(var + 1e-5f) * lng[t] + lnb[t];
    __syncthreads();
    m1[t] = xn;
  } else {
    __syncthreads();
  }
  __syncthreads();
  if (t < 64) {
    float a = b2[t];
    for (int k = 0; k < 128; k++) a += W2[t * 128 + k] * m1[k];
    m2[t] = fmaxf(a, 0.f);
  }
  __syncthreads();
  if (t < 64) {
    float a = W3[t] * m2[t];
    a = wred(a);
    if (t == 0) {
      out[0] = a + b3[0];
      out[1] = -acc[3] * (1.f / NN);
    }
  }
}

// ---------- host ----------

extern "C" void kernel_launch(void* const* d_in, const int* in_sizes, int n_in,
                              void* d_out, int out_size, void* d_ws, size_t ws_size,
                              hipStream_t stream) {
  const float* x_seq = (const float*)d_in[0];
  const float* h0    = (const float*)d_in[1];
  const float* c0    = (const float*)d_in[2];
  const float* ts    = (const float*)d_in[3];
  const float* Wx    = (const float*)d_in[4];
  const float* bx    = (const float*)d_in[5];
  const float* Wh    = (const float*)d_in[6];
  const float* bh    = (const float*)d_in[7];
  const float* lng   = (const float*)d_in[8];
  const float* lnb   = (const float*)d_in[9];
  const float* mapW  = (const float*)d_in[10];
  const float* pv    = (const float*)d_in[11];
  const float* Wih   = (const float*)d_in[12];
  const float* Whh   = (const float*)d_in[13];
  const float* bih   = (const float*)d_in[14];
  const float* bhh   = (const float*)d_in[15];
  const float* W1    = (const float*)d_in[16];
  const float* b1    = (const float*)d_in[17];
  const float* mlng  = (const float*)d_in[18];
  const float* mlnb  = (const float*)d_in[19];
  const float* W2    = (const float*)d_in[20];
  const float* b2    = (const float*)d_in[21];
  const float* W3    = (const float*)d_in[22];
  const float* b3    = (const float*)d_in[23];
  const int*   ei    = (const int*)d_in[24];

  char* wsp = (char*)d_ws;
  size_t off = 0;
  auto carve = [&](size_t bytes) -> char* {
    char* p = wsp + off;
    off += (bytes + 255) & ~(size_t)255;
    return p;
  };
  unsigned short* Wfrag = (unsigned short*)carve(98304 * 2);
  float* biasC   = (float*)carve(G4 * 4);
  float* mapWr   = (float*)carve(3 * HH * HH * 4);
  int*   degi    = (int*)carve(NN * 4);
  int*   cursor  = (int*)carve(NN * 4);
  int*   rankb   = (int*)carve(NN * 4);
  int*   row_ptr = (int*)carve((NN + 1) * 4);
  float* dis     = (float*)carve(NN * 4);
  float* self_n  = (float*)carve(NN * 4);
  int*   col_src = (int*)carve(EE * 4);
  float* col_w   = (float*)carve(EE * 4);
  unsigned short* hAll = (unsigned short*)carve((size_t)3 * NN * HH * 2);
  float*          cAll = (float*)carve((size_t)3 * NN * HH * 4);
  unsigned short* x2b  = (unsigned short*)carve((size_t)TSTEPS * NN * FF * 2);
  unsigned short* aggX = (unsigned short*)carve((size_t)TSTEPS * NN * FF * 2);
  unsigned short* aggH = (unsigned short*)carve((size_t)3 * NN * HH * 2);
  unsigned short* preB = (unsigned short*)carve((size_t)3 * NN * G4 * 2);  // also zpre2 scratch
  float* hidden  = (float*)carve((size_t)NN * HH * 4);
  float* sc      = (float*)carve(NN * 4);
  float* sig     = (float*)carve(NN * 4);
  float* acc     = (float*)carve(16 * 4);
  float* high    = (float*)carve(128 * 4);
  float* zpre    = (float*)carve((size_t)TSS * G4 * 4);
  float* hlast   = (float*)carve(128 * 4);

  // setup
  k_setup_w<<<384, 256, 0, stream>>>(Wx, Wh, bx, bh, mapW, Wfrag, biasC, mapWr);
  k_zero<<<40, 256, 0, stream>>>(degi, cursor, rankb, acc, high);
  k_deg<<<625, 256, 0, stream>>>(ei, degi);
  k_norm<<<40, 256, 0, stream>>>(degi, dis, self_n);
  k_scan<<<1, 1024, 0, stream>>>(degi, row_ptr, NN);
  k_fill<<<625, 256, 0, stream>>>(ei, row_ptr, cursor, dis, col_src, col_w);
  k_init3<<<5000, 256, 0, stream>>>(h0, c0, hAll, cAll);
  k_xcast<<<5000, 256, 0, stream>>>(x_seq, x2b);

  // x-aggregation for all 8 timesteps (bf16)
  k_aggx8<<<20000, 256, 0, stream>>>(x2b, row_ptr, col_src, col_w, self_n, aggX);

  // 8 fused rounds: rounds 0-3 chains A+B+C (M=3NN), rounds 4-7 chain A only
  for (int r = 0; r < TSTEPS; r++) {
    int M = (r < 4) ? 3 * NN : NN;
    k_aggh<<<M / 2, 256, 0, stream>>>(hAll, row_ptr, col_src, col_w, self_n, aggH, M);
    k_premm<<<dim3((M + 63) / 64, 2), 512, 0, stream>>>(aggX, aggH, Wfrag, biasC, preB, M, r);
    k_gates<<<M, 128, 0, stream>>>(preB, lng, lnb, hAll, cAll, M);
  }

  // hidden combine + pool
  k_hidden<<<dim3(79, 2), 256, 0, stream>>>(hAll, hAll + (size_t)NN * HH,
                                            hAll + (size_t)2 * NN * HH, mapWr, hidden);
  k_vnorm<<<1, 128, 0, stream>>>(pv, acc);
  k_sc<<<250, 256, 0, stream>>>(hidden, pv, acc, sc);
  k_sig<<<40, 256, 0, stream>>>(sc, acc, sig);
  k_rank<<<dim3(40, 10), 256, 0, stream>>>(sc, rankb);
  k_plogs<<<40, 256, 0, stream>>>(sig, rankb, acc);
  k_high<<<79, 128, 0, stream>>>(hidden, sig, rankb, high);

  // LSTM branch (zpre2 partials in preB scratch, free after GNN rounds)
  k_zpre2<<<dim3(8, 4, 16), 256, 0, stream>>>(Wih, ts, (float*)preB);
  k_zred<<<512, 256, 0, stream>>>((float*)preB, zpre);
  k_lstm<<<1, 1024, 0, stream>>>(Whh, bih, bhh, zpre, hlast);

  // head
  k_mlp<<<1, 256, 0, stream>>>(high, hlast, acc, W1, b1, mlng, mlnb, W2, b2, W3, b3,
                               (float*)d_out);
}

// Round 8
// 1106.699 us; speedup vs baseline: 2.4595x; 1.0631x over previous
//
#include <hip/hip_runtime.h>
#include <hip/hip_bf16.h>
#include <math.h>

#define NN 10000
#define FF 64
#define TSTEPS 8
#define EE 160000
#define TSS 200
#define HH 128
#define KK 5000
#define G4 512
#define KIN 192
#define EPSF 1e-8f

typedef __attribute__((ext_vector_type(8))) short short8v;
typedef __attribute__((ext_vector_type(4))) float f32x4;

__device__ inline float wred(float v){
  #pragma unroll
  for (int off = 32; off > 0; off >>= 1) v += __shfl_xor(v, off);
  return v;
}

__device__ inline unsigned short f2b(float f) {
  union { __hip_bfloat16 h; unsigned short u; } cv;
  cv.h = __float2bfloat16(f);
  return cv.u;
}
__device__ inline float b2f(unsigned short u) {
  return __uint_as_float(((unsigned int)u) << 16);
}

// ---------- setup kernels ----------

// biasC, mapWr, and the MFMA-fragment-ordered bf16 weight table Wfrag.
// Wfrag[((ks*32+ntg)*64+l)*8+jj] = bf16(W[k=ks*32+(l>>4)*8+jj][col=ntg*16+(l&15)])
__global__ void k_setup_w(const float* Wx, const float* Wh, const float* bx, const float* bh,
                          const float* mapW, unsigned short* Wfrag, float* biasC, float* mapWr) {
  int idx = blockIdx.x * 256 + threadIdx.x;   // grid 384*256 = 98304 = 6*32*64*8
  {
    int jj = idx & 7, l = (idx >> 3) & 63, ntg = (idx >> 9) & 31, ks = idx >> 14;
    int k = ks * 32 + ((l >> 4) << 3) + jj;
    int gh = ntg * 16 + (l & 15);
    int g = gh >> 7, hh = gh & 127;
    float v = (k < FF) ? Wx[(g * HH + hh) * FF + k] : Wh[(g * HH + hh) * HH + (k - FF)];
    Wfrag[idx] = f2b(v);
  }
  if (idx < G4) biasC[idx] = bx[idx] + bh[idx];
  if (idx < 3 * HH * HH) {
    int s = idx / (HH * HH), r = idx % (HH * HH);
    int d = r / HH, j = r % HH;
    mapWr[idx] = mapW[(s * HH + j) * HH + d];
  }
}

__global__ void k_zero(int* deg, int* cursor, int* rank, float* acc, float* high) {
  int i = blockIdx.x * 256 + threadIdx.x;
  if (i < NN) { deg[i] = 0; cursor[i] = 0; rank[i] = 0; }
  if (i < 16) acc[i] = 0.f;
  if (i < 128) high[i] = 0.f;
}

__global__ void k_deg(const int* ei, int* deg) {
  int e = blockIdx.x * 256 + threadIdx.x;
  if (e < EE) atomicAdd(&deg[ei[EE + e]], 1);
}

__global__ void k_norm(const int* deg, float* dis, float* self_norm) {
  int n = blockIdx.x * 256 + threadIdx.x;
  if (n < NN) {
    float d = 1.0f + (float)deg[n];
    dis[n] = rsqrtf(d);
    self_norm[n] = 1.0f / d;
  }
}

__global__ void k_scan(const int* deg, int* row_ptr, int n) {
  __shared__ int buf[1024];
  __shared__ int carry;
  if (threadIdx.x == 0) carry = 0;
  __syncthreads();
  for (int base = 0; base < n; base += 1024) {
    int i = base + threadIdx.x;
    int v = (i < n) ? deg[i] : 0;
    buf[threadIdx.x] = v;
    __syncthreads();
    for (int off = 1; off < 1024; off <<= 1) {
      int t = (threadIdx.x >= off) ? buf[threadIdx.x - off] : 0;
      __syncthreads();
      buf[threadIdx.x] += t;
      __syncthreads();
    }
    if (i < n) row_ptr[i] = carry + buf[threadIdx.x] - v;
    __syncthreads();
    if (threadIdx.x == 1023) carry += buf[1023];
    __syncthreads();
  }
  if (threadIdx.x == 0) row_ptr[n] = carry;
}

__global__ void k_fill(const int* ei, const int* row_ptr, int* cursor, const float* dis,
                       int* col_src, float* col_w) {
  int e = blockIdx.x * 256 + threadIdx.x;
  if (e < EE) {
    int s = ei[e], d = ei[EE + e];
    int pos = row_ptr[d] + atomicAdd(&cursor[d], 1);
    col_src[pos] = s;
    col_w[pos] = dis[s] * dis[d];
  }
}

// hAll bf16 (3 chains), cAll fp32
__global__ void k_init3(const float* h0, const float* c0, unsigned short* hAll, float* cAll) {
  int i = blockIdx.x * 256 + threadIdx.x;
  if (i < NN * HH) {
    unsigned short h = f2b(h0[i]);
    float c = c0[i];
    hAll[i] = h; hAll[NN * HH + i] = h; hAll[2 * NN * HH + i] = h;
    cAll[i] = c; cAll[NN * HH + i] = c; cAll[2 * NN * HH + i] = c;
  }
}

// cast x_seq to bf16 once (halves gather traffic in k_aggx8)
__global__ void k_xcast(const float* x, unsigned short* xb) {
  int i = blockIdx.x * 256 + threadIdx.x;   // 1,280,000 float4s
  float4 v = *(const float4*)(x + (size_t)i * 4);
  ushort4 u;
  u.x = f2b(v.x); u.y = f2b(v.y); u.z = f2b(v.z); u.w = f2b(v.w);
  *(ushort4*)(xb + (size_t)i * 4) = u;
}

// ---------- GNN cell kernels ----------

// x-aggregation for all 8 timesteps: aggX[t*NN+n][64] bf16.
__global__ void __launch_bounds__(256) k_aggx8(const unsigned short* xb, const int* row_ptr,
    const int* col_src, const float* col_w, const float* self_n, unsigned short* aggX) {
  __shared__ int es[4][64];
  __shared__ float ew[4][64];
  int wv = threadIdx.x >> 6, lane = threadIdx.x & 63;
  int p = blockIdx.x * 4 + wv;          // < 8*NN
  int t = p / NN, n = p - t * NN;
  int e0 = row_ptr[n], e1 = row_ptr[n + 1];
  float acc = 0.f;
  for (int eb = e0; eb < e1; eb += 64) {
    int cnt = min(64, e1 - eb);
    if (lane < cnt) { es[wv][lane] = col_src[eb + lane]; ew[wv][lane] = col_w[eb + lane]; }
    __builtin_amdgcn_wave_barrier();
    for (int i = 0; i < cnt; i++)
      acc += b2f(xb[((size_t)t * NN + es[wv][i]) * FF + lane]) * ew[wv][i];
    __builtin_amdgcn_wave_barrier();
  }
  acc += b2f(xb[((size_t)t * NN + n) * FF + lane]) * self_n[n];
  aggX[(size_t)p * FF + lane] = f2b(acc);
}

// h-aggregation (bf16 in/out), M rows of hAll.
__global__ void __launch_bounds__(256) k_aggh(const unsigned short* hAll, const int* row_ptr,
    const int* col_src, const float* col_w, const float* self_n, unsigned short* aggH, int M) {
  __shared__ int es[4][64];
  __shared__ float ew[4][64];
  int w = threadIdx.x >> 6, lane = threadIdx.x & 63;
  int m = blockIdx.x * 2 + (w >> 1);
  if (m >= M) return;
  int ch = (w & 1) * 64 + lane;
  int c = (m >= 2 * NN) ? 2 : (m >= NN ? 1 : 0);
  int n = m - c * NN;
  int e0 = row_ptr[n], e1 = row_ptr[n + 1];
  const unsigned short* hb = hAll + (size_t)c * NN * HH;
  float acc = 0.f;
  for (int eb = e0; eb < e1; eb += 64) {
    int cnt = min(64, e1 - eb);
    if (lane < cnt) { es[w][lane] = col_src[eb + lane]; ew[w][lane] = col_w[eb + lane]; }
    __builtin_amdgcn_wave_barrier();
    for (int i = 0; i < cnt; i++)
      acc += b2f(hb[(size_t)es[w][i] * HH + ch]) * ew[w][i];
    __builtin_amdgcn_wave_barrier();
  }
  acc += b2f(hAll[(size_t)m * HH + ch]) * self_n[n];
  aggH[(size_t)m * HH + ch] = f2b(acc);
}

// MFMA bf16 cell GEMM: pre[M x 512] (bf16) = [aggX|aggH](M x 192) @ W(192x512) + bias.
__global__ void __launch_bounds__(512) k_premm(const unsigned short* aggX,
    const unsigned short* aggH, const unsigned short* Wfrag, const float* biasC,
    unsigned short* preB, int M, int r) {
  __shared__ unsigned short Af[1536 * 8];   // [mt 0..3][ks 0..5][lane 0..63][8] = 24KB
  int m0 = blockIdx.x * 64;
  int n0 = blockIdx.y * 256;
  int tid = threadIdx.x;
  int l = tid & 63, wid = tid >> 6;
  int wm = wid >> 2, wn = wid & 3;
  #pragma unroll
  for (int q = 0; q < 3; q++) {
    int chunk = tid + q * 512;
    int mt = chunk / 384, rem = chunk - mt * 384;
    int ks = rem >> 6, cl = rem & 63;
    int row = m0 + mt * 16 + (cl & 15);
    int kk = ks * 32 + ((cl >> 4) << 3);
    short8v v = {};
    if (row < M) {
      const unsigned short* src;
      if (kk < FF) {
        int ch = (row >= 2 * NN) ? 2 : (row >= NN ? 1 : 0);
        int n = row - ch * NN;
        int t = (ch == 0) ? r : (2 * r + ch - 1);
        src = aggX + ((size_t)t * NN + n) * FF + kk;
      } else {
        src = aggH + (size_t)row * HH + (kk - FF);
      }
      v = *(const short8v*)src;
    }
    *(short8v*)&Af[chunk * 8] = v;
  }
  __syncthreads();
  f32x4 acc[2][4];
  #pragma unroll
  for (int i = 0; i < 2; i++)
    #pragma unroll
    for (int j = 0; j < 4; j++) acc[i][j] = (f32x4){0.f, 0.f, 0.f, 0.f};
  #pragma unroll
  for (int ks = 0; ks < 6; ks++) {
    short8v a0 = *(const short8v*)&Af[(((wm * 2 + 0) * 6 + ks) * 64 + l) * 8];
    short8v a1 = *(const short8v*)&Af[(((wm * 2 + 1) * 6 + ks) * 64 + l) * 8];
    #pragma unroll
    for (int j = 0; j < 4; j++) {
      int ntg = (n0 >> 4) + wn * 4 + j;
      short8v b = *(const short8v*)(Wfrag + (((size_t)ks * 32 + ntg) * 64 + l) * 8);
      acc[0][j] = __builtin_amdgcn_mfma_f32_16x16x32_bf16(a0, b, acc[0][j], 0, 0, 0);
      acc[1][j] = __builtin_amdgcn_mfma_f32_16x16x32_bf16(a1, b, acc[1][j], 0, 0, 0);
    }
  }
  #pragma unroll
  for (int i = 0; i < 2; i++)
    #pragma unroll
    for (int j = 0; j < 4; j++) {
      int colg = n0 + wn * 64 + j * 16 + (l & 15);
      float bv = biasC[colg];
      #pragma unroll
      for (int rg = 0; rg < 4; rg++) {
        int row = m0 + wm * 32 + i * 16 + ((l >> 4) * 4) + rg;
        if (row < M) preB[(size_t)row * G4 + colg] = f2b(acc[i][j][rg] + bv);
      }
    }
}

// gates + LN + state update (bf16 pre/h, fp32 c/math).  grid = M blocks, 128 threads.
__global__ void __launch_bounds__(128) k_gates(const unsigned short* preB, const float* lng,
                                               const float* lnb, unsigned short* h, float* c,
                                               int M) {
  int b = blockIdx.x;
  int j = threadIdx.x;
  const unsigned short* p = preB + (size_t)b * G4;
  float iv = b2f(p[j]), fv = b2f(p[128 + j]), ov = b2f(p[256 + j]), gv = b2f(p[384 + j]);
  float s = wred(gv), s2 = wred(gv * gv);
  __shared__ float sh[4];
  int wid = j >> 6;
  if ((j & 63) == 0) { sh[wid] = s; sh[2 + wid] = s2; }
  __syncthreads();
  float mean = (sh[0] + sh[1]) * (1.f / 128.f);
  float var = (sh[2] + sh[3]) * (1.f / 128.f) - mean * mean;
  float gn = (gv - mean) * rsqrtf(var + 1e-5f) * lng[j] + lnb[j];
  float gt = tanhf(gn);
  float ii = fmaxf(iv, 0.f), ff = fmaxf(fv, 0.f), oo = fmaxf(ov, 0.f);
  size_t ci = (size_t)b * HH + j;
  float cn = ff * c[ci] + ii * gt;
  c[ci] = cn;
  h[ci] = f2b(oo * tanhf(cn));
}

// hidden = hA@W0^T + hB@W1^T + hC@W2^T (h bf16, W fp32, out fp32).  BM=128, BN=64.
__global__ void __launch_bounds__(256) k_hidden(const unsigned short* hA, const unsigned short* hB,
                                                const unsigned short* hC, const float* Wr,
                                                float* out) {
  __shared__ __align__(16) float As[8][128];
  __shared__ __align__(16) float Bs[8][64];
  int m0 = blockIdx.x * 128, n0 = blockIdx.y * 64;
  int tid = threadIdx.x;
  int tx = tid & 15, ty = tid >> 4;
  float acc[8][4] = {};
  for (int kc = 0; kc < 48; kc++) {
    int k0 = kc * 8;
    const unsigned short* S = (k0 < 128) ? hA : (k0 < 256 ? hB : hC);
    int koff = k0 & 127;
    {
      int ml = tid >> 1, kq = (tid & 1) * 4;
      int m = m0 + ml;
      float4 v = make_float4(0.f, 0.f, 0.f, 0.f);
      if (m < NN) {
        ushort4 u = *(const ushort4*)(S + (size_t)m * HH + koff + kq);
        v.x = b2f(u.x); v.y = b2f(u.y); v.z = b2f(u.z); v.w = b2f(u.w);
      }
      As[kq + 0][ml] = v.x; As[kq + 1][ml] = v.y; As[kq + 2][ml] = v.z; As[kq + 3][ml] = v.w;
    }
    #pragma unroll
    for (int q = 0; q < 2; q++) {
      int e = tid + q * 256;
      int kl = e >> 6, nl = e & 63;
      Bs[kl][nl] = Wr[(size_t)(k0 + kl) * HH + n0 + nl];
    }
    __syncthreads();
    #pragma unroll
    for (int k = 0; k < 8; k++) {
      float4 a0 = *(const float4*)&As[k][ty * 4];
      float4 a1 = *(const float4*)&As[k][64 + ty * 4];
      float4 b0 = *(const float4*)&Bs[k][tx * 4];
      const float av0[4] = {a0.x, a0.y, a0.z, a0.w};
      const float av1[4] = {a1.x, a1.y, a1.z, a1.w};
      const float bv[4] = {b0.x, b0.y, b0.z, b0.w};
      #pragma unroll
      for (int i = 0; i < 4; i++)
        #pragma unroll
        for (int j = 0; j < 4; j++) {
          acc[i][j] += av0[i] * bv[j];
          acc[4 + i][j] += av1[i] * bv[j];
        }
    }
    __syncthreads();
  }
  #pragma unroll
  for (int g = 0; g < 2; g++)
    #pragma unroll
    for (int i = 0; i < 4; i++) {
      int m = m0 + g * 64 + ty * 4 + i;
      if (m < NN) {
        float4 r;
        r.x = acc[g * 4 + i][0]; r.y = acc[g * 4 + i][1];
        r.z = acc[g * 4 + i][2]; r.w = acc[g * 4 + i][3];
        *(float4*)(out + (size_t)m * HH + n0 + tx * 4) = r;
      }
    }
}

// ---------- pool kernels ----------

__global__ void k_vnorm(const float* pv, float* acc) {
  int t = threadIdx.x;  // 128
  float v = pv[t];
  float s = wred(v * v);
  __shared__ float sh[2];
  if ((t & 63) == 0) sh[t >> 6] = s;
  __syncthreads();
  if (t == 0) acc[0] = 1.0f / (sqrtf(sh[0] + sh[1]) + EPSF);
}

__global__ void __launch_bounds__(256) k_sc(const float* hidden, const float* pv, float* acc,
                                            float* sc) {
  int wid = threadIdx.x >> 6, lane = threadIdx.x & 63;
  float2 vv = *(const float2*)(pv + lane * 2);
  float inv = acc[0];
  float ls = 0.f, ls2 = 0.f;
  for (int n = blockIdx.x * 4 + wid; n < NN; n += gridDim.x * 4) {
    float2 hv = *(const float2*)(hidden + (size_t)n * HH + lane * 2);
    float dot = hv.x * vv.x + hv.y * vv.y;
    dot = wred(dot);
    if (lane == 0) {
      float s = dot * inv;
      sc[n] = s;
      ls += s;
      ls2 += s * s;
    }
  }
  __shared__ float sh[8];
  if (lane == 0) { sh[wid] = ls; sh[4 + wid] = ls2; }
  __syncthreads();
  if (threadIdx.x == 0) {
    atomicAdd(&acc[1], sh[0] + sh[1] + sh[2] + sh[3]);
    atomicAdd(&acc[2], sh[4] + sh[5] + sh[6] + sh[7]);
  }
}

__global__ void k_sig(const float* sc, const float* acc, float* sig) {
  int n = blockIdx.x * 256 + threadIdx.x;
  if (n < NN) {
    float mean = acc[1] * (1.f / NN);
    float var = acc[2] * (1.f / NN) - mean * mean;
    float sd = sqrtf(fmaxf(var, 0.f)) + EPSF;
    float z = (sc[n] - mean) / sd;
    sig[n] = 1.f / (1.f + expf(-z));
  }
}

__global__ void __launch_bounds__(256) k_rank(const float* sc, int* rank) {
  __shared__ float sj[1024];
  int i = blockIdx.x * 256 + threadIdx.x;
  int j0 = blockIdx.y * 1024;
  for (int k = threadIdx.x; k < 1024; k += 256) {
    int j = j0 + k;
    sj[k] = (j < NN) ? sc[j] : -3.0e38f;
  }
  __syncthreads();
  float si = (i < NN) ? sc[i] : 0.f;
  int jmax = NN - j0; if (jmax > 1024) jmax = 1024;
  int cnt = 0;
  for (int k = 0; k < jmax; k++) {
    float v = sj[k];
    int j = j0 + k;
    cnt += (v > si) || (v == si && j < i);
  }
  if (i < NN && cnt) atomicAdd(&rank[i], cnt);
}

__global__ void __launch_bounds__(256) k_plogs(const float* sig, const int* rank, float* acc) {
  int i = blockIdx.x * 256 + threadIdx.x;
  float v = 0.f;
  if (i < NN) {
    float s = sig[i];
    v = (rank[i] < KK) ? logf(s + EPSF) : logf(1.f - s + EPSF);
  }
  v = wred(v);
  __shared__ float sh[4];
  if ((threadIdx.x & 63) == 0) sh[threadIdx.x >> 6] = v;
  __syncthreads();
  if (threadIdx.x == 0) atomicAdd(&acc[3], sh[0] + sh[1] + sh[2] + sh[3]);
}

__global__ void __launch_bounds__(128) k_high(const float* hidden, const float* sig,
                                              const int* rank, float* high) {
  int ch = threadIdx.x;
  int n0 = blockIdx.x * 128;
  float a = 0.f;
  for (int q = 0; q < 128; q++) {
    int n = n0 + q;
    if (n >= NN) break;
    if (rank[n] < KK) a += hidden[(size_t)n * HH + ch] * sig[n];
  }
  atomicAdd(&high[ch], a);
}

// ---------- LSTM kernels ----------

__global__ void __launch_bounds__(256) k_zpre2(const float* Wih, const float* ts, float* part) {
  __shared__ __align__(16) float As[16][64];
  __shared__ __align__(16) float Bs[16][64];
  int m0 = blockIdx.x * 64;
  int n0 = blockIdx.y * 64;
  int ks = blockIdx.z;
  int kbeg = ks * 624;
  int kend = (ks == 15) ? NN : kbeg + 624;
  int tid = threadIdx.x;
  int tx = tid & 15, ty = tid >> 4;
  int lm = tid >> 2, kq = (tid & 3) * 4;
  bool bvalid = (n0 + lm) < TSS;
  float acc[4][4] = {};
  for (int k0 = kbeg; k0 < kend; k0 += 16) {
    {
      float4 v = *(const float4*)(Wih + (size_t)(m0 + lm) * NN + k0 + kq);
      As[kq + 0][lm] = v.x; As[kq + 1][lm] = v.y; As[kq + 2][lm] = v.z; As[kq + 3][lm] = v.w;
    }
    {
      float4 v = make_float4(0.f, 0.f, 0.f, 0.f);
      if (bvalid) v = *(const float4*)(ts + (size_t)(n0 + lm) * NN + k0 + kq);
      Bs[kq + 0][lm] = v.x; Bs[kq + 1][lm] = v.y; Bs[kq + 2][lm] = v.z; Bs[kq + 3][lm] = v.w;
    }
    __syncthreads();
    #pragma unroll
    for (int k = 0; k < 16; k++) {
      float4 a0 = *(const float4*)&As[k][ty * 4];
      float4 b0 = *(const float4*)&Bs[k][tx * 4];
      const float av[4] = {a0.x, a0.y, a0.z, a0.w};
      const float bv[4] = {b0.x, b0.y, b0.z, b0.w};
      #pragma unroll
      for (int i = 0; i < 4; i++)
        #pragma unroll
        for (int j = 0; j < 4; j++)
          acc[i][j] += av[i] * bv[j];
    }
    __syncthreads();
  }
  float* pd = part + ((size_t)ks << 17);
  #pragma unroll
  for (int i = 0; i < 4; i++) {
    float4 r4 = make_float4(acc[i][0], acc[i][1], acc[i][2], acc[i][3]);
    *(float4*)(pd + (size_t)(m0 + ty * 4 + i) * 256 + n0 + tx * 4) = r4;
  }
}

__global__ void __launch_bounds__(256) k_zred(const float* part, float* zpre) {
  int r = blockIdx.x;
  int t = threadIdx.x;
  int base = r * 256 + t;
  float s = 0.f;
  #pragma unroll
  for (int k = 0; k < 16; k++) s += part[(k << 17) + base];
  if (t < TSS) zpre[(size_t)t * G4 + r] = s;
}

// serial recurrence: 512 threads, thread r owns Whh row r as 32 NAMED float4
// variables (cannot be runtime-indexed -> guaranteed VGPRs, no scratch).
// Matvec is macro-expanded: 128 fmaf with literal-lane readlane broadcasts of
// the wave-replicated h registers; 4 accumulators break the dep chain.
#define RLN(x, J) __uint_as_float(__builtin_amdgcn_readlane(__float_as_uint(x), (J)))
#define MAC4(Q, HR, B, D) \
  D = fmaf(wv##Q.x, RLN(HR, (B) + 0), D); \
  D = fmaf(wv##Q.y, RLN(HR, (B) + 1), D); \
  D = fmaf(wv##Q.z, RLN(HR, (B) + 2), D); \
  D = fmaf(wv##Q.w, RLN(HR, (B) + 3), D);
#define LDW(Q) float4 wv##Q = *(const float4*)(wr + 4 * Q);

__global__ void __launch_bounds__(512) k_lstm(const float* Whh, const float* bih, const float* bhh,
                                              const float* zpre, float* h_last) {
  __shared__ float gact[512];
  __shared__ float hs[128];
  int r = threadIdx.x;
  int l = r & 63;
  const float* wr = Whh + (size_t)r * HH;
  LDW(0) LDW(1) LDW(2) LDW(3) LDW(4) LDW(5) LDW(6) LDW(7)
  LDW(8) LDW(9) LDW(10) LDW(11) LDW(12) LDW(13) LDW(14) LDW(15)
  LDW(16) LDW(17) LDW(18) LDW(19) LDW(20) LDW(21) LDW(22) LDW(23)
  LDW(24) LDW(25) LDW(26) LDW(27) LDW(28) LDW(29) LDW(30) LDW(31)
  float bias = bih[r] + bhh[r];
  float hreg0 = 0.f, hreg1 = 0.f, creg = 0.f;
  int gate = r >> 7;
  for (int t = 0; t < TSS; t++) {
    float z = zpre[(size_t)t * G4 + r];
    float d0 = 0.f, d1 = 0.f, d2 = 0.f, d3 = 0.f;
    MAC4(0, hreg0, 0, d0)  MAC4(1, hreg0, 4, d1)  MAC4(2, hreg0, 8, d2)  MAC4(3, hreg0, 12, d3)
    MAC4(4, hreg0, 16, d0) MAC4(5, hreg0, 20, d1) MAC4(6, hreg0, 24, d2) MAC4(7, hreg0, 28, d3)
    MAC4(8, hreg0, 32, d0) MAC4(9, hreg0, 36, d1) MAC4(10, hreg0, 40, d2) MAC4(11, hreg0, 44, d3)
    MAC4(12, hreg0, 48, d0) MAC4(13, hreg0, 52, d1) MAC4(14, hreg0, 56, d2) MAC4(15, hreg0, 60, d3)
    MAC4(16, hreg1, 0, d0)  MAC4(17, hreg1, 4, d1)  MAC4(18, hreg1, 8, d2)  MAC4(19, hreg1, 12, d3)
    MAC4(20, hreg1, 16, d0) MAC4(21, hreg1, 20, d1) MAC4(22, hreg1, 24, d2) MAC4(23, hreg1, 28, d3)
    MAC4(24, hreg1, 32, d0) MAC4(25, hreg1, 36, d1) MAC4(26, hreg1, 40, d2) MAC4(27, hreg1, 44, d3)
    MAC4(28, hreg1, 48, d0) MAC4(29, hreg1, 52, d1) MAC4(30, hreg1, 56, d2) MAC4(31, hreg1, 60, d3)
    float d = ((d0 + d1) + (d2 + d3)) + bias + z;
    float a = (gate == 2) ? tanhf(d) : (1.f / (1.f + expf(-d)));
    gact[r] = a;
    __syncthreads();
    if (r < 128) {
      creg = gact[128 + r] * creg + gact[r] * gact[256 + r];
      hs[r] = gact[384 + r] * tanhf(creg);
    }
    __syncthreads();
    hreg0 = hs[l];
    hreg1 = hs[64 + l];
  }
  if (r < 128) h_last[r] = hs[r];
}

// ---------- final MLP ----------

__global__ void __launch_bounds__(256) k_mlp(const float* high, const float* hlast, const float* acc,
    const float* W1, const float* b1, const float* lng, const float* lnb,
    const float* W2, const float* b2, const float* W3, const float* b3, float* out) {
  __shared__ float fus[256];
  __shared__ float m1[128];
  __shared__ float m2[64];
  __shared__ float red[4];
  int t = threadIdx.x;
  fus[t] = (t < 128) ? high[t] * (1.f / KK) : hlast[t - 128];
  __syncthreads();
  if (t < 128) {
    float a = b1[t];
    for (int k = 0; k < 256; k++) a += W1[t * 256 + k] * fus[k];
    m1[t] = fmaxf(a, 0.f);
  }
  __syncthreads();
  if (t < 128) {
    float x = m1[t];
    float s = wred(x), s2 = wred(x * x);
    if ((t & 63) == 0) { red[t >> 6] = s; red[2 + (t >> 6)] = s2; }
  }
  __syncthreads();
  if (t < 128) {
    float mean = (red[0] + red[1]) * (1.f / 128.f);
    float var = (red[2] + red[3]) * (1.f / 128.f) - mean * mean;
    float xn = (m1[t] - mean) * rsqrtf(var + 1e-5f) * lng[t] + lnb[t];
    __syncthreads();
    m1[t] = xn;
  } else {
    __syncthreads();
  }
  __syncthreads();
  if (t < 64) {
    float a = b2[t];
    for (int k = 0; k < 128; k++) a += W2[t * 128 + k] * m1[k];
    m2[t] = fmaxf(a, 0.f);
  }
  __syncthreads();
  if (t < 64) {
    float a = W3[t] * m2[t];
    a = wred(a);
    if (t == 0) {
      out[0] = a + b3[0];
      out[1] = -acc[3] * (1.f / NN);
    }
  }
}

// ---------- host ----------

extern "C" void kernel_launch(void* const* d_in, const int* in_sizes, int n_in,
                              void* d_out, int out_size, void* d_ws, size_t ws_size,
                              hipStream_t stream) {
  const float* x_seq = (const float*)d_in[0];
  const float* h0    = (const float*)d_in[1];
  const float* c0    = (const float*)d_in[2];
  const float* ts    = (const float*)d_in[3];
  const float* Wx    = (const float*)d_in[4];
  const float* bx    = (const float*)d_in[5];
  const float* Wh    = (const float*)d_in[6];
  const float* bh    = (const float*)d_in[7];
  const float* lng   = (const float*)d_in[8];
  const float* lnb   = (const float*)d_in[9];
  const float* mapW  = (const float*)d_in[10];
  const float* pv    = (const float*)d_in[11];
  const float* Wih   = (const float*)d_in[12];
  const float* Whh   = (const float*)d_in[13];
  const float* bih   = (const float*)d_in[14];
  const float* bhh   = (const float*)d_in[15];
  const float* W1    = (const float*)d_in[16];
  const float* b1    = (const float*)d_in[17];
  const float* mlng  = (const float*)d_in[18];
  const float* mlnb  = (const float*)d_in[19];
  const float* W2    = (const float*)d_in[20];
  const float* b2    = (const float*)d_in[21];
  const float* W3    = (const float*)d_in[22];
  const float* b3    = (const float*)d_in[23];
  const int*   ei    = (const int*)d_in[24];

  char* wsp = (char*)d_ws;
  size_t off = 0;
  auto carve = [&](size_t bytes) -> char* {
    char* p = wsp + off;
    off += (bytes + 255) & ~(size_t)255;
    return p;
  };
  unsigned short* Wfrag = (unsigned short*)carve(98304 * 2);
  float* biasC   = (float*)carve(G4 * 4);
  float* mapWr   = (float*)carve(3 * HH * HH * 4);
  int*   degi    = (int*)carve(NN * 4);
  int*   cursor  = (int*)carve(NN * 4);
  int*   rankb   = (int*)carve(NN * 4);
  int*   row_ptr = (int*)carve((NN + 1) * 4);
  float* dis     = (float*)carve(NN * 4);
  float* self_n  = (float*)carve(NN * 4);
  int*   col_src = (int*)carve(EE * 4);
  float* col_w   = (float*)carve(EE * 4);
  unsigned short* hAll = (unsigned short*)carve((size_t)3 * NN * HH * 2);
  float*          cAll = (float*)carve((size_t)3 * NN * HH * 4);
  unsigned short* x2b  = (unsigned short*)carve((size_t)TSTEPS * NN * FF * 2);
  unsigned short* aggX = (unsigned short*)carve((size_t)TSTEPS * NN * FF * 2);
  unsigned short* aggH = (unsigned short*)carve((size_t)3 * NN * HH * 2);
  unsigned short* preB = (unsigned short*)carve((size_t)3 * NN * G4 * 2);  // also zpre2 scratch
  float* hidden  = (float*)carve((size_t)NN * HH * 4);
  float* sc      = (float*)carve(NN * 4);
  float* sig     = (float*)carve(NN * 4);
  float* acc     = (float*)carve(16 * 4);
  float* high    = (float*)carve(128 * 4);
  float* zpre    = (float*)carve((size_t)TSS * G4 * 4);
  float* hlast   = (float*)carve(128 * 4);

  // setup
  k_setup_w<<<384, 256, 0, stream>>>(Wx, Wh, bx, bh, mapW, Wfrag, biasC, mapWr);
  k_zero<<<40, 256, 0, stream>>>(degi, cursor, rankb, acc, high);
  k_deg<<<625, 256, 0, stream>>>(ei, degi);
  k_norm<<<40, 256, 0, stream>>>(degi, dis, self_n);
  k_scan<<<1, 1024, 0, stream>>>(degi, row_ptr, NN);
  k_fill<<<625, 256, 0, stream>>>(ei, row_ptr, cursor, dis, col_src, col_w);
  k_init3<<<5000, 256, 0, stream>>>(h0, c0, hAll, cAll);
  k_xcast<<<5000, 256, 0, stream>>>(x_seq, x2b);

  // x-aggregation for all 8 timesteps (bf16)
  k_aggx8<<<20000, 256, 0, stream>>>(x2b, row_ptr, col_src, col_w, self_n, aggX);

  // 8 fused rounds: rounds 0-3 chains A+B+C (M=3NN), rounds 4-7 chain A only
  for (int r = 0; r < TSTEPS; r++) {
    int M = (r < 4) ? 3 * NN : NN;
    k_aggh<<<M / 2, 256, 0, stream>>>(hAll, row_ptr, col_src, col_w, self_n, aggH, M);
    k_premm<<<dim3((M + 63) / 64, 2), 512, 0, stream>>>(aggX, aggH, Wfrag, biasC, preB, M, r);
    k_gates<<<M, 128, 0, stream>>>(preB, lng, lnb, hAll, cAll, M);
  }

  // hidden combine + pool
  k_hidden<<<dim3(79, 2), 256, 0, stream>>>(hAll, hAll + (size_t)NN * HH,
                                            hAll + (size_t)2 * NN * HH, mapWr, hidden);
  k_vnorm<<<1, 128, 0, stream>>>(pv, acc);
  k_sc<<<250, 256, 0, stream>>>(hidden, pv, acc, sc);
  k_sig<<<40, 256, 0, stream>>>(sc, acc, sig);
  k_rank<<<dim3(40, 10), 256, 0, stream>>>(sc, rankb);
  k_plogs<<<40, 256, 0, stream>>>(sig, rankb, acc);
  k_high<<<79, 128, 0, stream>>>(hidden, sig, rankb, high);

  // LSTM branch (zpre2 partials in preB scratch, free after GNN rounds)
  k_zpre2<<<dim3(8, 4, 16), 256, 0, stream>>>(Wih, ts, (float*)preB);
  k_zred<<<512, 256, 0, stream>>>((float*)preB, zpre);
  k_lstm<<<1, 512, 0, stream>>>(Whh, bih, bhh, zpre, hlast);

  // head
  k_mlp<<<1, 256, 0, stream>>>(high, hlast, acc, W1, b1, mlng, mlnb, W2, b2, W3, b3,
                               (float*)d_out);
}